// Round 3
// baseline (432.234 us; speedup 1.0000x reference)
//
#include <hip/hip_runtime.h>
#include <stdint.h>

// Problem constants
#define S_LEN 2048
#define DIM_   4096
#define NH_    32
#define NKV_   8
#define HD_    128
#define QK_SCALE 0.08838834764831845f   // 1/sqrt(128)

typedef __attribute__((ext_vector_type(8)))  short  s16x8;   // 8 bf16 (4 VGPRs) MFMA frag
typedef __attribute__((ext_vector_type(4)))  float  f32x4;   // 16x16 MFMA accum
typedef __attribute__((ext_vector_type(16))) float  f32x16;  // 32x32 MFMA accum
typedef __attribute__((ext_vector_type(8))) unsigned short u16x8;
typedef __attribute__((ext_vector_type(4))) unsigned short u16x4;

union frag_u { s16x8 f; uint32_t w[4]; };

__device__ __forceinline__ unsigned short f2bf(float f) {
  union { float f; uint32_t u; } v; v.f = f;
  return (unsigned short)((v.u + 0x7fffu + ((v.u >> 16) & 1u)) >> 16);   // RNE
}

__device__ __forceinline__ uint32_t cvt_pk_bf16(float lo, float hi2) {
  uint32_t r;
  asm volatile("v_cvt_pk_bf16_f32 %0, %1, %2" : "=v"(r) : "v"(lo), "v"(hi2));
  return r;
}

// async global->LDS, 16B per lane. LDS dest is wave-uniform base + lane*16.
__device__ __forceinline__ void async_cp16(const void* g, void* l) {
  __builtin_amdgcn_global_load_lds(
      (const __attribute__((address_space(1))) unsigned int*)g,
      (__attribute__((address_space(3))) unsigned int*)l, 16, 0, 0);
}

#define WAITV(n) asm volatile("s_waitcnt vmcnt(" #n ")" ::: "memory")

// ---------------- cast fp32 -> bf16 (vectorized x4) ----------------
__global__ __launch_bounds__(256) void cast_f32_bf16(
    const float* __restrict__ src, unsigned short* __restrict__ dst, int n4) {
  const int i = blockIdx.x * 256 + threadIdx.x;
  if (i >= n4) return;
  const float4 v = ((const float4*)src)[i];
  u16x4 o; o[0] = f2bf(v.x); o[1] = f2bf(v.y); o[2] = f2bf(v.z); o[3] = f2bf(v.w);
  ((u16x4*)dst)[i] = o;
}

// ======================= 256x256 deep-pipelined GEMM ========================
// C = A(MxK) * B^T(NxK), bf16 in fp32 out. K global stride = 4096 for both uses.
// 8 waves (2Mx4N), per-wave 128x64 out, 32x32x16 MFMA, BK=32.
// LDS: 4-slot ring x (A 16KB + B 16KB) = 128KB. Stage 3 tiles ahead.
// Pair-packed LDS rows: LDS-row hr (128B) = logical rows {2hr, 2hr+1} x 32 k.
// 16B-slot swizzle: stored_slot = (kslot + 4*(row&1)) ^ (hr&7)  -> conflict-free.
// Boundary: s_waitcnt vmcnt(8) + s_barrier  (tile kt+1 guaranteed complete).
template <int NK, int NTILES, int KSPLIT>
__global__ __launch_bounds__(512, 2) void gemm256(
    const unsigned short* __restrict__ A, const unsigned short* __restrict__ B,
    float* __restrict__ C, int ldc, int cHalfOff) {
  __shared__ unsigned short ldsA[4 * 8192];   // 4 slots x 256x32 bf16 (pair-packed)
  __shared__ unsigned short ldsB[4 * 8192];

  const int CHUNK = NTILES * KSPLIT;          // wgs per XCD
  const int bid = blockIdx.x;
  const int sw = (bid & 7) * CHUNK + (bid >> 3);   // bijective XCD swizzle
  const int m = sw & 7;                        // 8 M-tiles always
  const int q = sw >> 3;
  const int n = q % NTILES;
  const int kh = q / NTILES;
  const int m0 = m * 256, n0 = n * 256;
  const int kbase = kh * (NK * 32);
  float* Cw = C + (size_t)kh * cHalfOff;

  const int tid = threadIdx.x;
  const int wave = tid >> 6, lane = tid & 63;
  const int col = lane & 31, hi = lane >> 5;
  const int wm = wave >> 2, wn = wave & 3;

  // ---- staging per-thread source offsets (2 chunks of 1024B each per matrix) ----
  // chunk ch covers logical rows 16ch..16ch+15; lane l -> LDS byte ch*1024 + l*16.
  // stored slot s=(l&7) at LDS-row R=(l>>3) holds logical slot sl = s ^ R:
  //   row = 16ch + 2R + (sl>>2), k-elems = (sl&3)*8.
  const int R = lane >> 3, sl = (lane & 7) ^ R;
  size_t aoff[2], boff[2];
#pragma unroll
  for (int i = 0; i < 2; ++i) {
    const int ch = wave * 2 + i;
    const int row = 16 * ch + 2 * R + (sl >> 2);
    const int ke = (sl & 3) * 8;
    aoff[i] = (size_t)(m0 + row) * 4096 + kbase + ke;
    boff[i] = (size_t)(n0 + row) * 4096 + kbase + ke;
  }

  // ---- fragment LDS byte offsets (kt-invariant) ----
  int offA[4][2], offB[2][2];
#pragma unroll
  for (int rb = 0; rb < 4; ++rb) {
    const int r = wm * 128 + rb * 32 + col;
    const int hr = r >> 1, odd = r & 1, key = hr & 7;
#pragma unroll
    for (int ks = 0; ks < 2; ++ks)
      offA[rb][ks] = hr * 128 + ((((ks * 2 + hi) + 4 * odd) ^ key) * 16);
  }
#pragma unroll
  for (int nb = 0; nb < 2; ++nb) {
    const int r = wn * 64 + nb * 32 + col;
    const int hr = r >> 1, odd = r & 1, key = hr & 7;
#pragma unroll
    for (int ks = 0; ks < 2; ++ks)
      offB[nb][ks] = hr * 128 + ((((ks * 2 + hi) + 4 * odd) ^ key) * 16);
  }

  f32x16 acc[4][2] = {};

#define STAGE(KT, SLOT)                                                     \
  {                                                                         \
    _Pragma("unroll")                                                       \
    for (int i_ = 0; i_ < 2; ++i_) {                                        \
      const int ch_ = wave * 2 + i_;                                        \
      async_cp16(A + aoff[i_] + (size_t)(KT) * 32,                          \
                 (char*)ldsA + (SLOT) * 16384 + ch_ * 1024);                \
      async_cp16(B + boff[i_] + (size_t)(KT) * 32,                          \
                 (char*)ldsB + (SLOT) * 16384 + ch_ * 1024);                \
    }                                                                       \
  }

#define COMPUTE(SLOT)                                                       \
  {                                                                         \
    const char* __restrict__ pa = (const char*)ldsA + (SLOT) * 16384;       \
    const char* __restrict__ pb = (const char*)ldsB + (SLOT) * 16384;       \
    s16x8 fa[4][2], fb[2][2];                                               \
    _Pragma("unroll")                                                       \
    for (int rb = 0; rb < 4; ++rb)                                          \
      _Pragma("unroll")                                                     \
      for (int ks = 0; ks < 2; ++ks)                                        \
        fa[rb][ks] = *(const s16x8*)(pa + offA[rb][ks]);                    \
    _Pragma("unroll")                                                       \
    for (int nb = 0; nb < 2; ++nb)                                          \
      _Pragma("unroll")                                                     \
      for (int ks = 0; ks < 2; ++ks)                                        \
        fb[nb][ks] = *(const s16x8*)(pb + offB[nb][ks]);                    \
    __builtin_amdgcn_s_setprio(1);                                          \
    _Pragma("unroll")                                                       \
    for (int ks = 0; ks < 2; ++ks)                                          \
      _Pragma("unroll")                                                     \
      for (int rb = 0; rb < 4; ++rb)                                        \
        _Pragma("unroll")                                                   \
        for (int nb = 0; nb < 2; ++nb)                                      \
          acc[rb][nb] = __builtin_amdgcn_mfma_f32_32x32x16_bf16(            \
              fa[rb][ks], fb[nb][ks], acc[rb][nb], 0, 0, 0);                \
    __builtin_amdgcn_s_setprio(0);                                          \
  }

  // prologue: fill 3 ring slots, wait tile 0 (allow tiles 1,2 = 8 loads)
  STAGE(0, 0); STAGE(1, 1); STAGE(2, 2);
  WAITV(8);
  __builtin_amdgcn_s_barrier();

  int kt = 0;
  for (; kt < NK - 3; ++kt) {
    STAGE(kt + 3, (kt + 3) & 3);
    COMPUTE(kt & 3);
    WAITV(8);                       // tile kt+1 complete; 2 tiles in flight
    __builtin_amdgcn_s_barrier();
  }
  COMPUTE(kt & 3); WAITV(4); __builtin_amdgcn_s_barrier(); ++kt;   // NK-3
  COMPUTE(kt & 3); WAITV(0); __builtin_amdgcn_s_barrier(); ++kt;   // NK-2
  COMPUTE(kt & 3);                                                  // NK-1

  // epilogue: C[m0+wm*128+rb*32+row][n0+wn*64+nb*32+col]
#pragma unroll
  for (int rb = 0; rb < 4; ++rb)
#pragma unroll
    for (int nb = 0; nb < 2; ++nb) {
      float* cp = Cw + (size_t)(m0 + wm * 128 + rb * 32) * ldc + n0 + wn * 64 + nb * 32 + col;
#pragma unroll
      for (int r = 0; r < 16; ++r) {
        const int rowIn = (r & 3) + 8 * (r >> 2) + 4 * hi;
        cp[(size_t)rowIn * ldc] = acc[rb][nb][r];
      }
    }
#undef STAGE
#undef COMPUTE
}

// ---------------- fp32 add (K-split reduction) ----------------
__global__ __launch_bounds__(256) void add2_kern(
    const float* __restrict__ a, const float* __restrict__ b,
    float* __restrict__ o, int n4) {
  const int i = blockIdx.x * 256 + threadIdx.x;
  if (i >= n4) return;
  const float4 x = ((const float4*)a)[i];
  const float4 y = ((const float4*)b)[i];
  float4 r; r.x = x.x + y.x; r.y = x.y + y.y; r.z = x.z + y.z; r.w = x.w + y.w;
  ((float4*)o)[i] = r;
}

// ---------------- RoPE on Q (folds QK scale), fp32 -> bf16 ----------
__global__ __launch_bounds__(256) void rope_q_kern(
    const float* __restrict__ xqkv, const float* __restrict__ cos_f,
    const float* __restrict__ sin_f, unsigned short* __restrict__ qb) {
  const int gid = blockIdx.x * 256 + threadIdx.x;
  const int e0 = gid * 8;
  const int s = e0 >> 12;
  const int col = e0 & 4095;
  const int i0 = (col & 127) >> 1;
  const float* src = xqkv + (size_t)s * 6144 + col;
  const float4 f1 = *(const float4*)src;
  const float4 f2 = *(const float4*)(src + 4);
  const float4 c  = *(const float4*)(cos_f + s * 64 + i0);
  const float4 sn = *(const float4*)(sin_f + s * 64 + i0);
  u16x8 o;
  o[0] = f2bf((f1.x * c.x - f1.y * sn.x) * QK_SCALE);
  o[1] = f2bf((f1.x * sn.x + f1.y * c.x) * QK_SCALE);
  o[2] = f2bf((f1.z * c.y - f1.w * sn.y) * QK_SCALE);
  o[3] = f2bf((f1.z * sn.y + f1.w * c.y) * QK_SCALE);
  o[4] = f2bf((f2.x * c.z - f2.y * sn.z) * QK_SCALE);
  o[5] = f2bf((f2.x * sn.z + f2.y * c.z) * QK_SCALE);
  o[6] = f2bf((f2.z * c.w - f2.w * sn.w) * QK_SCALE);
  o[7] = f2bf((f2.z * sn.w + f2.w * c.w) * QK_SCALE);
  *(u16x8*)(qb + e0) = o;
}

// ---------------- RoPE on K: fp32 cache out + bf16 attn K -----------
__global__ __launch_bounds__(256) void rope_k_kern(
    const float* __restrict__ xqkv, const float* __restrict__ cos_f,
    const float* __restrict__ sin_f, float* __restrict__ ck, unsigned short* __restrict__ kb) {
  const int gid = blockIdx.x * 256 + threadIdx.x;
  const int e0 = gid * 8;
  const int s = e0 >> 10;
  const int col = e0 & 1023;
  const int i0 = (col & 127) >> 1;
  const float* src = xqkv + (size_t)s * 6144 + 4096 + col;
  const float4 f1 = *(const float4*)src;
  const float4 f2 = *(const float4*)(src + 4);
  const float4 c  = *(const float4*)(cos_f + s * 64 + i0);
  const float4 sn = *(const float4*)(sin_f + s * 64 + i0);
  const float r0 = f1.x * c.x - f1.y * sn.x, r1 = f1.x * sn.x + f1.y * c.x;
  const float r2 = f1.z * c.y - f1.w * sn.y, r3 = f1.z * sn.y + f1.w * c.y;
  const float r4 = f2.x * c.z - f2.y * sn.z, r5 = f2.x * sn.z + f2.y * c.z;
  const float r6 = f2.z * c.w - f2.w * sn.w, r7 = f2.z * sn.w + f2.w * c.w;
  float4 o1; o1.x = r0; o1.y = r1; o1.z = r2; o1.w = r3;
  float4 o2; o2.x = r4; o2.y = r5; o2.z = r6; o2.w = r7;
  *(float4*)(ck + (size_t)s * 1024 + col) = o1;
  *(float4*)(ck + (size_t)s * 1024 + col + 4) = o2;
  u16x8 o;
  o[0] = f2bf(r0); o[1] = f2bf(r1); o[2] = f2bf(r2); o[3] = f2bf(r3);
  o[4] = f2bf(r4); o[5] = f2bf(r5); o[6] = f2bf(r6); o[7] = f2bf(r7);
  *(u16x8*)(kb + (size_t)s * 1024 + col) = o;
}

// ------- V: fp32 cache out (coalesced) + bf16 V^T [NKV*HD][S] -------
__global__ __launch_bounds__(256) void vtrans_kern(
    const float* __restrict__ xqkv, float* __restrict__ cv, unsigned short* __restrict__ vtb) {
  __shared__ float tile[64][65];
  const int st = blockIdx.x * 64;
  const int ct = blockIdx.y * 64;
  const int tid = threadIdx.x;
#pragma unroll
  for (int j = 0; j < 16; ++j) {
    const int lin = tid + j * 256;
    const int si = lin >> 6, ci = lin & 63;
    const float v = xqkv[(size_t)(st + si) * 6144 + 5120 + ct + ci];
    cv[(size_t)(st + si) * 1024 + ct + ci] = v;
    tile[si][ci] = v;
  }
  __syncthreads();
#pragma unroll
  for (int j = 0; j < 16; ++j) {
    const int lin = tid + j * 256;
    const int co = lin >> 6, so = lin & 63;
    vtb[(size_t)(ct + co) * 2048 + st + so] = f2bf(tile[so][co]);
  }
}

// ---------------- flash attention v2 (unchanged from R2) ------------
__global__ __launch_bounds__(256, 2) void attn_fwd2(
    const unsigned short* __restrict__ qb, const unsigned short* __restrict__ kb,
    const unsigned short* __restrict__ vtb, unsigned short* __restrict__ ob) {
  __shared__ unsigned short Ks[2][64 * 128];
  __shared__ unsigned short Vs[2][128 * 64];
  const int bx = blockIdx.x;
  const int h  = blockIdx.y;
  const int hkv = h >> 2;
  const int g = (bx & 1) ? (15 - (bx >> 1)) : (bx >> 1);
  const int qtile = (h < 16) ? g : (15 - g);
  const int q0 = qtile * 128;
  const int tid = threadIdx.x, wave = tid >> 6, lane = tid & 63;
  const int col = lane & 31;
  const int hi  = lane >> 5;
  const int q0w = q0 + wave * 32;
  const int nt = (q0 >> 6) + 2;

  s16x8 qf[8];
  {
    const unsigned short* qrow = qb + (size_t)(q0w + col) * 4096 + h * 128 + hi * 8;
#pragma unroll
    for (int ks = 0; ks < 8; ++ks) qf[ks] = *(const s16x8*)(qrow + ks * 16);
  }

  f32x16 oacc[4] = {};
  float m_s = -3e30f, l_s = 0.0f;

#define STAGE_K(KT, B)                                                        \
  {                                                                           \
    const unsigned short* src = kb + (size_t)((KT) * 64) * 1024 + hkv * 128;  \
    _Pragma("unroll")                                                         \
    for (int i_ = 0; i_ < 4; ++i_) {                                          \
      const int c_ = wave * 4 + i_;                                           \
      const int row_ = c_ * 4 + (lane >> 4);                                  \
      const int cb_ = ((lane & 15) * 16) ^ ((row_ & 7) << 4);                 \
      async_cp16(src + (size_t)row_ * 1024 + (cb_ >> 1), (char*)Ks[B] + c_ * 1024); \
    }                                                                         \
  }
#define STAGE_V(KT, B)                                                        \
  {                                                                           \
    const unsigned short* src = vtb + (size_t)hkv * (128 * 2048) + (KT) * 64; \
    _Pragma("unroll")                                                         \
    for (int i_ = 0; i_ < 4; ++i_) {                                          \
      const int c_ = wave * 4 + i_;                                           \
      const int row_ = c_ * 8 + (lane >> 3);                                  \
      const int cb_ = ((lane & 7) * 16) ^ ((row_ & 7) << 4);                  \
      async_cp16(src + (size_t)row_ * 2048 + (cb_ >> 1), (char*)Vs[B] + c_ * 1024); \
    }                                                                         \
  }

  STAGE_K(0, 0); STAGE_V(0, 0);
  __syncthreads();

  for (int kt = 0; kt < nt; ++kt) {
    const int kv0 = kt * 64;
    const int cur = kt & 1;
    if (kt + 1 < nt) { STAGE_K(kt + 1, cur ^ 1); STAGE_V(kt + 1, cur ^ 1); }

    if (kv0 < q0w + 32) {
      f32x16 s0 = {}, s1 = {};
#pragma unroll
      for (int ks = 0; ks < 8; ++ks) {
        const int gcb = 32 * ks + 16 * hi;
        const int sw = (col & 7) << 4;
        const s16x8 k0 = *(const s16x8*)((const char*)Ks[cur] + col * 256 + (gcb ^ sw));
        const s16x8 k1 = *(const s16x8*)((const char*)Ks[cur] + (32 + col) * 256 + (gcb ^ sw));
        s0 = __builtin_amdgcn_mfma_f32_32x32x16_bf16(k0, qf[ks], s0, 0, 0, 0);
        s1 = __builtin_amdgcn_mfma_f32_32x32x16_bf16(k1, qf[ks], s1, 0, 0, 0);
      }

      const int qg = q0w + col;
      if (kv0 + 63 > q0w) {
#pragma unroll
        for (int r = 0; r < 16; ++r) {
          const int kvl = (r & 3) + 8 * (r >> 2) + 4 * hi;
          if (kv0 + kvl > qg)      s0[r] = -3e30f;
          if (kv0 + 32 + kvl > qg) s1[r] = -3e30f;
        }
      }

      float mxl = s0[0];
#pragma unroll
      for (int r = 1; r < 16; ++r) mxl = fmaxf(mxl, s0[r]);
#pragma unroll
      for (int r = 0; r < 16; ++r) mxl = fmaxf(mxl, s1[r]);
      const float mxf = fmaxf(mxl, __shfl_xor(mxl, 32));
      if (__any(mxf > m_s + 8.0f)) {
        const float mn = fmaxf(m_s, mxf);
        const float scl = __expf(m_s - mn);
        m_s = mn;
        l_s *= scl;
#pragma unroll
        for (int r = 0; r < 16; ++r) {
          const int qq = (r & 3) + 8 * (r >> 2) + 4 * hi;
          const float sr = __int_as_float(
              __builtin_amdgcn_ds_bpermute(qq * 4, __float_as_int(scl)));
          oacc[0][r] *= sr; oacc[1][r] *= sr; oacc[2][r] *= sr; oacc[3][r] *= sr;
        }
      }
      float lsum = 0.0f;
#pragma unroll
      for (int r = 0; r < 16; ++r) {
        s0[r] = __expf(s0[r] - m_s); s1[r] = __expf(s1[r] - m_s);
        lsum += s0[r] + s1[r];
      }
      lsum += __shfl_xor(lsum, 32);
      l_s += lsum;

#define PV_STEP(KS, PP)                                                       \
      {                                                                       \
        const int rb2 = 8 * ((KS) & 1);                                       \
        const uint32_t g0a = cvt_pk_bf16(PP[rb2 + 0], PP[rb2 + 1]);           \
        const uint32_t g0b = cvt_pk_bf16(PP[rb2 + 2], PP[rb2 + 3]);           \
        const uint32_t g1a = cvt_pk_bf16(PP[rb2 + 4], PP[rb2 + 5]);           \
        const uint32_t g1b = cvt_pk_bf16(PP[rb2 + 6], PP[rb2 + 7]);           \
        const uint32_t sa = hi ? g0a : g1a, sb = hi ? g0b : g1b;              \
        const uint32_t ra = (uint32_t)__shfl_xor((int)sa, 32);                \
        const uint32_t rb_ = (uint32_t)__shfl_xor((int)sb, 32);               \
        frag_u af;                                                            \
        af.w[0] = hi ? ra  : g0a; af.w[1] = hi ? rb_ : g0b;                   \
        af.w[2] = hi ? g1a : ra;  af.w[3] = hi ? g1b : rb_;                   \
        const int gcb = 32 * (KS) + 16 * hi;                                  \
        const int vsw = (col & 7) << 4;                                       \
        _Pragma("unroll")                                                     \
        for (int db = 0; db < 4; ++db) {                                      \
          const s16x8 bv = *(const s16x8*)((const char*)Vs[cur] +             \
              (db * 32 + col) * 128 + (gcb ^ vsw));                           \
          oacc[db] = __builtin_amdgcn_mfma_f32_32x32x16_bf16(af.f, bv, oacc[db], 0, 0, 0); \
        }                                                                     \
      }
      PV_STEP(0, s0); PV_STEP(1, s0); PV_STEP(2, s1); PV_STEP(3, s1);
#undef PV_STEP
    }
    __syncthreads();
  }

  const float linv = 1.0f / l_s;
#pragma unroll
  for (int r = 0; r < 16; ++r) {
    const int qq = (r & 3) + 8 * (r >> 2) + 4 * hi;
    const float lr = __int_as_float(
        __builtin_amdgcn_ds_bpermute(qq * 4, __float_as_int(linv)));
    unsigned short* orow = ob + (size_t)(q0w + qq) * 4096 + h * 128 + col;
#pragma unroll
    for (int db = 0; db < 4; ++db)
      orow[db * 32] = f2bf(oacc[db][r] * lr);
  }
#undef STAGE_K
#undef STAGE_V
}

// ------------------------------ launch ------------------------------
extern "C" void kernel_launch(void* const* d_in, const int* in_sizes, int n_in,
                              void* d_out, int out_size, void* d_ws, size_t ws_size,
                              hipStream_t stream) {
  const float* x     = (const float*)d_in[0];
  const float* cos_f = (const float*)d_in[1];
  const float* sin_f = (const float*)d_in[2];
  const float* wq = (const float*)d_in[4];
  const float* wk = (const float*)d_in[5];
  const float* wv = (const float*)d_in[6];
  const float* wo = (const float*)d_in[7];
  float* out = (float*)d_out;

  char* ws = (char*)d_ws;
  unsigned short* xb    = (unsigned short*)(ws);                 // 2048x4096 bf16
  unsigned short* wqkvb = (unsigned short*)(ws + 16777216);      // 6144x4096 bf16
  unsigned short* wob   = (unsigned short*)(ws + 67108864);      // 4096x4096 bf16
  float*          xqkv  = (float*)(ws + 100663296);              // 2048x6144 fp32
  unsigned short* qb    = (unsigned short*)(ws + 150994944);     // 2048x4096 bf16
  unsigned short* kb    = (unsigned short*)(ws + 167772160);     // 2048x1024 bf16
  unsigned short* vtb   = (unsigned short*)(ws + 171966464);     // [8*128][2048] bf16
  unsigned short* attno = (unsigned short*)(ws + 176160768);     // 2048x4096 bf16
  float*          ctmp  = (float*)(ws);                          // 2x 2048x4096 fp32
                                                                 // (reuses xb/wqkvb region,
                                                                 //  both dead by then)

  cast_f32_bf16<<<dim3(8192), 256, 0, stream>>>(x, xb, 2097152);
  cast_f32_bf16<<<dim3(16384), 256, 0, stream>>>(wq, wqkvb, 4194304);
  cast_f32_bf16<<<dim3(4096), 256, 0, stream>>>(wk, wqkvb + 16777216, 1048576);
  cast_f32_bf16<<<dim3(4096), 256, 0, stream>>>(wv, wqkvb + 20971520, 1048576);
  cast_f32_bf16<<<dim3(16384), 256, 0, stream>>>(wo, wob, 4194304);

  // fused QKV projection: [2048x4096] x [6144x4096]^T -> [2048x6144] fp32
  gemm256<128, 24, 1><<<dim3(192), 512, 0, stream>>>(xb, wqkvb, xqkv, 6144, 0);

  rope_q_kern<<<dim3(4096), 256, 0, stream>>>(xqkv, cos_f, sin_f, qb);
  rope_k_kern<<<dim3(1024), 256, 0, stream>>>(xqkv, cos_f, sin_f, out + 8388608, kb);
  vtrans_kern<<<dim3(32, 16), 256, 0, stream>>>(xqkv, out + 12582912, vtb);

  (void)hipMemsetAsync(out + 10485760, 0, 8388608, stream);
  (void)hipMemsetAsync(out + 14680064, 0, 8388608, stream);

  attn_fwd2<<<dim3(16, 32), 256, 0, stream>>>(qb, kb, vtb, attno);

  // output projection, K-split x2: [2048x4096] x [4096x4096]^T, halves -> ctmp
  gemm256<64, 16, 2><<<dim3(256), 512, 0, stream>>>(attno, wob, ctmp, 4096, 8388608);
  add2_kern<<<dim3(8192), 256, 0, stream>>>(ctmp, ctmp + 8388608, out, 2097152);
}

// Round 5
// 358.795 us; speedup vs baseline: 1.2047x; 1.2047x over previous
//
#include <hip/hip_runtime.h>
#include <stdint.h>

// Problem constants
#define S_LEN 2048
#define DIM_   4096
#define NH_    32
#define NKV_   8
#define HD_    128
#define QK_SCALE 0.08838834764831845f   // 1/sqrt(128)

typedef __attribute__((ext_vector_type(8)))  short  s16x8;   // 8 bf16 (4 VGPRs) MFMA frag
typedef __attribute__((ext_vector_type(4)))  float  f32x4;   // 16x16 MFMA accum
typedef __attribute__((ext_vector_type(16))) float  f32x16;  // 32x32 MFMA accum
typedef __attribute__((ext_vector_type(8))) unsigned short u16x8;
typedef __attribute__((ext_vector_type(4))) unsigned short u16x4;

union frag_u { s16x8 f; uint32_t w[4]; };

__device__ __forceinline__ unsigned short f2bf(float f) {
  union { float f; uint32_t u; } v; v.f = f;
  return (unsigned short)((v.u + 0x7fffu + ((v.u >> 16) & 1u)) >> 16);   // RNE
}

__device__ __forceinline__ uint32_t cvt_pk_bf16(float lo, float hi2) {
  uint32_t r;
  asm volatile("v_cvt_pk_bf16_f32 %0, %1, %2" : "=v"(r) : "v"(lo), "v"(hi2));
  return r;
}

// async global->LDS, 16B per lane. LDS dest is wave-uniform base + lane*16.
__device__ __forceinline__ void async_cp16(const void* g, void* l) {
  __builtin_amdgcn_global_load_lds(
      (const __attribute__((address_space(1))) unsigned int*)g,
      (__attribute__((address_space(3))) unsigned int*)l, 16, 0, 0);
}

#define WAITV(n) asm volatile("s_waitcnt vmcnt(" #n ")" ::: "memory")

// ---------------- cast fp32 -> bf16 (vectorized x4) ----------------
__global__ __launch_bounds__(256) void cast_f32_bf16(
    const float* __restrict__ src, unsigned short* __restrict__ dst, int n4) {
  const int i = blockIdx.x * 256 + threadIdx.x;
  if (i >= n4) return;
  const float4 v = ((const float4*)src)[i];
  u16x4 o; o[0] = f2bf(v.x); o[1] = f2bf(v.y); o[2] = f2bf(v.z); o[3] = f2bf(v.w);
  ((u16x4*)dst)[i] = o;
}

// ================== 256x256 8-phase GEMM (m201 port) =====================
// C = A(MxK)*B^T(NxK), bf16 in fp32 out. K stride 4096. M = 2048 (8 tiles).
// 8 waves 2Mx4N; per-wave 128x64 out.
// LDS: [buf][mat][half][128][64] bf16 = 128 KiB. st_16x32 swizzle
// (byte ^= ((byte>>9)&1)<<5), applied on staging SOURCE and ds_read (#21).
// Phases per K-tile group (quadrants (0,0),(0,1),(1,1),(1,0)); ds_reads
// 12/4/8/4; stages: B0(j+1)@g0 -> buf^1, A0(j+2)@g1, B1(j+2)@g2,
// A1(j+2)@g3 -> buf. Gate vmcnt(6) at g3 only (3 half-tiles in flight).
template <int NT, int NTN, int KSPLIT>
__global__ __launch_bounds__(512, 2) void gemm8p(
    const unsigned short* __restrict__ A, const unsigned short* __restrict__ B,
    float* __restrict__ C, int ldc, size_t cHalfOff) {
  __shared__ unsigned short lds[65536];   // 128 KiB

  const int bid = blockIdx.x;
  const int xcd = bid & 7, ii = bid >> 3;
  const int percomb = (NTN * KSPLIT) / 8;
  const int idx = xcd * percomb + (ii >> 3);
  const int n = idx / KSPLIT, kh = idx % KSPLIT;
  const int m = ii & 7;
  const int m0 = m * 256, n0 = n * 256;
  const int kbase = kh * (NT * 64);
  float* Cw = C + (size_t)kh * cHalfOff;

  const int tid = threadIdx.x;
  const int wave = tid >> 6, lane = tid & 63;
  const int wm = wave >> 2, wn = wave & 3;
  const int fr = lane & 15;
  const int slotx = ((lane >> 4) * 16) ^ ((lane & 4) << 3);   // swizzled 16B slot
  const int abase = (wm * 64 + fr) * 128 + slotx;             // A frag base (bytes)
  const int bbase = (wn * 32 + fr) * 128 + slotx;             // B frag base (region off in LDB)

  // staging source: LDS offset o = i*8192+tid*16; logical l = o ^ swz
  const int scb = ((tid & 7) * 16) ^ (((tid >> 5) & 1) << 5); // col-bytes
  uint32_t aoff[2][2], boff[2][2];                            // [half][i] element offs
#pragma unroll
  for (int h = 0; h < 2; ++h)
#pragma unroll
    for (int i = 0; i < 2; ++i) {
      const int row = h * 128 + i * 64 + (tid >> 3);
      aoff[h][i] = (uint32_t)((m0 + row) * 4096 + kbase + (scb >> 1));
      boff[h][i] = (uint32_t)((n0 + row) * 4096 + kbase + (scb >> 1));
    }

  f32x4 acc[2][2][4][2] = {};
  s16x8 fa[4][2], fb[2][2];

#define STGA(H, T, BUF)                                                       \
  { _Pragma("unroll") for (int i_ = 0; i_ < 2; ++i_)                          \
      async_cp16(A + aoff[H][i_] + (size_t)(T) * 64,                          \
                 (char*)lds + (BUF) * 65536 + (H) * 16384 + i_ * 8192 + tid * 16); }
#define STGB(H, T, BUF)                                                       \
  { _Pragma("unroll") for (int i_ = 0; i_ < 2; ++i_)                          \
      async_cp16(B + boff[H][i_] + (size_t)(T) * 64,                          \
                 (char*)lds + (BUF) * 65536 + 32768 + (H) * 16384 + i_ * 8192 + tid * 16); }
#define LDA(AA, P)                                                            \
  { _Pragma("unroll") for (int rf = 0; rf < 4; ++rf)                          \
      _Pragma("unroll") for (int kk = 0; kk < 2; ++kk)                        \
        fa[rf][kk] = *(const s16x8*)((char*)lds + (P) * 65536 + (AA) * 16384 +\
                                     rf * 2048 + kk * 64 + abase); }
#define LDB(BB, P)                                                            \
  { _Pragma("unroll") for (int cf = 0; cf < 2; ++cf)                          \
      _Pragma("unroll") for (int kk = 0; kk < 2; ++kk)                        \
        fb[cf][kk] = *(const s16x8*)((char*)lds + (P) * 65536 + 32768 +       \
                                     (BB) * 16384 + cf * 2048 + kk * 64 + bbase); }
#define BARLG()                                                               \
  __builtin_amdgcn_s_barrier();                                               \
  asm volatile("s_waitcnt lgkmcnt(0)" ::: "memory");                          \
  __builtin_amdgcn_sched_barrier(0);
#define MF(AA, BB)                                                            \
  __builtin_amdgcn_s_setprio(1);                                              \
  { _Pragma("unroll") for (int kk = 0; kk < 2; ++kk)                          \
      _Pragma("unroll") for (int rf = 0; rf < 4; ++rf)                        \
        _Pragma("unroll") for (int cf = 0; cf < 2; ++cf)                      \
          acc[AA][BB][rf][cf] = __builtin_amdgcn_mfma_f32_16x16x32_bf16(      \
              fa[rf][kk], fb[cf][kk], acc[AA][BB][rf][cf], 0, 0, 0); }        \
  __builtin_amdgcn_s_setprio(0);

#define GROUP(J, P, DOS0, DOS123, GATE)                                       \
  {                                                                           \
    LDA(0, P); LDB(0, P);                                                     \
    if (DOS0) { STGB(0, (J) + 1, (P) ^ 1); }                                  \
    BARLG(); MF(0, 0);                                                        \
    __builtin_amdgcn_s_barrier();                                             \
    LDB(1, P);                                                                \
    if (DOS123) { STGA(0, (J) + 2, P); }                                      \
    BARLG(); MF(0, 1);                                                        \
    __builtin_amdgcn_s_barrier();                                             \
    LDA(1, P);                                                                \
    if (DOS123) { STGB(1, (J) + 2, P); }                                      \
    BARLG(); MF(1, 1);                                                        \
    __builtin_amdgcn_s_barrier();                                             \
    LDB(0, P);                                                                \
    if (DOS123) { STGA(1, (J) + 2, P); }                                      \
    BARLG(); MF(1, 0); GATE;                                                  \
    __builtin_amdgcn_s_barrier();                                             \
  }

  // prologue: A0(0),B1(0),A1(0),B0(0) -> buf0; A0(1),B1(1),A1(1) -> buf1
  STGA(0, 0, 0); STGB(1, 0, 0); STGA(1, 0, 0); STGB(0, 0, 0);
  STGA(0, 1, 1); STGB(1, 1, 1); STGA(1, 1, 1);
  WAITV(6);
  __builtin_amdgcn_s_barrier();

  for (int j = 0; j + 3 < NT; j += 2) {
    GROUP(j, 0, true, true, WAITV(6));
    GROUP(j + 1, 1, true, true, WAITV(6));
  }
  GROUP(NT - 2, 0, true, false, WAITV(0));
  GROUP(NT - 1, 1, false, false, );

  // epilogue
#pragma unroll
  for (int a = 0; a < 2; ++a)
#pragma unroll
    for (int b = 0; b < 2; ++b)
#pragma unroll
      for (int rf = 0; rf < 4; ++rf)
#pragma unroll
        for (int cf = 0; cf < 2; ++cf) {
          float* cp = Cw + (size_t)(m0 + a * 128 + wm * 64 + rf * 16 + (lane >> 4) * 4) * ldc
                         + (n0 + b * 128 + wn * 32 + cf * 16 + fr);
#pragma unroll
          for (int r = 0; r < 4; ++r) cp[(size_t)r * ldc] = acc[a][b][rf][cf][r];
        }
#undef STGA
#undef STGB
#undef LDA
#undef LDB
#undef BARLG
#undef MF
#undef GROUP
}

// ---------------- fp32 add (K-split reduction) ----------------
__global__ __launch_bounds__(256) void add2_kern(
    const float* __restrict__ a, const float* __restrict__ b,
    float* __restrict__ o, int n4) {
  const int i = blockIdx.x * 256 + threadIdx.x;
  if (i >= n4) return;
  const float4 x = ((const float4*)a)[i];
  const float4 y = ((const float4*)b)[i];
  float4 r; r.x = x.x + y.x; r.y = x.y + y.y; r.z = x.z + y.z; r.w = x.w + y.w;
  ((float4*)o)[i] = r;
}

// ---------------- RoPE on Q (folds QK scale), fp32 -> bf16 ----------
__global__ __launch_bounds__(256) void rope_q_kern(
    const float* __restrict__ xqkv, const float* __restrict__ cos_f,
    const float* __restrict__ sin_f, unsigned short* __restrict__ qb) {
  const int gid = blockIdx.x * 256 + threadIdx.x;
  const int e0 = gid * 8;
  const int s = e0 >> 12;
  const int col = e0 & 4095;
  const int i0 = (col & 127) >> 1;
  const float* src = xqkv + (size_t)s * 6144 + col;
  const float4 f1 = *(const float4*)src;
  const float4 f2 = *(const float4*)(src + 4);
  const float4 c  = *(const float4*)(cos_f + s * 64 + i0);
  const float4 sn = *(const float4*)(sin_f + s * 64 + i0);
  u16x8 o;
  o[0] = f2bf((f1.x * c.x - f1.y * sn.x) * QK_SCALE);
  o[1] = f2bf((f1.x * sn.x + f1.y * c.x) * QK_SCALE);
  o[2] = f2bf((f1.z * c.y - f1.w * sn.y) * QK_SCALE);
  o[3] = f2bf((f1.z * sn.y + f1.w * c.y) * QK_SCALE);
  o[4] = f2bf((f2.x * c.z - f2.y * sn.z) * QK_SCALE);
  o[5] = f2bf((f2.x * sn.z + f2.y * c.z) * QK_SCALE);
  o[6] = f2bf((f2.z * c.w - f2.w * sn.w) * QK_SCALE);
  o[7] = f2bf((f2.z * sn.w + f2.w * c.w) * QK_SCALE);
  *(u16x8*)(qb + e0) = o;
}

// ---------------- RoPE on K: fp32 cache out + bf16 attn K -----------
__global__ __launch_bounds__(256) void rope_k_kern(
    const float* __restrict__ xqkv, const float* __restrict__ cos_f,
    const float* __restrict__ sin_f, float* __restrict__ ck, unsigned short* __restrict__ kb) {
  const int gid = blockIdx.x * 256 + threadIdx.x;
  const int e0 = gid * 8;
  const int s = e0 >> 10;
  const int col = e0 & 1023;
  const int i0 = (col & 127) >> 1;
  const float* src = xqkv + (size_t)s * 6144 + 4096 + col;
  const float4 f1 = *(const float4*)src;
  const float4 f2 = *(const float4*)(src + 4);
  const float4 c  = *(const float4*)(cos_f + s * 64 + i0);
  const float4 sn = *(const float4*)(sin_f + s * 64 + i0);
  const float r0 = f1.x * c.x - f1.y * sn.x, r1 = f1.x * sn.x + f1.y * c.x;
  const float r2 = f1.z * c.y - f1.w * sn.y, r3 = f1.z * sn.y + f1.w * c.y;
  const float r4 = f2.x * c.z - f2.y * sn.z, r5 = f2.x * sn.z + f2.y * c.z;
  const float r6 = f2.z * c.w - f2.w * sn.w, r7 = f2.z * sn.w + f2.w * c.w;
  float4 o1; o1.x = r0; o1.y = r1; o1.z = r2; o1.w = r3;
  float4 o2; o2.x = r4; o2.y = r5; o2.z = r6; o2.w = r7;
  *(float4*)(ck + (size_t)s * 1024 + col) = o1;
  *(float4*)(ck + (size_t)s * 1024 + col + 4) = o2;
  u16x8 o;
  o[0] = f2bf(r0); o[1] = f2bf(r1); o[2] = f2bf(r2); o[3] = f2bf(r3);
  o[4] = f2bf(r4); o[5] = f2bf(r5); o[6] = f2bf(r6); o[7] = f2bf(r7);
  *(u16x8*)(kb + (size_t)s * 1024 + col) = o;
}

// ------- V: fp32 cache out (coalesced) + bf16 V^T [NKV*HD][S] -------
__global__ __launch_bounds__(256) void vtrans_kern(
    const float* __restrict__ xqkv, float* __restrict__ cv, unsigned short* __restrict__ vtb) {
  __shared__ float tile[64][65];
  const int st = blockIdx.x * 64;
  const int ct = blockIdx.y * 64;
  const int tid = threadIdx.x;
#pragma unroll
  for (int j = 0; j < 16; ++j) {
    const int lin = tid + j * 256;
    const int si = lin >> 6, ci = lin & 63;
    const float v = xqkv[(size_t)(st + si) * 6144 + 5120 + ct + ci];
    cv[(size_t)(st + si) * 1024 + ct + ci] = v;
    tile[si][ci] = v;
  }
  __syncthreads();
#pragma unroll
  for (int j = 0; j < 16; ++j) {
    const int lin = tid + j * 256;
    const int co = lin >> 6, so = lin & 63;
    vtb[(size_t)(ct + co) * 2048 + st + so] = f2bf(tile[so][co]);
  }
}

// ---------------- flash attention v2 (unchanged from R2) ------------
__global__ __launch_bounds__(256, 2) void attn_fwd2(
    const unsigned short* __restrict__ qb, const unsigned short* __restrict__ kb,
    const unsigned short* __restrict__ vtb, unsigned short* __restrict__ ob) {
  __shared__ unsigned short Ks[2][64 * 128];
  __shared__ unsigned short Vs[2][128 * 64];
  const int bx = blockIdx.x;
  const int h  = blockIdx.y;
  const int hkv = h >> 2;
  const int g = (bx & 1) ? (15 - (bx >> 1)) : (bx >> 1);
  const int qtile = (h < 16) ? g : (15 - g);
  const int q0 = qtile * 128;
  const int tid = threadIdx.x, wave = tid >> 6, lane = tid & 63;
  const int col = lane & 31;
  const int hi  = lane >> 5;
  const int q0w = q0 + wave * 32;
  const int nt = (q0 >> 6) + 2;

  s16x8 qf[8];
  {
    const unsigned short* qrow = qb + (size_t)(q0w + col) * 4096 + h * 128 + hi * 8;
#pragma unroll
    for (int ks = 0; ks < 8; ++ks) qf[ks] = *(const s16x8*)(qrow + ks * 16);
  }

  f32x16 oacc[4] = {};
  float m_s = -3e30f, l_s = 0.0f;

#define STAGE_K(KT, B)                                                        \
  {                                                                           \
    const unsigned short* src = kb + (size_t)((KT) * 64) * 1024 + hkv * 128;  \
    _Pragma("unroll")                                                         \
    for (int i_ = 0; i_ < 4; ++i_) {                                          \
      const int c_ = wave * 4 + i_;                                           \
      const int row_ = c_ * 4 + (lane >> 4);                                  \
      const int cb_ = ((lane & 15) * 16) ^ ((row_ & 7) << 4);                 \
      async_cp16(src + (size_t)row_ * 1024 + (cb_ >> 1), (char*)Ks[B] + c_ * 1024); \
    }                                                                         \
  }
#define STAGE_V(KT, B)                                                        \
  {                                                                           \
    const unsigned short* src = vtb + (size_t)hkv * (128 * 2048) + (KT) * 64; \
    _Pragma("unroll")                                                         \
    for (int i_ = 0; i_ < 4; ++i_) {                                          \
      const int c_ = wave * 4 + i_;                                           \
      const int row_ = c_ * 8 + (lane >> 3);                                  \
      const int cb_ = ((lane & 7) * 16) ^ ((row_ & 7) << 4);                  \
      async_cp16(src + (size_t)row_ * 2048 + (cb_ >> 1), (char*)Vs[B] + c_ * 1024); \
    }                                                                         \
  }

  STAGE_K(0, 0); STAGE_V(0, 0);
  __syncthreads();

  for (int kt = 0; kt < nt; ++kt) {
    const int kv0 = kt * 64;
    const int cur = kt & 1;
    if (kt + 1 < nt) { STAGE_K(kt + 1, cur ^ 1); STAGE_V(kt + 1, cur ^ 1); }

    if (kv0 < q0w + 32) {
      f32x16 s0 = {}, s1 = {};
#pragma unroll
      for (int ks = 0; ks < 8; ++ks) {
        const int gcb = 32 * ks + 16 * hi;
        const int sw = (col & 7) << 4;
        const s16x8 k0 = *(const s16x8*)((const char*)Ks[cur] + col * 256 + (gcb ^ sw));
        const s16x8 k1 = *(const s16x8*)((const char*)Ks[cur] + (32 + col) * 256 + (gcb ^ sw));
        s0 = __builtin_amdgcn_mfma_f32_32x32x16_bf16(k0, qf[ks], s0, 0, 0, 0);
        s1 = __builtin_amdgcn_mfma_f32_32x32x16_bf16(k1, qf[ks], s1, 0, 0, 0);
      }

      const int qg = q0w + col;
      if (kv0 + 63 > q0w) {
#pragma unroll
        for (int r = 0; r < 16; ++r) {
          const int kvl = (r & 3) + 8 * (r >> 2) + 4 * hi;
          if (kv0 + kvl > qg)      s0[r] = -3e30f;
          if (kv0 + 32 + kvl > qg) s1[r] = -3e30f;
        }
      }

      float mxl = s0[0];
#pragma unroll
      for (int r = 1; r < 16; ++r) mxl = fmaxf(mxl, s0[r]);
#pragma unroll
      for (int r = 0; r < 16; ++r) mxl = fmaxf(mxl, s1[r]);
      const float mxf = fmaxf(mxl, __shfl_xor(mxl, 32));
      if (__any(mxf > m_s + 8.0f)) {
        const float mn = fmaxf(m_s, mxf);
        const float scl = __expf(m_s - mn);
        m_s = mn;
        l_s *= scl;
#pragma unroll
        for (int r = 0; r < 16; ++r) {
          const int qq = (r & 3) + 8 * (r >> 2) + 4 * hi;
          const float sr = __int_as_float(
              __builtin_amdgcn_ds_bpermute(qq * 4, __float_as_int(scl)));
          oacc[0][r] *= sr; oacc[1][r] *= sr; oacc[2][r] *= sr; oacc[3][r] *= sr;
        }
      }
      float lsum = 0.0f;
#pragma unroll
      for (int r = 0; r < 16; ++r) {
        s0[r] = __expf(s0[r] - m_s); s1[r] = __expf(s1[r] - m_s);
        lsum += s0[r] + s1[r];
      }
      lsum += __shfl_xor(lsum, 32);
      l_s += lsum;

#define PV_STEP(KS, PP)                                                       \
      {                                                                       \
        const int rb2 = 8 * ((KS) & 1);                                       \
        const uint32_t g0a = cvt_pk_bf16(PP[rb2 + 0], PP[rb2 + 1]);           \
        const uint32_t g0b = cvt_pk_bf16(PP[rb2 + 2], PP[rb2 + 3]);           \
        const uint32_t g1a = cvt_pk_bf16(PP[rb2 + 4], PP[rb2 + 5]);           \
        const uint32_t g1b = cvt_pk_bf16(PP[rb2 + 6], PP[rb2 + 7]);           \
        const uint32_t sa = hi ? g0a : g1a, sb = hi ? g0b : g1b;              \
        const uint32_t ra = (uint32_t)__shfl_xor((int)sa, 32);                \
        const uint32_t rb_ = (uint32_t)__shfl_xor((int)sb, 32);               \
        frag_u af;                                                            \
        af.w[0] = hi ? ra  : g0a; af.w[1] = hi ? rb_ : g0b;                   \
        af.w[2] = hi ? g1a : ra;  af.w[3] = hi ? g1b : rb_;                   \
        const int gcb = 32 * (KS) + 16 * hi;                                  \
        const int vsw = (col & 7) << 4;                                       \
        _Pragma("unroll")                                                     \
        for (int db = 0; db < 4; ++db) {                                      \
          const s16x8 bv = *(const s16x8*)((const char*)Vs[cur] +             \
              (db * 32 + col) * 128 + (gcb ^ vsw));                           \
          oacc[db] = __builtin_amdgcn_mfma_f32_32x32x16_bf16(af.f, bv, oacc[db], 0, 0, 0); \
        }                                                                     \
      }
      PV_STEP(0, s0); PV_STEP(1, s0); PV_STEP(2, s1); PV_STEP(3, s1);
#undef PV_STEP
    }
    __syncthreads();
  }

  const float linv = 1.0f / l_s;
#pragma unroll
  for (int r = 0; r < 16; ++r) {
    const int qq = (r & 3) + 8 * (r >> 2) + 4 * hi;
    const float lr = __int_as_float(
        __builtin_amdgcn_ds_bpermute(qq * 4, __float_as_int(linv)));
    unsigned short* orow = ob + (size_t)(q0w + qq) * 4096 + h * 128 + col;
#pragma unroll
    for (int db = 0; db < 4; ++db)
      orow[db * 32] = f2bf(oacc[db][r] * lr);
  }
#undef STAGE_K
#undef STAGE_V
}

// ------------------------------ launch ------------------------------
extern "C" void kernel_launch(void* const* d_in, const int* in_sizes, int n_in,
                              void* d_out, int out_size, void* d_ws, size_t ws_size,
                              hipStream_t stream) {
  const float* x     = (const float*)d_in[0];
  const float* cos_f = (const float*)d_in[1];
  const float* sin_f = (const float*)d_in[2];
  const float* wq = (const float*)d_in[4];
  const float* wk = (const float*)d_in[5];
  const float* wv = (const float*)d_in[6];
  const float* wo = (const float*)d_in[7];
  float* out = (float*)d_out;

  char* ws = (char*)d_ws;
  unsigned short* xb    = (unsigned short*)(ws);                 // 2048x4096 bf16
  unsigned short* wqkvb = (unsigned short*)(ws + 16777216);      // 6144x4096 bf16
  unsigned short* wob   = (unsigned short*)(ws + 67108864);      // 4096x4096 bf16
  float*          xqkv  = (float*)(ws + 100663296);              // 2048x6144 fp32
  unsigned short* qb    = (unsigned short*)(ws + 150994944);     // 2048x4096 bf16
  unsigned short* kb    = (unsigned short*)(ws + 167772160);     // 2048x1024 bf16
  unsigned short* vtb   = (unsigned short*)(ws + 171966464);     // [8*128][2048] bf16
  unsigned short* attno = (unsigned short*)(ws + 176160768);     // 2048x4096 bf16
  float*          ctmp  = (float*)(ws);                          // 2x 2048x4096 fp32
                                                                 // (xb/wqkvb dead by then)

  cast_f32_bf16<<<dim3(8192), 256, 0, stream>>>(x, xb, 2097152);
  cast_f32_bf16<<<dim3(16384), 256, 0, stream>>>(wq, wqkvb, 4194304);
  cast_f32_bf16<<<dim3(4096), 256, 0, stream>>>(wk, wqkvb + 16777216, 1048576);
  cast_f32_bf16<<<dim3(4096), 256, 0, stream>>>(wv, wqkvb + 20971520, 1048576);
  cast_f32_bf16<<<dim3(16384), 256, 0, stream>>>(wo, wob, 4194304);

  // fused QKV projection: [2048x4096] x [6144x4096]^T -> [2048x6144] fp32
  gemm8p<64, 24, 1><<<dim3(192), 512, 0, stream>>>(xb, wqkvb, xqkv, 6144, 0);

  rope_q_kern<<<dim3(4096), 256, 0, stream>>>(xqkv, cos_f, sin_f, qb);
  rope_k_kern<<<dim3(1024), 256, 0, stream>>>(xqkv, cos_f, sin_f, out + 8388608, kb);
  vtrans_kern<<<dim3(32, 16), 256, 0, stream>>>(xqkv, out + 12582912, vtb);

  (void)hipMemsetAsync(out + 10485760, 0, 8388608, stream);
  (void)hipMemsetAsync(out + 14680064, 0, 8388608, stream);

  attn_fwd2<<<dim3(16, 32), 256, 0, stream>>>(qb, kb, vtb, attno);

  // output projection, K-split x2: [2048x4096] x [4096x4096]^T -> ctmp halves
  gemm8p<32, 16, 2><<<dim3(256), 512, 0, stream>>>(attno, wob, ctmp, 4096, 8388608);
  add2_kern<<<dim3(8192), 256, 0, stream>>>(ctmp, ctmp + 8388608, out, 2097152);
}

// Round 6
// 336.349 us; speedup vs baseline: 1.2851x; 1.0667x over previous
//
#include <hip/hip_runtime.h>
#include <stdint.h>

// Problem constants
#define S_LEN 2048
#define DIM_   4096
#define NH_    32
#define NKV_   8
#define HD_    128
#define QK_SCALE 0.08838834764831845f   // 1/sqrt(128)

typedef __attribute__((ext_vector_type(8)))  short  s16x8;   // 8 bf16 (4 VGPRs) MFMA frag
typedef __attribute__((ext_vector_type(4)))  float  f32x4;   // 16x16 MFMA accum
typedef __attribute__((ext_vector_type(16))) float  f32x16;  // 32x32 MFMA accum
typedef __attribute__((ext_vector_type(8))) unsigned short u16x8;
typedef __attribute__((ext_vector_type(4))) unsigned short u16x4;

union frag_u { s16x8 f; uint32_t w[4]; };

__device__ __forceinline__ unsigned short f2bf(float f) {
  union { float f; uint32_t u; } v; v.f = f;
  return (unsigned short)((v.u + 0x7fffu + ((v.u >> 16) & 1u)) >> 16);   // RNE
}

__device__ __forceinline__ uint32_t cvt_pk_bf16(float lo, float hi2) {
  uint32_t r;
  asm volatile("v_cvt_pk_bf16_f32 %0, %1, %2" : "=v"(r) : "v"(lo), "v"(hi2));
  return r;
}

// async global->LDS, 16B per lane. LDS dest is wave-uniform base + lane*16.
__device__ __forceinline__ void async_cp16(const void* g, void* l) {
  __builtin_amdgcn_global_load_lds(
      (const __attribute__((address_space(1))) unsigned int*)g,
      (__attribute__((address_space(3))) unsigned int*)l, 16, 0, 0);
}

#define WAITV(n) asm volatile("s_waitcnt vmcnt(" #n ")" ::: "memory")

// ---------------- cast fp32 -> bf16 (vectorized x4) ----------------
__global__ __launch_bounds__(256) void cast_f32_bf16(
    const float* __restrict__ src, unsigned short* __restrict__ dst, int n4) {
  const int i = blockIdx.x * 256 + threadIdx.x;
  if (i >= n4) return;
  const float4 v = ((const float4*)src)[i];
  u16x4 o; o[0] = f2bf(v.x); o[1] = f2bf(v.y); o[2] = f2bf(v.z); o[3] = f2bf(v.w);
  ((u16x4*)dst)[i] = o;
}

// ================== 256x256 8-phase GEMM, rotate-slot LDS ==================
// C = A(MxK)*B^T(NxK), bf16 in fp32 out. K stride 4096. M = 2048 (8 tiles).
// 8 waves 2Mx4N; per-wave 128x64 out; BK=64; LDS [buf][A|B][half][128 rows x
// 128 B] = 128 KiB. Conflict-free rotate-slot: stored 16B-slot s=(sl+row)&7.
// ds_read bank-set = (kk*4+g+fr)&7 -> any 8 consecutive lanes cover all 8
// sets exactly once. Staging keeps linear global_load_lds dest; inverse perm
// sl=((tid&7)-(tid>>3))&7 applied to the GLOBAL source (both-sides rule).
// Phases/k-tile: ds_reads 12/4/8/0 (both B halves held in regs - no re-read);
// stages B0(j+1)@p0->buf^1, A0(j+2)@p1, B1(j+2)@p2, A1(j+2)@p3 -> buf.
// Single gate vmcnt(6) at p3 (3 half-tiles in flight).
template <int NT, int NTN, int KSPLIT>
__global__ __launch_bounds__(512, 2) void gemm8p(
    const unsigned short* __restrict__ A, const unsigned short* __restrict__ B,
    float* __restrict__ C, int ldc, size_t cHalfOff) {
  __shared__ unsigned short lds[65536];   // 128 KiB

  const int bid = blockIdx.x;
  const int xcd = bid & 7, ii = bid >> 3;
  const int percomb = (NTN * KSPLIT) / 8;
  const int idx = xcd * percomb + (ii >> 3);
  const int n = idx / KSPLIT, kh = idx % KSPLIT;
  const int m = ii & 7;
  const int m0 = m * 256, n0 = n * 256;
  const int kbase = kh * (NT * 64);
  float* Cw = C + (size_t)kh * cHalfOff;

  const int tid = threadIdx.x;
  const int wave = tid >> 6, lane = tid & 63;
  const int wm = wave >> 2, wn = wave & 3;
  const int fr = lane & 15, g = lane >> 4;

  // ---- fragment LDS byte offsets (within a 16 KiB half region) ----
  int offA[4][2], offB[2][2];
#pragma unroll
  for (int rf = 0; rf < 4; ++rf)
#pragma unroll
    for (int kk = 0; kk < 2; ++kk)
      offA[rf][kk] = (wm * 64 + rf * 16 + fr) * 128 + (((kk * 4 + g + fr) & 7) << 4);
#pragma unroll
  for (int cf = 0; cf < 2; ++cf)
#pragma unroll
    for (int kk = 0; kk < 2; ++kk)
      offB[cf][kk] = (wn * 32 + cf * 16 + fr) * 128 + (((kk * 4 + g + fr) & 7) << 4);

  // ---- staging source offsets (inverse rotate-slot on global source) ----
  const int srk = (((tid & 7) - (tid >> 3)) & 7) * 8;   // k-element offset
  uint32_t aoff[2][2], boff[2][2];                      // [half][chunk]
#pragma unroll
  for (int h = 0; h < 2; ++h)
#pragma unroll
    for (int i = 0; i < 2; ++i) {
      const int row = h * 128 + i * 64 + (tid >> 3);
      aoff[h][i] = (uint32_t)((m0 + row) * 4096 + kbase + srk);
      boff[h][i] = (uint32_t)((n0 + row) * 4096 + kbase + srk);
    }

  f32x4 acc[2][2][4][2] = {};
  s16x8 fa[4][2], fbA[2][2], fbB[2][2];

#define STGA(H, T, BUF)                                                       \
  { _Pragma("unroll") for (int i_ = 0; i_ < 2; ++i_)                          \
      async_cp16(A + aoff[H][i_] + (size_t)(T) * 64,                          \
                 (char*)lds + (BUF) * 65536 + (H) * 16384 + i_ * 8192 + tid * 16); }
#define STGB(H, T, BUF)                                                       \
  { _Pragma("unroll") for (int i_ = 0; i_ < 2; ++i_)                          \
      async_cp16(B + boff[H][i_] + (size_t)(T) * 64,                          \
                 (char*)lds + (BUF) * 65536 + 32768 + (H) * 16384 + i_ * 8192 + tid * 16); }
#define LDA(AA, P)                                                            \
  { _Pragma("unroll") for (int rf = 0; rf < 4; ++rf)                          \
      _Pragma("unroll") for (int kk = 0; kk < 2; ++kk)                        \
        fa[rf][kk] = *(const s16x8*)((char*)lds + (P) * 65536 +               \
                                     (AA) * 16384 + offA[rf][kk]); }
#define LDBH(FB, BB, P)                                                       \
  { _Pragma("unroll") for (int cf = 0; cf < 2; ++cf)                          \
      _Pragma("unroll") for (int kk = 0; kk < 2; ++kk)                        \
        FB[cf][kk] = *(const s16x8*)((char*)lds + (P) * 65536 + 32768 +       \
                                     (BB) * 16384 + offB[cf][kk]); }
#define BARLG()                                                               \
  __builtin_amdgcn_s_barrier();                                               \
  asm volatile("s_waitcnt lgkmcnt(0)" ::: "memory");                          \
  __builtin_amdgcn_sched_barrier(0);
#define MF(AA, BB, FB)                                                        \
  __builtin_amdgcn_s_setprio(1);                                              \
  { _Pragma("unroll") for (int kk = 0; kk < 2; ++kk)                          \
      _Pragma("unroll") for (int rf = 0; rf < 4; ++rf)                        \
        _Pragma("unroll") for (int cf = 0; cf < 2; ++cf)                      \
          acc[AA][BB][rf][cf] = __builtin_amdgcn_mfma_f32_16x16x32_bf16(      \
              fa[rf][kk], FB[cf][kk], acc[AA][BB][rf][cf], 0, 0, 0); }        \
  __builtin_amdgcn_s_setprio(0);

#define GROUP(J, P, DOS0, DOS123, GATE)                                       \
  {                                                                           \
    LDA(0, P); LDBH(fbA, 0, P);                                               \
    if (DOS0) { STGB(0, (J) + 1, (P) ^ 1); }                                  \
    BARLG(); MF(0, 0, fbA);                                                   \
    __builtin_amdgcn_s_barrier();                                             \
    LDBH(fbB, 1, P);                                                          \
    if (DOS123) { STGA(0, (J) + 2, P); }                                      \
    BARLG(); MF(0, 1, fbB);                                                   \
    __builtin_amdgcn_s_barrier();                                             \
    LDA(1, P);                                                                \
    if (DOS123) { STGB(1, (J) + 2, P); }                                      \
    BARLG(); MF(1, 1, fbB);                                                   \
    __builtin_amdgcn_s_barrier();                                             \
    if (DOS123) { STGA(1, (J) + 2, P); }                                      \
    BARLG(); MF(1, 0, fbA); GATE;                                             \
    __builtin_amdgcn_s_barrier();                                             \
  }

  // prologue: tile0 -> buf0 (A0,B1,A1,B0); tile1 A0,B1,A1 -> buf1
  STGA(0, 0, 0); STGB(1, 0, 0); STGA(1, 0, 0); STGB(0, 0, 0);
  STGA(0, 1, 1); STGB(1, 1, 1); STGA(1, 1, 1);
  WAITV(6);
  __builtin_amdgcn_s_barrier();

  for (int j = 0; j + 3 < NT; j += 2) {
    GROUP(j, 0, true, true, WAITV(6));
    GROUP(j + 1, 1, true, true, WAITV(6));
  }
  GROUP(NT - 2, 0, true, false, WAITV(0));
  GROUP(NT - 1, 1, false, false, );

  // epilogue
#pragma unroll
  for (int a = 0; a < 2; ++a)
#pragma unroll
    for (int b = 0; b < 2; ++b)
#pragma unroll
      for (int rf = 0; rf < 4; ++rf)
#pragma unroll
        for (int cf = 0; cf < 2; ++cf) {
          float* cp = Cw + (size_t)(m0 + a * 128 + wm * 64 + rf * 16 + (lane >> 4) * 4) * ldc
                         + (n0 + b * 128 + wn * 32 + cf * 16 + fr);
#pragma unroll
          for (int r = 0; r < 4; ++r) cp[(size_t)r * ldc] = acc[a][b][rf][cf][r];
        }
#undef STGA
#undef STGB
#undef LDA
#undef LDBH
#undef BARLG
#undef MF
#undef GROUP
}

// ---------------- fp32 add (K-split reduction) ----------------
__global__ __launch_bounds__(256) void add2_kern(
    const float* __restrict__ a, const float* __restrict__ b,
    float* __restrict__ o, int n4) {
  const int i = blockIdx.x * 256 + threadIdx.x;
  if (i >= n4) return;
  const float4 x = ((const float4*)a)[i];
  const float4 y = ((const float4*)b)[i];
  float4 r; r.x = x.x + y.x; r.y = x.y + y.y; r.z = x.z + y.z; r.w = x.w + y.w;
  ((float4*)o)[i] = r;
}

// ---------------- RoPE on Q (folds QK scale), fp32 -> bf16 ----------
__global__ __launch_bounds__(256) void rope_q_kern(
    const float* __restrict__ xqkv, const float* __restrict__ cos_f,
    const float* __restrict__ sin_f, unsigned short* __restrict__ qb) {
  const int gid = blockIdx.x * 256 + threadIdx.x;
  const int e0 = gid * 8;
  const int s = e0 >> 12;
  const int col = e0 & 4095;
  const int i0 = (col & 127) >> 1;
  const float* src = xqkv + (size_t)s * 6144 + col;
  const float4 f1 = *(const float4*)src;
  const float4 f2 = *(const float4*)(src + 4);
  const float4 c  = *(const float4*)(cos_f + s * 64 + i0);
  const float4 sn = *(const float4*)(sin_f + s * 64 + i0);
  u16x8 o;
  o[0] = f2bf((f1.x * c.x - f1.y * sn.x) * QK_SCALE);
  o[1] = f2bf((f1.x * sn.x + f1.y * c.x) * QK_SCALE);
  o[2] = f2bf((f1.z * c.y - f1.w * sn.y) * QK_SCALE);
  o[3] = f2bf((f1.z * sn.y + f1.w * c.y) * QK_SCALE);
  o[4] = f2bf((f2.x * c.z - f2.y * sn.z) * QK_SCALE);
  o[5] = f2bf((f2.x * sn.z + f2.y * c.z) * QK_SCALE);
  o[6] = f2bf((f2.z * c.w - f2.w * sn.w) * QK_SCALE);
  o[7] = f2bf((f2.z * sn.w + f2.w * c.w) * QK_SCALE);
  *(u16x8*)(qb + e0) = o;
}

// ---------------- RoPE on K: fp32 cache out + bf16 attn K -----------
__global__ __launch_bounds__(256) void rope_k_kern(
    const float* __restrict__ xqkv, const float* __restrict__ cos_f,
    const float* __restrict__ sin_f, float* __restrict__ ck, unsigned short* __restrict__ kb) {
  const int gid = blockIdx.x * 256 + threadIdx.x;
  const int e0 = gid * 8;
  const int s = e0 >> 10;
  const int col = e0 & 1023;
  const int i0 = (col & 127) >> 1;
  const float* src = xqkv + (size_t)s * 6144 + 4096 + col;
  const float4 f1 = *(const float4*)src;
  const float4 f2 = *(const float4*)(src + 4);
  const float4 c  = *(const float4*)(cos_f + s * 64 + i0);
  const float4 sn = *(const float4*)(sin_f + s * 64 + i0);
  const float r0 = f1.x * c.x - f1.y * sn.x, r1 = f1.x * sn.x + f1.y * c.x;
  const float r2 = f1.z * c.y - f1.w * sn.y, r3 = f1.z * sn.y + f1.w * c.y;
  const float r4 = f2.x * c.z - f2.y * sn.z, r5 = f2.x * sn.z + f2.y * c.z;
  const float r6 = f2.z * c.w - f2.w * sn.w, r7 = f2.z * sn.w + f2.w * c.w;
  float4 o1; o1.x = r0; o1.y = r1; o1.z = r2; o1.w = r3;
  float4 o2; o2.x = r4; o2.y = r5; o2.z = r6; o2.w = r7;
  *(float4*)(ck + (size_t)s * 1024 + col) = o1;
  *(float4*)(ck + (size_t)s * 1024 + col + 4) = o2;
  u16x8 o;
  o[0] = f2bf(r0); o[1] = f2bf(r1); o[2] = f2bf(r2); o[3] = f2bf(r3);
  o[4] = f2bf(r4); o[5] = f2bf(r5); o[6] = f2bf(r6); o[7] = f2bf(r7);
  *(u16x8*)(kb + (size_t)s * 1024 + col) = o;
}

// ------- V: fp32 cache out (coalesced) + bf16 V^T [NKV*HD][S] -------
__global__ __launch_bounds__(256) void vtrans_kern(
    const float* __restrict__ xqkv, float* __restrict__ cv, unsigned short* __restrict__ vtb) {
  __shared__ float tile[64][65];
  const int st = blockIdx.x * 64;
  const int ct = blockIdx.y * 64;
  const int tid = threadIdx.x;
#pragma unroll
  for (int j = 0; j < 16; ++j) {
    const int lin = tid + j * 256;
    const int si = lin >> 6, ci = lin & 63;
    const float v = xqkv[(size_t)(st + si) * 6144 + 5120 + ct + ci];
    cv[(size_t)(st + si) * 1024 + ct + ci] = v;
    tile[si][ci] = v;
  }
  __syncthreads();
#pragma unroll
  for (int j = 0; j < 16; ++j) {
    const int lin = tid + j * 256;
    const int co = lin >> 6, so = lin & 63;
    vtb[(size_t)(ct + co) * 2048 + st + so] = f2bf(tile[so][co]);
  }
}

// ---------------- flash attention v2 (unchanged) --------------------
__global__ __launch_bounds__(256, 2) void attn_fwd2(
    const unsigned short* __restrict__ qb, const unsigned short* __restrict__ kb,
    const unsigned short* __restrict__ vtb, unsigned short* __restrict__ ob) {
  __shared__ unsigned short Ks[2][64 * 128];
  __shared__ unsigned short Vs[2][128 * 64];
  const int bx = blockIdx.x;
  const int h  = blockIdx.y;
  const int hkv = h >> 2;
  const int g = (bx & 1) ? (15 - (bx >> 1)) : (bx >> 1);
  const int qtile = (h < 16) ? g : (15 - g);
  const int q0 = qtile * 128;
  const int tid = threadIdx.x, wave = tid >> 6, lane = tid & 63;
  const int col = lane & 31;
  const int hi  = lane >> 5;
  const int q0w = q0 + wave * 32;
  const int nt = (q0 >> 6) + 2;

  s16x8 qf[8];
  {
    const unsigned short* qrow = qb + (size_t)(q0w + col) * 4096 + h * 128 + hi * 8;
#pragma unroll
    for (int ks = 0; ks < 8; ++ks) qf[ks] = *(const s16x8*)(qrow + ks * 16);
  }

  f32x16 oacc[4] = {};
  float m_s = -3e30f, l_s = 0.0f;

#define STAGE_K(KT, B)                                                        \
  {                                                                           \
    const unsigned short* src = kb + (size_t)((KT) * 64) * 1024 + hkv * 128;  \
    _Pragma("unroll")                                                         \
    for (int i_ = 0; i_ < 4; ++i_) {                                          \
      const int c_ = wave * 4 + i_;                                           \
      const int row_ = c_ * 4 + (lane >> 4);                                  \
      const int cb_ = ((lane & 15) * 16) ^ ((row_ & 7) << 4);                 \
      async_cp16(src + (size_t)row_ * 1024 + (cb_ >> 1), (char*)Ks[B] + c_ * 1024); \
    }                                                                         \
  }
#define STAGE_V(KT, B)                                                        \
  {                                                                           \
    const unsigned short* src = vtb + (size_t)hkv * (128 * 2048) + (KT) * 64; \
    _Pragma("unroll")                                                         \
    for (int i_ = 0; i_ < 4; ++i_) {                                          \
      const int c_ = wave * 4 + i_;                                           \
      const int row_ = c_ * 8 + (lane >> 3);                                  \
      const int cb_ = ((lane & 7) * 16) ^ ((row_ & 7) << 4);                  \
      async_cp16(src + (size_t)row_ * 2048 + (cb_ >> 1), (char*)Vs[B] + c_ * 1024); \
    }                                                                         \
  }

  STAGE_K(0, 0); STAGE_V(0, 0);
  __syncthreads();

  for (int kt = 0; kt < nt; ++kt) {
    const int kv0 = kt * 64;
    const int cur = kt & 1;
    if (kt + 1 < nt) { STAGE_K(kt + 1, cur ^ 1); STAGE_V(kt + 1, cur ^ 1); }

    if (kv0 < q0w + 32) {
      f32x16 s0 = {}, s1 = {};
#pragma unroll
      for (int ks = 0; ks < 8; ++ks) {
        const int gcb = 32 * ks + 16 * hi;
        const int sw = (col & 7) << 4;
        const s16x8 k0 = *(const s16x8*)((const char*)Ks[cur] + col * 256 + (gcb ^ sw));
        const s16x8 k1 = *(const s16x8*)((const char*)Ks[cur] + (32 + col) * 256 + (gcb ^ sw));
        s0 = __builtin_amdgcn_mfma_f32_32x32x16_bf16(k0, qf[ks], s0, 0, 0, 0);
        s1 = __builtin_amdgcn_mfma_f32_32x32x16_bf16(k1, qf[ks], s1, 0, 0, 0);
      }

      const int qg = q0w + col;
      if (kv0 + 63 > q0w) {
#pragma unroll
        for (int r = 0; r < 16; ++r) {
          const int kvl = (r & 3) + 8 * (r >> 2) + 4 * hi;
          if (kv0 + kvl > qg)      s0[r] = -3e30f;
          if (kv0 + 32 + kvl > qg) s1[r] = -3e30f;
        }
      }

      float mxl = s0[0];
#pragma unroll
      for (int r = 1; r < 16; ++r) mxl = fmaxf(mxl, s0[r]);
#pragma unroll
      for (int r = 0; r < 16; ++r) mxl = fmaxf(mxl, s1[r]);
      const float mxf = fmaxf(mxl, __shfl_xor(mxl, 32));
      if (__any(mxf > m_s + 8.0f)) {
        const float mn = fmaxf(m_s, mxf);
        const float scl = __expf(m_s - mn);
        m_s = mn;
        l_s *= scl;
#pragma unroll
        for (int r = 0; r < 16; ++r) {
          const int qq = (r & 3) + 8 * (r >> 2) + 4 * hi;
          const float sr = __int_as_float(
              __builtin_amdgcn_ds_bpermute(qq * 4, __float_as_int(scl)));
          oacc[0][r] *= sr; oacc[1][r] *= sr; oacc[2][r] *= sr; oacc[3][r] *= sr;
        }
      }
      float lsum = 0.0f;
#pragma unroll
      for (int r = 0; r < 16; ++r) {
        s0[r] = __expf(s0[r] - m_s); s1[r] = __expf(s1[r] - m_s);
        lsum += s0[r] + s1[r];
      }
      lsum += __shfl_xor(lsum, 32);
      l_s += lsum;

#define PV_STEP(KS, PP)                                                       \
      {                                                                       \
        const int rb2 = 8 * ((KS) & 1);                                       \
        const uint32_t g0a = cvt_pk_bf16(PP[rb2 + 0], PP[rb2 + 1]);           \
        const uint32_t g0b = cvt_pk_bf16(PP[rb2 + 2], PP[rb2 + 3]);           \
        const uint32_t g1a = cvt_pk_bf16(PP[rb2 + 4], PP[rb2 + 5]);           \
        const uint32_t g1b = cvt_pk_bf16(PP[rb2 + 6], PP[rb2 + 7]);           \
        const uint32_t sa = hi ? g0a : g1a, sb = hi ? g0b : g1b;              \
        const uint32_t ra = (uint32_t)__shfl_xor((int)sa, 32);                \
        const uint32_t rb_ = (uint32_t)__shfl_xor((int)sb, 32);               \
        frag_u af;                                                            \
        af.w[0] = hi ? ra  : g0a; af.w[1] = hi ? rb_ : g0b;                   \
        af.w[2] = hi ? g1a : ra;  af.w[3] = hi ? g1b : rb_;                   \
        const int gcb = 32 * (KS) + 16 * hi;                                  \
        const int vsw = (col & 7) << 4;                                       \
        _Pragma("unroll")                                                     \
        for (int db = 0; db < 4; ++db) {                                      \
          const s16x8 bv = *(const s16x8*)((const char*)Vs[cur] +             \
              (db * 32 + col) * 128 + (gcb ^ vsw));                           \
          oacc[db] = __builtin_amdgcn_mfma_f32_32x32x16_bf16(af.f, bv, oacc[db], 0, 0, 0); \
        }                                                                     \
      }
      PV_STEP(0, s0); PV_STEP(1, s0); PV_STEP(2, s1); PV_STEP(3, s1);
#undef PV_STEP
    }
    __syncthreads();
  }

  const float linv = 1.0f / l_s;
#pragma unroll
  for (int r = 0; r < 16; ++r) {
    const int qq = (r & 3) + 8 * (r >> 2) + 4 * hi;
    const float lr = __int_as_float(
        __builtin_amdgcn_ds_bpermute(qq * 4, __float_as_int(linv)));
    unsigned short* orow = ob + (size_t)(q0w + qq) * 4096 + h * 128 + col;
#pragma unroll
    for (int db = 0; db < 4; ++db)
      orow[db * 32] = f2bf(oacc[db][r] * lr);
  }
#undef STAGE_K
#undef STAGE_V
}

// ------------------------------ launch ------------------------------
extern "C" void kernel_launch(void* const* d_in, const int* in_sizes, int n_in,
                              void* d_out, int out_size, void* d_ws, size_t ws_size,
                              hipStream_t stream) {
  const float* x     = (const float*)d_in[0];
  const float* cos_f = (const float*)d_in[1];
  const float* sin_f = (const float*)d_in[2];
  const float* wq = (const float*)d_in[4];
  const float* wk = (const float*)d_in[5];
  const float* wv = (const float*)d_in[6];
  const float* wo = (const float*)d_in[7];
  float* out = (float*)d_out;

  char* ws = (char*)d_ws;
  unsigned short* xb    = (unsigned short*)(ws);                 // 2048x4096 bf16
  unsigned short* wqkvb = (unsigned short*)(ws + 16777216);      // 6144x4096 bf16
  unsigned short* wob   = (unsigned short*)(ws + 67108864);      // 4096x4096 bf16
  float*          xqkv  = (float*)(ws + 100663296);              // 2048x6144 fp32
  unsigned short* qb    = (unsigned short*)(ws + 150994944);     // 2048x4096 bf16
  unsigned short* kb    = (unsigned short*)(ws + 167772160);     // 2048x1024 bf16
  unsigned short* vtb   = (unsigned short*)(ws + 171966464);     // [8*128][2048] bf16
  unsigned short* attno = (unsigned short*)(ws + 176160768);     // 2048x4096 bf16
  float*          ctmp  = (float*)(ws);                          // 2x 2048x4096 fp32
                                                                 // (xb/wqkvb dead by then)

  cast_f32_bf16<<<dim3(8192), 256, 0, stream>>>(x, xb, 2097152);
  cast_f32_bf16<<<dim3(16384), 256, 0, stream>>>(wq, wqkvb, 4194304);
  cast_f32_bf16<<<dim3(4096), 256, 0, stream>>>(wk, wqkvb + 16777216, 1048576);
  cast_f32_bf16<<<dim3(4096), 256, 0, stream>>>(wv, wqkvb + 20971520, 1048576);
  cast_f32_bf16<<<dim3(16384), 256, 0, stream>>>(wo, wob, 4194304);

  // fused QKV projection: [2048x4096] x [6144x4096]^T -> [2048x6144] fp32
  gemm8p<64, 24, 1><<<dim3(192), 512, 0, stream>>>(xb, wqkvb, xqkv, 6144, 0);

  rope_q_kern<<<dim3(4096), 256, 0, stream>>>(xqkv, cos_f, sin_f, qb);
  rope_k_kern<<<dim3(1024), 256, 0, stream>>>(xqkv, cos_f, sin_f, out + 8388608, kb);
  vtrans_kern<<<dim3(32, 16), 256, 0, stream>>>(xqkv, out + 12582912, vtb);

  (void)hipMemsetAsync(out + 10485760, 0, 8388608, stream);
  (void)hipMemsetAsync(out + 14680064, 0, 8388608, stream);

  attn_fwd2<<<dim3(16, 32), 256, 0, stream>>>(qb, kb, vtb, attno);

  // output projection, K-split x2: [2048x4096] x [4096x4096]^T -> ctmp halves
  gemm8p<32, 16, 2><<<dim3(256), 512, 0, stream>>>(attno, wob, ctmp, 4096, 8388608);
  add2_kern<<<dim3(8192), 256, 0, stream>>>(ctmp, ctmp + 8388608, out, 2097152);
}

// Round 7
// 328.815 us; speedup vs baseline: 1.3145x; 1.0229x over previous
//
#include <hip/hip_runtime.h>
#include <stdint.h>

// Problem constants
#define S_LEN 2048
#define DIM_   4096
#define NH_    32
#define NKV_   8
#define HD_    128
#define QK_SCALE 0.08838834764831845f   // 1/sqrt(128)

typedef __attribute__((ext_vector_type(8)))  short  s16x8;   // 8 bf16 (4 VGPRs) MFMA frag
typedef __attribute__((ext_vector_type(4)))  float  f32x4;   // 16x16 MFMA accum
typedef __attribute__((ext_vector_type(16))) float  f32x16;  // 32x32 MFMA accum
typedef __attribute__((ext_vector_type(8))) unsigned short u16x8;
typedef __attribute__((ext_vector_type(4))) unsigned short u16x4;

union frag_u { s16x8 f; uint32_t w[4]; };

__device__ __forceinline__ unsigned short f2bf(float f) {
  union { float f; uint32_t u; } v; v.f = f;
  return (unsigned short)((v.u + 0x7fffu + ((v.u >> 16) & 1u)) >> 16);   // RNE
}

__device__ __forceinline__ uint32_t cvt_pk_bf16(float lo, float hi2) {
  uint32_t r;
  asm volatile("v_cvt_pk_bf16_f32 %0, %1, %2" : "=v"(r) : "v"(lo), "v"(hi2));
  return r;
}

// async global->LDS, 16B per lane. LDS dest is wave-uniform base + lane*16.
__device__ __forceinline__ void async_cp16(const void* g, void* l) {
  __builtin_amdgcn_global_load_lds(
      (const __attribute__((address_space(1))) unsigned int*)g,
      (__attribute__((address_space(3))) unsigned int*)l, 16, 0, 0);
}

#define WAITV(n) asm volatile("s_waitcnt vmcnt(" #n ")" ::: "memory")

// ---------------- cast fp32 -> bf16 (vectorized x4) ----------------
__global__ __launch_bounds__(256) void cast_f32_bf16(
    const float* __restrict__ src, unsigned short* __restrict__ dst, int n4) {
  const int i = blockIdx.x * 256 + threadIdx.x;
  if (i >= n4) return;
  const float4 v = ((const float4*)src)[i];
  u16x4 o; o[0] = f2bf(v.x); o[1] = f2bf(v.y); o[2] = f2bf(v.z); o[3] = f2bf(v.w);
  ((u16x4*)dst)[i] = o;
}

// ============ 128 x (2*HALF_N) 2-phase GEMM, rotate-slot LDS ===============
// C = A(MxK)*B^T(NxK), bf16 in fp32 out. K=4096 (NT=64 BK=64 tiles).
// Grid MUST be 16 m-tiles x (N/(2*HALF_N)) n-tiles = 256 blocks (full chip).
// 8 waves (2wm x 4wn); per-wave out: M=64 (32 from each A-half, rf=2),
// N = 2*HALF_N/4 (cf=NCF per B-half) -> every wave active in every phase.
// LDS per buf: A halves 2x8KB + B halves 2x(HALF_N*128B). Rotate-slot
// (verified conflict-free in R6): stored 16B-slot s=(sl+row)&7; inverse perm
// on the global staging source; any 8 consecutive lanes hit 8 distinct slots.
// Phases per k-tile J (buf P=J&1):
//   p0: LDA(0) 4 + LDB(both halves) 4*NCF ds_reads; stage A1(J+1)->P^1;
//       barrier; lgkmcnt(0); MFMA(AA=0) 2*NCF*2*2
//   p1: LDA(1) 4; stage A0,B0,B1(J+2)->P; barrier; lgkmcnt(0); MFMA(AA=1);
//       gate vmcnt(1+2*LB); barrier
// Ledger (loads/thread: A-half=1, B-half=LB): gate leaves exactly
// {A0,B0,B1(J+2)} in flight; tile J+1 proven resident at group J+1 entry.
template <int NT, int HALF_N, int NCF, int LB>
__global__ __launch_bounds__(512, 2) void gemmF(
    const unsigned short* __restrict__ A, const unsigned short* __restrict__ B,
    float* __restrict__ C, int ldc) {
  constexpr int HB   = HALF_N * 128;        // bytes per B half region
  constexpr int BUFB = 16384 + 2 * HB;      // bytes per buffer
  __shared__ unsigned char lds[2 * BUFB];

  const int bid = blockIdx.x;
  const int idx = (bid & 7) * 32 + (bid >> 3);   // XCD-contiguous
  const int m = idx & 15, n = idx >> 4;
  const int m0 = m * 128, n0 = n * (2 * HALF_N);

  const int tid = threadIdx.x;
  const int wave = tid >> 6, lane = tid & 63;
  const int wm = wave >> 2, wn = wave & 3;
  const int fr = lane & 15, g = lane >> 4;

  // fragment LDS offsets within a half region (rotate-slot read side)
  int offA[2][2], offB[NCF][2];
#pragma unroll
  for (int rf = 0; rf < 2; ++rf)
#pragma unroll
    for (int kk = 0; kk < 2; ++kk)
      offA[rf][kk] = (wm * 32 + rf * 16 + fr) * 128 + (((kk * 4 + g + fr) & 7) << 4);
#pragma unroll
  for (int cf = 0; cf < NCF; ++cf)
#pragma unroll
    for (int kk = 0; kk < 2; ++kk)
      offB[cf][kk] = (wn * NCF * 16 + cf * 16 + fr) * 128 + (((kk * 4 + g + fr) & 7) << 4);

  // staging source offsets (inverse rotate-slot on global source)
  const int srk = (((tid & 7) - (tid >> 3)) & 7) * 8;
  uint32_t aoff[2];        // [A half]
  uint32_t boff[2][LB];    // [B half][chunk]
#pragma unroll
  for (int h = 0; h < 2; ++h) {
    aoff[h] = (uint32_t)((m0 + h * 64 + (tid >> 3)) * 4096 + srk);
#pragma unroll
    for (int i = 0; i < LB; ++i)
      boff[h][i] = (uint32_t)((n0 + h * HALF_N + i * 64 + (tid >> 3)) * 4096 + srk);
  }

  f32x4 acc[2][2][2][NCF] = {};   // [AA][rf][Bhalf][cf]
  s16x8 fa[2][2], fb[2][NCF][2];

#define STGA(H, T, BUF)                                                       \
  async_cp16(A + aoff[H] + (size_t)(T) * 64,                                  \
             (char*)lds + (BUF) * BUFB + (H) * 8192 + tid * 16);
#define STGB(H, T, BUF)                                                       \
  { _Pragma("unroll") for (int i_ = 0; i_ < LB; ++i_)                         \
      async_cp16(B + boff[H][i_] + (size_t)(T) * 64,                          \
                 (char*)lds + (BUF) * BUFB + 16384 + (H) * HB + i_ * 8192 + tid * 16); }
#define LDA(AA, P)                                                            \
  { _Pragma("unroll") for (int rf = 0; rf < 2; ++rf)                          \
      _Pragma("unroll") for (int kk = 0; kk < 2; ++kk)                        \
        fa[rf][kk] = *(const s16x8*)((char*)lds + (P) * BUFB +                \
                                     (AA) * 8192 + offA[rf][kk]); }
#define LDBF(P)                                                               \
  { _Pragma("unroll") for (int h_ = 0; h_ < 2; ++h_)                          \
      _Pragma("unroll") for (int cf = 0; cf < NCF; ++cf)                      \
        _Pragma("unroll") for (int kk = 0; kk < 2; ++kk)                      \
          fb[h_][cf][kk] = *(const s16x8*)((char*)lds + (P) * BUFB + 16384 +  \
                                           h_ * HB + offB[cf][kk]); }
#define BARLG()                                                               \
  __builtin_amdgcn_s_barrier();                                               \
  asm volatile("s_waitcnt lgkmcnt(0)" ::: "memory");                          \
  __builtin_amdgcn_sched_barrier(0);
#define MF(AA)                                                                \
  __builtin_amdgcn_s_setprio(1);                                              \
  { _Pragma("unroll") for (int kk = 0; kk < 2; ++kk)                          \
      _Pragma("unroll") for (int rf = 0; rf < 2; ++rf)                        \
        _Pragma("unroll") for (int h_ = 0; h_ < 2; ++h_)                      \
          _Pragma("unroll") for (int cf = 0; cf < NCF; ++cf)                  \
            acc[AA][rf][h_][cf] = __builtin_amdgcn_mfma_f32_16x16x32_bf16(    \
                fa[rf][kk], fb[h_][cf][kk], acc[AA][rf][h_][cf], 0, 0, 0); }  \
  __builtin_amdgcn_s_setprio(0);
#define GATEN do { if constexpr (LB == 3) { WAITV(7); } else { WAITV(5); } } while (0)

#define GROUPF(J, P, DO1, DO2, GATE)                                          \
  {                                                                           \
    LDA(0, P); LDBF(P);                                                       \
    if (DO1) { STGA(1, (J) + 1, (P) ^ 1); }                                   \
    BARLG(); MF(0);                                                           \
    __builtin_amdgcn_s_barrier();                                             \
    LDA(1, P);                                                                \
    if (DO2) { STGA(0, (J) + 2, P); STGB(0, (J) + 2, P); STGB(1, (J) + 2, P); } \
    BARLG(); MF(1);                                                           \
    GATE;                                                                     \
    __builtin_amdgcn_s_barrier();                                             \
  }

  // prologue: tile0 complete -> buf0; tile1 A0,B0,B1 -> buf1 (A1(1) at grp0 p0)
  STGA(0, 0, 0); STGB(0, 0, 0); STGB(1, 0, 0); STGA(1, 0, 0);
  STGA(0, 1, 1); STGB(0, 1, 1); STGB(1, 1, 1);
  GATEN;
  __builtin_amdgcn_s_barrier();

  for (int j = 0; j + 3 < NT; j += 2) {
    GROUPF(j, 0, true, true, GATEN);
    GROUPF(j + 1, 1, true, true, GATEN);
  }
  GROUPF(NT - 2, 0, true, false, WAITV(0));
  GROUPF(NT - 1, 1, false, false, );

  // epilogue: C[m0 + AA*64 + wm*32 + rf*16 + g*4 + r][n0 + h*HALF_N + wn*NCF*16 + cf*16 + fr]
#pragma unroll
  for (int AA = 0; AA < 2; ++AA)
#pragma unroll
    for (int rf = 0; rf < 2; ++rf)
#pragma unroll
      for (int h = 0; h < 2; ++h)
#pragma unroll
        for (int cf = 0; cf < NCF; ++cf) {
          float* cp = C + (size_t)(m0 + AA * 64 + wm * 32 + rf * 16 + g * 4) * ldc
                        + (n0 + h * HALF_N + wn * NCF * 16 + cf * 16 + fr);
#pragma unroll
          for (int r = 0; r < 4; ++r) cp[(size_t)r * ldc] = acc[AA][rf][h][cf][r];
        }
#undef STGA
#undef STGB
#undef LDA
#undef LDBF
#undef BARLG
#undef MF
#undef GATEN
#undef GROUPF
}

// ---------------- RoPE on Q (folds QK scale), fp32 -> bf16 ----------
__global__ __launch_bounds__(256) void rope_q_kern(
    const float* __restrict__ xqkv, const float* __restrict__ cos_f,
    const float* __restrict__ sin_f, unsigned short* __restrict__ qb) {
  const int gid = blockIdx.x * 256 + threadIdx.x;
  const int e0 = gid * 8;
  const int s = e0 >> 12;
  const int col = e0 & 4095;
  const int i0 = (col & 127) >> 1;
  const float* src = xqkv + (size_t)s * 6144 + col;
  const float4 f1 = *(const float4*)src;
  const float4 f2 = *(const float4*)(src + 4);
  const float4 c  = *(const float4*)(cos_f + s * 64 + i0);
  const float4 sn = *(const float4*)(sin_f + s * 64 + i0);
  u16x8 o;
  o[0] = f2bf((f1.x * c.x - f1.y * sn.x) * QK_SCALE);
  o[1] = f2bf((f1.x * sn.x + f1.y * c.x) * QK_SCALE);
  o[2] = f2bf((f1.z * c.y - f1.w * sn.y) * QK_SCALE);
  o[3] = f2bf((f1.z * sn.y + f1.w * c.y) * QK_SCALE);
  o[4] = f2bf((f2.x * c.z - f2.y * sn.z) * QK_SCALE);
  o[5] = f2bf((f2.x * sn.z + f2.y * c.z) * QK_SCALE);
  o[6] = f2bf((f2.z * c.w - f2.w * sn.w) * QK_SCALE);
  o[7] = f2bf((f2.z * sn.w + f2.w * c.w) * QK_SCALE);
  *(u16x8*)(qb + e0) = o;
}

// ---------------- RoPE on K: fp32 cache out + bf16 attn K -----------
__global__ __launch_bounds__(256) void rope_k_kern(
    const float* __restrict__ xqkv, const float* __restrict__ cos_f,
    const float* __restrict__ sin_f, float* __restrict__ ck, unsigned short* __restrict__ kb) {
  const int gid = blockIdx.x * 256 + threadIdx.x;
  const int e0 = gid * 8;
  const int s = e0 >> 10;
  const int col = e0 & 1023;
  const int i0 = (col & 127) >> 1;
  const float* src = xqkv + (size_t)s * 6144 + 4096 + col;
  const float4 f1 = *(const float4*)src;
  const float4 f2 = *(const float4*)(src + 4);
  const float4 c  = *(const float4*)(cos_f + s * 64 + i0);
  const float4 sn = *(const float4*)(sin_f + s * 64 + i0);
  const float r0 = f1.x * c.x - f1.y * sn.x, r1 = f1.x * sn.x + f1.y * c.x;
  const float r2 = f1.z * c.y - f1.w * sn.y, r3 = f1.z * sn.y + f1.w * c.y;
  const float r4 = f2.x * c.z - f2.y * sn.z, r5 = f2.x * sn.z + f2.y * c.z;
  const float r6 = f2.z * c.w - f2.w * sn.w, r7 = f2.z * sn.w + f2.w * c.w;
  float4 o1; o1.x = r0; o1.y = r1; o1.z = r2; o1.w = r3;
  float4 o2; o2.x = r4; o2.y = r5; o2.z = r6; o2.w = r7;
  *(float4*)(ck + (size_t)s * 1024 + col) = o1;
  *(float4*)(ck + (size_t)s * 1024 + col + 4) = o2;
  u16x8 o;
  o[0] = f2bf(r0); o[1] = f2bf(r1); o[2] = f2bf(r2); o[3] = f2bf(r3);
  o[4] = f2bf(r4); o[5] = f2bf(r5); o[6] = f2bf(r6); o[7] = f2bf(r7);
  *(u16x8*)(kb + (size_t)s * 1024 + col) = o;
}

// ------- V: fp32 cache out (coalesced) + bf16 V^T [NKV*HD][S] -------
__global__ __launch_bounds__(256) void vtrans_kern(
    const float* __restrict__ xqkv, float* __restrict__ cv, unsigned short* __restrict__ vtb) {
  __shared__ float tile[64][65];
  const int st = blockIdx.x * 64;
  const int ct = blockIdx.y * 64;
  const int tid = threadIdx.x;
#pragma unroll
  for (int j = 0; j < 16; ++j) {
    const int lin = tid + j * 256;
    const int si = lin >> 6, ci = lin & 63;
    const float v = xqkv[(size_t)(st + si) * 6144 + 5120 + ct + ci];
    cv[(size_t)(st + si) * 1024 + ct + ci] = v;
    tile[si][ci] = v;
  }
  __syncthreads();
#pragma unroll
  for (int j = 0; j < 16; ++j) {
    const int lin = tid + j * 256;
    const int co = lin >> 6, so = lin & 63;
    vtb[(size_t)(ct + co) * 2048 + st + so] = f2bf(tile[so][co]);
  }
}

// ---------------- flash attention v2 (unchanged) --------------------
__global__ __launch_bounds__(256, 2) void attn_fwd2(
    const unsigned short* __restrict__ qb, const unsigned short* __restrict__ kb,
    const unsigned short* __restrict__ vtb, unsigned short* __restrict__ ob) {
  __shared__ unsigned short Ks[2][64 * 128];
  __shared__ unsigned short Vs[2][128 * 64];
  const int bx = blockIdx.x;
  const int h  = blockIdx.y;
  const int hkv = h >> 2;
  const int g = (bx & 1) ? (15 - (bx >> 1)) : (bx >> 1);
  const int qtile = (h < 16) ? g : (15 - g);
  const int q0 = qtile * 128;
  const int tid = threadIdx.x, wave = tid >> 6, lane = tid & 63;
  const int col = lane & 31;
  const int hi  = lane >> 5;
  const int q0w = q0 + wave * 32;
  const int nt = (q0 >> 6) + 2;

  s16x8 qf[8];
  {
    const unsigned short* qrow = qb + (size_t)(q0w + col) * 4096 + h * 128 + hi * 8;
#pragma unroll
    for (int ks = 0; ks < 8; ++ks) qf[ks] = *(const s16x8*)(qrow + ks * 16);
  }

  f32x16 oacc[4] = {};
  float m_s = -3e30f, l_s = 0.0f;

#define STAGE_K(KT, B)                                                        \
  {                                                                           \
    const unsigned short* src = kb + (size_t)((KT) * 64) * 1024 + hkv * 128;  \
    _Pragma("unroll")                                                         \
    for (int i_ = 0; i_ < 4; ++i_) {                                          \
      const int c_ = wave * 4 + i_;                                           \
      const int row_ = c_ * 4 + (lane >> 4);                                  \
      const int cb_ = ((lane & 15) * 16) ^ ((row_ & 7) << 4);                 \
      async_cp16(src + (size_t)row_ * 1024 + (cb_ >> 1), (char*)Ks[B] + c_ * 1024); \
    }                                                                         \
  }
#define STAGE_V(KT, B)                                                        \
  {                                                                           \
    const unsigned short* src = vtb + (size_t)hkv * (128 * 2048) + (KT) * 64; \
    _Pragma("unroll")                                                         \
    for (int i_ = 0; i_ < 4; ++i_) {                                          \
      const int c_ = wave * 4 + i_;                                           \
      const int row_ = c_ * 8 + (lane >> 3);                                  \
      const int cb_ = ((lane & 7) * 16) ^ ((row_ & 7) << 4);                  \
      async_cp16(src + (size_t)row_ * 2048 + (cb_ >> 1), (char*)Vs[B] + c_ * 1024); \
    }                                                                         \
  }

  STAGE_K(0, 0); STAGE_V(0, 0);
  __syncthreads();

  for (int kt = 0; kt < nt; ++kt) {
    const int kv0 = kt * 64;
    const int cur = kt & 1;
    if (kt + 1 < nt) { STAGE_K(kt + 1, cur ^ 1); STAGE_V(kt + 1, cur ^ 1); }

    if (kv0 < q0w + 32) {
      f32x16 s0 = {}, s1 = {};
#pragma unroll
      for (int ks = 0; ks < 8; ++ks) {
        const int gcb = 32 * ks + 16 * hi;
        const int sw = (col & 7) << 4;
        const s16x8 k0 = *(const s16x8*)((const char*)Ks[cur] + col * 256 + (gcb ^ sw));
        const s16x8 k1 = *(const s16x8*)((const char*)Ks[cur] + (32 + col) * 256 + (gcb ^ sw));
        s0 = __builtin_amdgcn_mfma_f32_32x32x16_bf16(k0, qf[ks], s0, 0, 0, 0);
        s1 = __builtin_amdgcn_mfma_f32_32x32x16_bf16(k1, qf[ks], s1, 0, 0, 0);
      }

      const int qg = q0w + col;
      if (kv0 + 63 > q0w) {
#pragma unroll
        for (int r = 0; r < 16; ++r) {
          const int kvl = (r & 3) + 8 * (r >> 2) + 4 * hi;
          if (kv0 + kvl > qg)      s0[r] = -3e30f;
          if (kv0 + 32 + kvl > qg) s1[r] = -3e30f;
        }
      }

      float mxl = s0[0];
#pragma unroll
      for (int r = 1; r < 16; ++r) mxl = fmaxf(mxl, s0[r]);
#pragma unroll
      for (int r = 0; r < 16; ++r) mxl = fmaxf(mxl, s1[r]);
      const float mxf = fmaxf(mxl, __shfl_xor(mxl, 32));
      if (__any(mxf > m_s + 8.0f)) {
        const float mn = fmaxf(m_s, mxf);
        const float scl = __expf(m_s - mn);
        m_s = mn;
        l_s *= scl;
#pragma unroll
        for (int r = 0; r < 16; ++r) {
          const int qq = (r & 3) + 8 * (r >> 2) + 4 * hi;
          const float sr = __int_as_float(
              __builtin_amdgcn_ds_bpermute(qq * 4, __float_as_int(scl)));
          oacc[0][r] *= sr; oacc[1][r] *= sr; oacc[2][r] *= sr; oacc[3][r] *= sr;
        }
      }
      float lsum = 0.0f;
#pragma unroll
      for (int r = 0; r < 16; ++r) {
        s0[r] = __expf(s0[r] - m_s); s1[r] = __expf(s1[r] - m_s);
        lsum += s0[r] + s1[r];
      }
      lsum += __shfl_xor(lsum, 32);
      l_s += lsum;

#define PV_STEP(KS, PP)                                                       \
      {                                                                       \
        const int rb2 = 8 * ((KS) & 1);                                       \
        const uint32_t g0a = cvt_pk_bf16(PP[rb2 + 0], PP[rb2 + 1]);           \
        const uint32_t g0b = cvt_pk_bf16(PP[rb2 + 2], PP[rb2 + 3]);           \
        const uint32_t g1a = cvt_pk_bf16(PP[rb2 + 4], PP[rb2 + 5]);           \
        const uint32_t g1b = cvt_pk_bf16(PP[rb2 + 6], PP[rb2 + 7]);           \
        const uint32_t sa = hi ? g0a : g1a, sb = hi ? g0b : g1b;              \
        const uint32_t ra = (uint32_t)__shfl_xor((int)sa, 32);                \
        const uint32_t rb_ = (uint32_t)__shfl_xor((int)sb, 32);               \
        frag_u af;                                                            \
        af.w[0] = hi ? ra  : g0a; af.w[1] = hi ? rb_ : g0b;                   \
        af.w[2] = hi ? g1a : ra;  af.w[3] = hi ? g1b : rb_;                   \
        const int gcb = 32 * (KS) + 16 * hi;                                  \
        const int vsw = (col & 7) << 4;                                       \
        _Pragma("unroll")                                                     \
        for (int db = 0; db < 4; ++db) {                                      \
          const s16x8 bv = *(const s16x8*)((const char*)Vs[cur] +             \
              (db * 32 + col) * 128 + (gcb ^ vsw));                           \
          oacc[db] = __builtin_amdgcn_mfma_f32_32x32x16_bf16(af.f, bv, oacc[db], 0, 0, 0); \
        }                                                                     \
      }
      PV_STEP(0, s0); PV_STEP(1, s0); PV_STEP(2, s1); PV_STEP(3, s1);
#undef PV_STEP
    }
    __syncthreads();
  }

  const float linv = 1.0f / l_s;
#pragma unroll
  for (int r = 0; r < 16; ++r) {
    const int qq = (r & 3) + 8 * (r >> 2) + 4 * hi;
    const float lr = __int_as_float(
        __builtin_amdgcn_ds_bpermute(qq * 4, __float_as_int(linv)));
    unsigned short* orow = ob + (size_t)(q0w + qq) * 4096 + h * 128 + col;
#pragma unroll
    for (int db = 0; db < 4; ++db)
      orow[db * 32] = f2bf(oacc[db][r] * lr);
  }
#undef STAGE_K
#undef STAGE_V
}

// ------------------------------ launch ------------------------------
extern "C" void kernel_launch(void* const* d_in, const int* in_sizes, int n_in,
                              void* d_out, int out_size, void* d_ws, size_t ws_size,
                              hipStream_t stream) {
  const float* x     = (const float*)d_in[0];
  const float* cos_f = (const float*)d_in[1];
  const float* sin_f = (const float*)d_in[2];
  const float* wq = (const float*)d_in[4];
  const float* wk = (const float*)d_in[5];
  const float* wv = (const float*)d_in[6];
  const float* wo = (const float*)d_in[7];
  float* out = (float*)d_out;

  char* ws = (char*)d_ws;
  unsigned short* xb    = (unsigned short*)(ws);                 // 2048x4096 bf16
  unsigned short* wqkvb = (unsigned short*)(ws + 16777216);      // 6144x4096 bf16
  unsigned short* wob   = (unsigned short*)(ws + 67108864);      // 4096x4096 bf16
  float*          xqkv  = (float*)(ws + 100663296);              // 2048x6144 fp32
  unsigned short* qb    = (unsigned short*)(ws + 150994944);     // 2048x4096 bf16
  unsigned short* kb    = (unsigned short*)(ws + 167772160);     // 2048x1024 bf16
  unsigned short* vtb   = (unsigned short*)(ws + 171966464);     // [8*128][2048] bf16
  unsigned short* attno = (unsigned short*)(ws + 176160768);     // 2048x4096 bf16

  cast_f32_bf16<<<dim3(8192), 256, 0, stream>>>(x, xb, 2097152);
  cast_f32_bf16<<<dim3(16384), 256, 0, stream>>>(wq, wqkvb, 4194304);
  cast_f32_bf16<<<dim3(4096), 256, 0, stream>>>(wk, wqkvb + 16777216, 1048576);
  cast_f32_bf16<<<dim3(4096), 256, 0, stream>>>(wv, wqkvb + 20971520, 1048576);
  cast_f32_bf16<<<dim3(16384), 256, 0, stream>>>(wo, wob, 4194304);

  // fused QKV projection: [2048x4096] x [6144x4096]^T -> [2048x6144] fp32
  // 16 m-tiles x 16 n-tiles of 128x384 = 256 blocks (full chip)
  gemmF<64, 192, 3, 3><<<dim3(256), 512, 0, stream>>>(xb, wqkvb, xqkv, 6144);

  rope_q_kern<<<dim3(4096), 256, 0, stream>>>(xqkv, cos_f, sin_f, qb);
  rope_k_kern<<<dim3(1024), 256, 0, stream>>>(xqkv, cos_f, sin_f, out + 8388608, kb);
  vtrans_kern<<<dim3(32, 16), 256, 0, stream>>>(xqkv, out + 12582912, vtb);

  (void)hipMemsetAsync(out + 10485760, 0, 8388608, stream);
  (void)hipMemsetAsync(out + 14680064, 0, 8388608, stream);

  attn_fwd2<<<dim3(16, 32), 256, 0, stream>>>(qb, kb, vtb, attno);

  // output projection: [2048x4096] x [4096x4096]^T -> d_out directly
  // 16 x 16 tiles of 128x256 = 256 blocks, full K (no split, no add pass)
  gemmF<64, 128, 2, 2><<<dim3(256), 512, 0, stream>>>(attno, wob, out, 4096);
}

// Round 10
// 327.536 us; speedup vs baseline: 1.3197x; 1.0039x over previous
//
#include <hip/hip_runtime.h>
#include <stdint.h>

// Problem constants
#define S_LEN 2048
#define DIM_   4096
#define NH_    32
#define NKV_   8
#define HD_    128
#define QK_SCALE 0.08838834764831845f   // 1/sqrt(128)

typedef __attribute__((ext_vector_type(8)))  short  s16x8;   // 8 bf16 (4 VGPRs) MFMA frag
typedef __attribute__((ext_vector_type(4)))  float  f32x4;   // 16x16 MFMA accum
typedef __attribute__((ext_vector_type(16))) float  f32x16;  // 32x32 MFMA accum
typedef __attribute__((ext_vector_type(8))) unsigned short u16x8;
typedef __attribute__((ext_vector_type(4))) unsigned short u16x4;

union frag_u { s16x8 f; uint32_t w[4]; };

__device__ __forceinline__ unsigned short f2bf(float f) {
  union { float f; uint32_t u; } v; v.f = f;
  return (unsigned short)((v.u + 0x7fffu + ((v.u >> 16) & 1u)) >> 16);   // RNE
}

__device__ __forceinline__ uint32_t cvt_pk_bf16(float lo, float hi2) {
  uint32_t r;
  asm volatile("v_cvt_pk_bf16_f32 %0, %1, %2" : "=v"(r) : "v"(lo), "v"(hi2));
  return r;
}

// async global->LDS, 16B per lane. LDS dest is wave-uniform base + lane*16.
__device__ __forceinline__ void async_cp16(const void* g, void* l) {
  __builtin_amdgcn_global_load_lds(
      (const __attribute__((address_space(1))) unsigned int*)g,
      (__attribute__((address_space(3))) unsigned int*)l, 16, 0, 0);
}

#define WAITV(n) asm volatile("s_waitcnt vmcnt(" #n ")" ::: "memory")

// ---------------- cast fp32 -> bf16 (vectorized x4) ----------------
__global__ __launch_bounds__(256) void cast_f32_bf16(
    const float* __restrict__ src, unsigned short* __restrict__ dst, int n4) {
  const int i = blockIdx.x * 256 + threadIdx.x;
  if (i >= n4) return;
  const float4 v = ((const float4*)src)[i];
  u16x4 o; o[0] = f2bf(v.x); o[1] = f2bf(v.y); o[2] = f2bf(v.z); o[3] = f2bf(v.w);
  ((u16x4*)dst)[i] = o;
}

// ============ 128 x (2*HALF_N) 2-phase GEMM, rotate-slot LDS ===============
// C = A(MxK)*B^T(NxK), bf16 in fp32 out. K=4096 (NT=64 BK=64 tiles).
// Grid MUST be 16 m-tiles x (N/(2*HALF_N)) n-tiles = 256 blocks (full chip).
// 8 waves (2wm x 4wn); per-wave out: M=64 (32 from each A-half, rf=2),
// N = 2*HALF_N/4 (cf=NCF per B-half) -> every wave active in every phase.
// LDS per buf: A halves 2x8KB + B halves 2x(HALF_N*128B). Rotate-slot
// (verified conflict-free in R6): stored 16B-slot s=(sl+row)&7; inverse perm
// on the global staging source; any 8 consecutive lanes hit 8 distinct slots.
// Phases per k-tile J (buf P=J&1):
//   p0: LDA(0) 4 + LDB(both halves) 4*NCF ds_reads; stage A1(J+1)->P^1;
//       barrier; lgkmcnt(0); MFMA(AA=0) 2*NCF*2*2
//   p1: LDA(1) 4; stage A0,B0,B1(J+2)->P; barrier; lgkmcnt(0); MFMA(AA=1);
//       gate vmcnt(1+2*LB); barrier
// Ledger (loads/thread: A-half=1, B-half=LB): gate leaves exactly
// {A0,B0,B1(J+2)} in flight; tile J+1 proven resident at group J+1 entry.
template <int NT, int HALF_N, int NCF, int LB>
__global__ __launch_bounds__(512, 2) void gemmF(
    const unsigned short* __restrict__ A, const unsigned short* __restrict__ B,
    float* __restrict__ C, int ldc) {
  constexpr int HB   = HALF_N * 128;        // bytes per B half region
  constexpr int BUFB = 16384 + 2 * HB;      // bytes per buffer
  __shared__ unsigned char lds[2 * BUFB];

  const int bid = blockIdx.x;
  const int idx = (bid & 7) * 32 + (bid >> 3);   // XCD-contiguous
  const int m = idx & 15, n = idx >> 4;
  const int m0 = m * 128, n0 = n * (2 * HALF_N);

  const int tid = threadIdx.x;
  const int wave = tid >> 6, lane = tid & 63;
  const int wm = wave >> 2, wn = wave & 3;
  const int fr = lane & 15, g = lane >> 4;

  // fragment LDS offsets within a half region (rotate-slot read side)
  int offA[2][2], offB[NCF][2];
#pragma unroll
  for (int rf = 0; rf < 2; ++rf)
#pragma unroll
    for (int kk = 0; kk < 2; ++kk)
      offA[rf][kk] = (wm * 32 + rf * 16 + fr) * 128 + (((kk * 4 + g + fr) & 7) << 4);
#pragma unroll
  for (int cf = 0; cf < NCF; ++cf)
#pragma unroll
    for (int kk = 0; kk < 2; ++kk)
      offB[cf][kk] = (wn * NCF * 16 + cf * 16 + fr) * 128 + (((kk * 4 + g + fr) & 7) << 4);

  // staging source offsets (inverse rotate-slot on global source)
  const int srk = (((tid & 7) - (tid >> 3)) & 7) * 8;
  uint32_t aoff[2];        // [A half]
  uint32_t boff[2][LB];    // [B half][chunk]
#pragma unroll
  for (int h = 0; h < 2; ++h) {
    aoff[h] = (uint32_t)((m0 + h * 64 + (tid >> 3)) * 4096 + srk);
#pragma unroll
    for (int i = 0; i < LB; ++i)
      boff[h][i] = (uint32_t)((n0 + h * HALF_N + i * 64 + (tid >> 3)) * 4096 + srk);
  }

  f32x4 acc[2][2][2][NCF] = {};   // [AA][rf][Bhalf][cf]
  s16x8 fa[2][2], fb[2][NCF][2];

#define STGA(H, T, BUF)                                                       \
  async_cp16(A + aoff[H] + (size_t)(T) * 64,                                  \
             (char*)lds + (BUF) * BUFB + (H) * 8192 + tid * 16);
#define STGB(H, T, BUF)                                                       \
  { _Pragma("unroll") for (int i_ = 0; i_ < LB; ++i_)                         \
      async_cp16(B + boff[H][i_] + (size_t)(T) * 64,                          \
                 (char*)lds + (BUF) * BUFB + 16384 + (H) * HB + i_ * 8192 + tid * 16); }
#define LDA(AA, P)                                                            \
  { _Pragma("unroll") for (int rf = 0; rf < 2; ++rf)                          \
      _Pragma("unroll") for (int kk = 0; kk < 2; ++kk)                        \
        fa[rf][kk] = *(const s16x8*)((char*)lds + (P) * BUFB +                \
                                     (AA) * 8192 + offA[rf][kk]); }
#define LDBF(P)                                                               \
  { _Pragma("unroll") for (int h_ = 0; h_ < 2; ++h_)                          \
      _Pragma("unroll") for (int cf = 0; cf < NCF; ++cf)                      \
        _Pragma("unroll") for (int kk = 0; kk < 2; ++kk)                      \
          fb[h_][cf][kk] = *(const s16x8*)((char*)lds + (P) * BUFB + 16384 +  \
                                           h_ * HB + offB[cf][kk]); }
#define BARLG()                                                               \
  __builtin_amdgcn_s_barrier();                                               \
  asm volatile("s_waitcnt lgkmcnt(0)" ::: "memory");                          \
  __builtin_amdgcn_sched_barrier(0);
#define MF(AA)                                                                \
  __builtin_amdgcn_s_setprio(1);                                              \
  { _Pragma("unroll") for (int kk = 0; kk < 2; ++kk)                          \
      _Pragma("unroll") for (int rf = 0; rf < 2; ++rf)                        \
        _Pragma("unroll") for (int h_ = 0; h_ < 2; ++h_)                      \
          _Pragma("unroll") for (int cf = 0; cf < NCF; ++cf)                  \
            acc[AA][rf][h_][cf] = __builtin_amdgcn_mfma_f32_16x16x32_bf16(    \
                fa[rf][kk], fb[h_][cf][kk], acc[AA][rf][h_][cf], 0, 0, 0); }  \
  __builtin_amdgcn_s_setprio(0);
#define GATEN do { if constexpr (LB == 3) { WAITV(7); } else { WAITV(5); } } while (0)

#define GROUPF(J, P, DO1, DO2, GATE)                                          \
  {                                                                           \
    LDA(0, P); LDBF(P);                                                       \
    if (DO1) { STGA(1, (J) + 1, (P) ^ 1); }                                   \
    BARLG(); MF(0);                                                           \
    __builtin_amdgcn_s_barrier();                                             \
    LDA(1, P);                                                                \
    if (DO2) { STGA(0, (J) + 2, P); STGB(0, (J) + 2, P); STGB(1, (J) + 2, P); } \
    BARLG(); MF(1);                                                           \
    GATE;                                                                     \
    __builtin_amdgcn_s_barrier();                                             \
  }

  // prologue: tile0 complete -> buf0; tile1 A0,B0,B1 -> buf1 (A1(1) at grp0 p0)
  STGA(0, 0, 0); STGB(0, 0, 0); STGB(1, 0, 0); STGA(1, 0, 0);
  STGA(0, 1, 1); STGB(0, 1, 1); STGB(1, 1, 1);
  GATEN;
  __builtin_amdgcn_s_barrier();

  for (int j = 0; j + 3 < NT; j += 2) {
    GROUPF(j, 0, true, true, GATEN);
    GROUPF(j + 1, 1, true, true, GATEN);
  }
  GROUPF(NT - 2, 0, true, false, WAITV(0));
  GROUPF(NT - 1, 1, false, false, );

  // epilogue: C[m0 + AA*64 + wm*32 + rf*16 + g*4 + r][n0 + h*HALF_N + wn*NCF*16 + cf*16 + fr]
#pragma unroll
  for (int AA = 0; AA < 2; ++AA)
#pragma unroll
    for (int rf = 0; rf < 2; ++rf)
#pragma unroll
      for (int h = 0; h < 2; ++h)
#pragma unroll
        for (int cf = 0; cf < NCF; ++cf) {
          float* cp = C + (size_t)(m0 + AA * 64 + wm * 32 + rf * 16 + g * 4) * ldc
                        + (n0 + h * HALF_N + wn * NCF * 16 + cf * 16 + fr);
#pragma unroll
          for (int r = 0; r < 4; ++r) cp[(size_t)r * ldc] = acc[AA][rf][h][cf][r];
        }
#undef STGA
#undef STGB
#undef LDA
#undef LDBF
#undef BARLG
#undef MF
#undef GATEN
#undef GROUPF
}

// ---------------- RoPE on Q (folds QK scale), fp32 -> bf16 ----------
__global__ __launch_bounds__(256) void rope_q_kern(
    const float* __restrict__ xqkv, const float* __restrict__ cos_f,
    const float* __restrict__ sin_f, unsigned short* __restrict__ qb) {
  const int gid = blockIdx.x * 256 + threadIdx.x;
  const int e0 = gid * 8;
  const int s = e0 >> 12;
  const int col = e0 & 4095;
  const int i0 = (col & 127) >> 1;
  const float* src = xqkv + (size_t)s * 6144 + col;
  const float4 f1 = *(const float4*)src;
  const float4 f2 = *(const float4*)(src + 4);
  const float4 c  = *(const float4*)(cos_f + s * 64 + i0);
  const float4 sn = *(const float4*)(sin_f + s * 64 + i0);
  u16x8 o;
  o[0] = f2bf((f1.x * c.x - f1.y * sn.x) * QK_SCALE);
  o[1] = f2bf((f1.x * sn.x + f1.y * c.x) * QK_SCALE);
  o[2] = f2bf((f1.z * c.y - f1.w * sn.y) * QK_SCALE);
  o[3] = f2bf((f1.z * sn.y + f1.w * c.y) * QK_SCALE);
  o[4] = f2bf((f2.x * c.z - f2.y * sn.z) * QK_SCALE);
  o[5] = f2bf((f2.x * sn.z + f2.y * c.z) * QK_SCALE);
  o[6] = f2bf((f2.z * c.w - f2.w * sn.w) * QK_SCALE);
  o[7] = f2bf((f2.z * sn.w + f2.w * c.w) * QK_SCALE);
  *(u16x8*)(qb + e0) = o;
}

// ---------------- RoPE on K: fp32 cache out + bf16 attn K -----------
__global__ __launch_bounds__(256) void rope_k_kern(
    const float* __restrict__ xqkv, const float* __restrict__ cos_f,
    const float* __restrict__ sin_f, float* __restrict__ ck, unsigned short* __restrict__ kb) {
  const int gid = blockIdx.x * 256 + threadIdx.x;
  const int e0 = gid * 8;
  const int s = e0 >> 10;
  const int col = e0 & 1023;
  const int i0 = (col & 127) >> 1;
  const float* src = xqkv + (size_t)s * 6144 + 4096 + col;
  const float4 f1 = *(const float4*)src;
  const float4 f2 = *(const float4*)(src + 4);
  const float4 c  = *(const float4*)(cos_f + s * 64 + i0);
  const float4 sn = *(const float4*)(sin_f + s * 64 + i0);
  const float r0 = f1.x * c.x - f1.y * sn.x, r1 = f1.x * sn.x + f1.y * c.x;
  const float r2 = f1.z * c.y - f1.w * sn.y, r3 = f1.z * sn.y + f1.w * c.y;
  const float r4 = f2.x * c.z - f2.y * sn.z, r5 = f2.x * sn.z + f2.y * c.z;
  const float r6 = f2.z * c.w - f2.w * sn.w, r7 = f2.z * sn.w + f2.w * c.w;
  float4 o1; o1.x = r0; o1.y = r1; o1.z = r2; o1.w = r3;
  float4 o2; o2.x = r4; o2.y = r5; o2.z = r6; o2.w = r7;
  *(float4*)(ck + (size_t)s * 1024 + col) = o1;
  *(float4*)(ck + (size_t)s * 1024 + col + 4) = o2;
  u16x8 o;
  o[0] = f2bf(r0); o[1] = f2bf(r1); o[2] = f2bf(r2); o[3] = f2bf(r3);
  o[4] = f2bf(r4); o[5] = f2bf(r5); o[6] = f2bf(r6); o[7] = f2bf(r7);
  *(u16x8*)(kb + (size_t)s * 1024 + col) = o;
}

// ------- V: fp32 cache out (coalesced) + bf16 V^T [NKV*HD][S] -------
__global__ __launch_bounds__(256) void vtrans_kern(
    const float* __restrict__ xqkv, float* __restrict__ cv, unsigned short* __restrict__ vtb) {
  __shared__ float tile[64][65];
  const int st = blockIdx.x * 64;
  const int ct = blockIdx.y * 64;
  const int tid = threadIdx.x;
#pragma unroll
  for (int j = 0; j < 16; ++j) {
    const int lin = tid + j * 256;
    const int si = lin >> 6, ci = lin & 63;
    const float v = xqkv[(size_t)(st + si) * 6144 + 5120 + ct + ci];
    cv[(size_t)(st + si) * 1024 + ct + ci] = v;
    tile[si][ci] = v;
  }
  __syncthreads();
#pragma unroll
  for (int j = 0; j < 16; ++j) {
    const int lin = tid + j * 256;
    const int co = lin >> 6, so = lin & 63;
    vtb[(size_t)(ct + co) * 2048 + st + so] = f2bf(tile[so][co]);
  }
}

// ---------------- flash attention v2 (unchanged) --------------------
__global__ __launch_bounds__(256, 2) void attn_fwd2(
    const unsigned short* __restrict__ qb, const unsigned short* __restrict__ kb,
    const unsigned short* __restrict__ vtb, unsigned short* __restrict__ ob) {
  __shared__ unsigned short Ks[2][64 * 128];
  __shared__ unsigned short Vs[2][128 * 64];
  const int bx = blockIdx.x;
  const int h  = blockIdx.y;
  const int hkv = h >> 2;
  const int g = (bx & 1) ? (15 - (bx >> 1)) : (bx >> 1);
  const int qtile = (h < 16) ? g : (15 - g);
  const int q0 = qtile * 128;
  const int tid = threadIdx.x, wave = tid >> 6, lane = tid & 63;
  const int col = lane & 31;
  const int hi  = lane >> 5;
  const int q0w = q0 + wave * 32;
  const int nt = (q0 >> 6) + 2;

  s16x8 qf[8];
  {
    const unsigned short* qrow = qb + (size_t)(q0w + col) * 4096 + h * 128 + hi * 8;
#pragma unroll
    for (int ks = 0; ks < 8; ++ks) qf[ks] = *(const s16x8*)(qrow + ks * 16);
  }

  f32x16 oacc[4] = {};
  float m_s = -3e30f, l_s = 0.0f;

#define STAGE_K(KT, B)                                                        \
  {                                                                           \
    const unsigned short* src = kb + (size_t)((KT) * 64) * 1024 + hkv * 128;  \
    _Pragma("unroll")                                                         \
    for (int i_ = 0; i_ < 4; ++i_) {                                          \
      const int c_ = wave * 4 + i_;                                           \
      const int row_ = c_ * 4 + (lane >> 4);                                  \
      const int cb_ = ((lane & 15) * 16) ^ ((row_ & 7) << 4);                 \
      async_cp16(src + (size_t)row_ * 1024 + (cb_ >> 1), (char*)Ks[B] + c_ * 1024); \
    }                                                                         \
  }
#define STAGE_V(KT, B)                                                        \
  {                                                                           \
    const unsigned short* src = vtb + (size_t)hkv * (128 * 2048) + (KT) * 64; \
    _Pragma("unroll")                                                         \
    for (int i_ = 0; i_ < 4; ++i_) {                                          \
      const int c_ = wave * 4 + i_;                                           \
      const int row_ = c_ * 8 + (lane >> 3);                                  \
      const int cb_ = ((lane & 7) * 16) ^ ((row_ & 7) << 4);                  \
      async_cp16(src + (size_t)row_ * 2048 + (cb_ >> 1), (char*)Vs[B] + c_ * 1024); \
    }                                                                         \
  }

  STAGE_K(0, 0); STAGE_V(0, 0);
  __syncthreads();

  for (int kt = 0; kt < nt; ++kt) {
    const int kv0 = kt * 64;
    const int cur = kt & 1;
    if (kt + 1 < nt) { STAGE_K(kt + 1, cur ^ 1); STAGE_V(kt + 1, cur ^ 1); }

    if (kv0 < q0w + 32) {
      f32x16 s0 = {}, s1 = {};
#pragma unroll
      for (int ks = 0; ks < 8; ++ks) {
        const int gcb = 32 * ks + 16 * hi;
        const int sw = (col & 7) << 4;
        const s16x8 k0 = *(const s16x8*)((const char*)Ks[cur] + col * 256 + (gcb ^ sw));
        const s16x8 k1 = *(const s16x8*)((const char*)Ks[cur] + (32 + col) * 256 + (gcb ^ sw));
        s0 = __builtin_amdgcn_mfma_f32_32x32x16_bf16(k0, qf[ks], s0, 0, 0, 0);
        s1 = __builtin_amdgcn_mfma_f32_32x32x16_bf16(k1, qf[ks], s1, 0, 0, 0);
      }

      const int qg = q0w + col;
      if (kv0 + 63 > q0w) {
#pragma unroll
        for (int r = 0; r < 16; ++r) {
          const int kvl = (r & 3) + 8 * (r >> 2) + 4 * hi;
          if (kv0 + kvl > qg)      s0[r] = -3e30f;
          if (kv0 + 32 + kvl > qg) s1[r] = -3e30f;
        }
      }

      float mxl = s0[0];
#pragma unroll
      for (int r = 1; r < 16; ++r) mxl = fmaxf(mxl, s0[r]);
#pragma unroll
      for (int r = 0; r < 16; ++r) mxl = fmaxf(mxl, s1[r]);
      const float mxf = fmaxf(mxl, __shfl_xor(mxl, 32));
      if (__any(mxf > m_s + 8.0f)) {
        const float mn = fmaxf(m_s, mxf);
        const float scl = __expf(m_s - mn);
        m_s = mn;
        l_s *= scl;
#pragma unroll
        for (int r = 0; r < 16; ++r) {
          const int qq = (r & 3) + 8 * (r >> 2) + 4 * hi;
          const float sr = __int_as_float(
              __builtin_amdgcn_ds_bpermute(qq * 4, __float_as_int(scl)));
          oacc[0][r] *= sr; oacc[1][r] *= sr; oacc[2][r] *= sr; oacc[3][r] *= sr;
        }
      }
      float lsum = 0.0f;
#pragma unroll
      for (int r = 0; r < 16; ++r) {
        s0[r] = __expf(s0[r] - m_s); s1[r] = __expf(s1[r] - m_s);
        lsum += s0[r] + s1[r];
      }
      lsum += __shfl_xor(lsum, 32);
      l_s += lsum;

#define PV_STEP(KS, PP)                                                       \
      {                                                                       \
        const int rb2 = 8 * ((KS) & 1);                                       \
        const uint32_t g0a = cvt_pk_bf16(PP[rb2 + 0], PP[rb2 + 1]);           \
        const uint32_t g0b = cvt_pk_bf16(PP[rb2 + 2], PP[rb2 + 3]);           \
        const uint32_t g1a = cvt_pk_bf16(PP[rb2 + 4], PP[rb2 + 5]);           \
        const uint32_t g1b = cvt_pk_bf16(PP[rb2 + 6], PP[rb2 + 7]);           \
        const uint32_t sa = hi ? g0a : g1a, sb = hi ? g0b : g1b;              \
        const uint32_t ra = (uint32_t)__shfl_xor((int)sa, 32);                \
        const uint32_t rb_ = (uint32_t)__shfl_xor((int)sb, 32);               \
        frag_u af;                                                            \
        af.w[0] = hi ? ra  : g0a; af.w[1] = hi ? rb_ : g0b;                   \
        af.w[2] = hi ? g1a : ra;  af.w[3] = hi ? g1b : rb_;                   \
        const int gcb = 32 * (KS) + 16 * hi;                                  \
        const int vsw = (col & 7) << 4;                                       \
        _Pragma("unroll")                                                     \
        for (int db = 0; db < 4; ++db) {                                      \
          const s16x8 bv = *(const s16x8*)((const char*)Vs[cur] +             \
              (db * 32 + col) * 128 + (gcb ^ vsw));                           \
          oacc[db] = __builtin_amdgcn_mfma_f32_32x32x16_bf16(af.f, bv, oacc[db], 0, 0, 0); \
        }                                                                     \
      }
      PV_STEP(0, s0); PV_STEP(1, s0); PV_STEP(2, s1); PV_STEP(3, s1);
#undef PV_STEP
    }
    __syncthreads();
  }

  const float linv = 1.0f / l_s;
#pragma unroll
  for (int r = 0; r < 16; ++r) {
    const int qq = (r & 3) + 8 * (r >> 2) + 4 * hi;
    const float lr = __int_as_float(
        __builtin_amdgcn_ds_bpermute(qq * 4, __float_as_int(linv)));
    unsigned short* orow = ob + (size_t)(q0w + qq) * 4096 + h * 128 + col;
#pragma unroll
    for (int db = 0; db < 4; ++db)
      orow[db * 32] = f2bf(oacc[db][r] * lr);
  }
#undef STAGE_K
#undef STAGE_V
}

// ------------------------------ launch ------------------------------
extern "C" void kernel_launch(void* const* d_in, const int* in_sizes, int n_in,
                              void* d_out, int out_size, void* d_ws, size_t ws_size,
                              hipStream_t stream) {
  const float* x     = (const float*)d_in[0];
  const float* cos_f = (const float*)d_in[1];
  const float* sin_f = (const float*)d_in[2];
  const float* wq = (const float*)d_in[4];
  const float* wk = (const float*)d_in[5];
  const float* wv = (const float*)d_in[6];
  const float* wo = (const float*)d_in[7];
  float* out = (float*)d_out;

  char* ws = (char*)d_ws;
  unsigned short* xb    = (unsigned short*)(ws);                 // 2048x4096 bf16
  unsigned short* wqkvb = (unsigned short*)(ws + 16777216);      // 6144x4096 bf16
  unsigned short* wob   = (unsigned short*)(ws + 67108864);      // 4096x4096 bf16
  float*          xqkv  = (float*)(ws + 100663296);              // 2048x6144 fp32
  unsigned short* qb    = (unsigned short*)(ws + 150994944);     // 2048x4096 bf16
  unsigned short* kb    = (unsigned short*)(ws + 167772160);     // 2048x1024 bf16
  unsigned short* vtb   = (unsigned short*)(ws + 171966464);     // [8*128][2048] bf16
  unsigned short* attno = (unsigned short*)(ws + 176160768);     // 2048x4096 bf16

  cast_f32_bf16<<<dim3(8192), 256, 0, stream>>>(x, xb, 2097152);
  cast_f32_bf16<<<dim3(16384), 256, 0, stream>>>(wq, wqkvb, 4194304);
  cast_f32_bf16<<<dim3(4096), 256, 0, stream>>>(wk, wqkvb + 16777216, 1048576);
  cast_f32_bf16<<<dim3(4096), 256, 0, stream>>>(wv, wqkvb + 20971520, 1048576);
  cast_f32_bf16<<<dim3(16384), 256, 0, stream>>>(wo, wob, 4194304);

  // fused QKV projection: [2048x4096] x [6144x4096]^T -> [2048x6144] fp32
  // 16 m-tiles x 16 n-tiles of 128x384 = 256 blocks (full chip)
  gemmF<64, 192, 3, 3><<<dim3(256), 512, 0, stream>>>(xb, wqkvb, xqkv, 6144);

  rope_q_kern<<<dim3(4096), 256, 0, stream>>>(xqkv, cos_f, sin_f, qb);
  rope_k_kern<<<dim3(1024), 256, 0, stream>>>(xqkv, cos_f, sin_f, out + 8388608, kb);
  vtrans_kern<<<dim3(32, 16), 256, 0, stream>>>(xqkv, out + 12582912, vtb);

  (void)hipMemsetAsync(out + 10485760, 0, 8388608, stream);
  (void)hipMemsetAsync(out + 14680064, 0, 8388608, stream);

  attn_fwd2<<<dim3(16, 32), 256, 0, stream>>>(qb, kb, vtb, attno);

  // output projection: [2048x4096] x [4096x4096]^T -> d_out directly
  // 16 x 16 tiles of 128x256 = 256 blocks, full K (no split, no add pass)
  gemmF<64, 128, 2, 2><<<dim3(256), 512, 0, stream>>>(attno, wob, out, 4096);
}

// Round 11
// 317.707 us; speedup vs baseline: 1.3605x; 1.0309x over previous
//
#include <hip/hip_runtime.h>
#include <stdint.h>

// Problem constants
#define S_LEN 2048
#define DIM_   4096
#define NH_    32
#define NKV_   8
#define HD_    128
#define QK_SCALE 0.08838834764831845f   // 1/sqrt(128)

typedef __attribute__((ext_vector_type(8)))  short  s16x8;   // 8 bf16 (4 VGPRs) MFMA frag
typedef __attribute__((ext_vector_type(4)))  float  f32x4;   // 16x16 MFMA accum
typedef __attribute__((ext_vector_type(16))) float  f32x16;  // 32x32 MFMA accum
typedef __attribute__((ext_vector_type(8))) unsigned short u16x8;
typedef __attribute__((ext_vector_type(4))) unsigned short u16x4;

union frag_u { s16x8 f; uint32_t w[4]; };

__device__ __forceinline__ unsigned short f2bf(float f) {
  union { float f; uint32_t u; } v; v.f = f;
  return (unsigned short)((v.u + 0x7fffu + ((v.u >> 16) & 1u)) >> 16);   // RNE
}

__device__ __forceinline__ uint32_t cvt_pk_bf16(float lo, float hi2) {
  uint32_t r;
  asm volatile("v_cvt_pk_bf16_f32 %0, %1, %2" : "=v"(r) : "v"(lo), "v"(hi2));
  return r;
}

// async global->LDS, 16B per lane. LDS dest is wave-uniform base + lane*16.
__device__ __forceinline__ void async_cp16(const void* g, void* l) {
  __builtin_amdgcn_global_load_lds(
      (const __attribute__((address_space(1))) unsigned int*)g,
      (__attribute__((address_space(3))) unsigned int*)l, 16, 0, 0);
}

#define WAITV(n) asm volatile("s_waitcnt vmcnt(" #n ")" ::: "memory")

// ---------------- cast fp32 -> bf16 (vectorized x4) ----------------
__global__ __launch_bounds__(256) void cast_f32_bf16(
    const float* __restrict__ src, unsigned short* __restrict__ dst, int n4) {
  const int i = blockIdx.x * 256 + threadIdx.x;
  if (i >= n4) return;
  const float4 v = ((const float4*)src)[i];
  u16x4 o; o[0] = f2bf(v.x); o[1] = f2bf(v.y); o[2] = f2bf(v.z); o[3] = f2bf(v.w);
  ((u16x4*)dst)[i] = o;
}

// ======= 128 x NTILE_N 2-phase GEMM, rotate-slot LDS, 2 blocks/CU ==========
// C = A(MxK)*B^T(NxK), bf16 in fp32 out. K=4096 (NT=64 BK=64 tiles).
// Grid = 16 m-tiles x (N/NTILE_N) n-tiles = 512 blocks (2 blocks/CU: the
// cross-block TLP provides LDS<->MFMA overlap the 2-phase skeleton lacks).
// 8 waves (2wm x 4wn); per-wave out: M=64 (32 from each A-half, rf=2),
// N = NTILE_N/4 = NCF*16 (contiguous strip per wave).
// LDS per buf: A halves 2x8KB + B NTILE_N*128B (= NBCH x 8KB chunks).
// QKV: NTILE_N=192 -> 80KB total; outproj: 128 -> 64KB. Rotate-slot layout
// (R6-verified, 0 conflicts): stored 16B-slot s=(sl+row)&7, inverse perm on
// the global staging source; any 8 consecutive lanes hit 8 distinct slots.
// Sync skeleton IDENTICAL to R7 (proven): per k-tile J (buf P=J&1):
//   p0: LDA(0) + LDBF reads; stage A1(J+1)->P^1; barrier+lgkm(0); MF(0)
//   mid-barrier (WAR fence: all p0 reads complete before p1 stages land)
//   p1: LDA(1); stage A0(J+2),B(J+2)->P (regions disjoint from p1 reads);
//       barrier+lgkm(0); MF(1); gate WAITV(NBCH+1); barrier
// Gate ledger: entering group J in-flight = {A0,B}(J+1) = NBCH+1; p0 adds
// A1(J+1); p1 adds NBCH+1 for J+2; gate drains tile J+1 exactly.
template <int NT, int NTILE_N, int NCF, int NBCH>
__global__ __launch_bounds__(512, 4) void gemmF(
    const unsigned short* __restrict__ A, const unsigned short* __restrict__ B,
    float* __restrict__ C, int ldc) {
  constexpr int BUFB = 16384 + NTILE_N * 128;   // bytes per buffer
  __shared__ unsigned char lds[2 * BUFB];

  const int bid = blockIdx.x;
  const int idx = (bid & 7) * 64 + (bid >> 3);   // XCD-contiguous
  const int m = idx & 15, n = idx >> 4;
  const int m0 = m * 128, n0 = n * NTILE_N;

  const int tid = threadIdx.x;
  const int wave = tid >> 6, lane = tid & 63;
  const int wm = wave >> 2, wn = wave & 3;
  const int fr = lane & 15, g = lane >> 4;

  // fragment LDS offsets (rotate-slot read side)
  int offA[2][2], offB[NCF][2];
#pragma unroll
  for (int rf = 0; rf < 2; ++rf)
#pragma unroll
    for (int kk = 0; kk < 2; ++kk)
      offA[rf][kk] = (wm * 32 + rf * 16 + fr) * 128 + (((kk * 4 + g + fr) & 7) << 4);
#pragma unroll
  for (int cf = 0; cf < NCF; ++cf)
#pragma unroll
    for (int kk = 0; kk < 2; ++kk)
      offB[cf][kk] = (wn * NCF * 16 + cf * 16 + fr) * 128 + (((kk * 4 + g + fr) & 7) << 4);

  // staging source offsets (inverse rotate-slot on global source)
  const int srk = (((tid & 7) - (tid >> 3)) & 7) * 8;
  uint32_t aoff[2];        // [A half]  (8KB each = 512 x 16B)
  uint32_t boff[NBCH];     // [B chunk] (8KB each, contiguous 64-row chunks)
#pragma unroll
  for (int h = 0; h < 2; ++h)
    aoff[h] = (uint32_t)((m0 + h * 64 + (tid >> 3)) * 4096 + srk);
#pragma unroll
  for (int i = 0; i < NBCH; ++i)
    boff[i] = (uint32_t)((n0 + i * 64 + (tid >> 3)) * 4096 + srk);

  f32x4 acc[2][2][NCF] = {};   // [AA][rf][cf]
  s16x8 fa[2][2], fb[NCF][2];

#define STGA(H, T, BUF)                                                       \
  async_cp16(A + aoff[H] + (size_t)(T) * 64,                                  \
             (char*)lds + (BUF) * BUFB + (H) * 8192 + tid * 16);
#define STGB(T, BUF)                                                          \
  { _Pragma("unroll") for (int i_ = 0; i_ < NBCH; ++i_)                       \
      async_cp16(B + boff[i_] + (size_t)(T) * 64,                             \
                 (char*)lds + (BUF) * BUFB + 16384 + i_ * 8192 + tid * 16); }
#define LDA(AA, P)                                                            \
  { _Pragma("unroll") for (int rf = 0; rf < 2; ++rf)                          \
      _Pragma("unroll") for (int kk = 0; kk < 2; ++kk)                        \
        fa[rf][kk] = *(const s16x8*)((char*)lds + (P) * BUFB +                \
                                     (AA) * 8192 + offA[rf][kk]); }
#define LDBF(P)                                                               \
  { _Pragma("unroll") for (int cf = 0; cf < NCF; ++cf)                        \
      _Pragma("unroll") for (int kk = 0; kk < 2; ++kk)                        \
        fb[cf][kk] = *(const s16x8*)((char*)lds + (P) * BUFB + 16384 +        \
                                     offB[cf][kk]); }
#define BARLG()                                                               \
  __builtin_amdgcn_s_barrier();                                               \
  asm volatile("s_waitcnt lgkmcnt(0)" ::: "memory");                          \
  __builtin_amdgcn_sched_barrier(0);
#define MF(AA)                                                                \
  __builtin_amdgcn_s_setprio(1);                                              \
  { _Pragma("unroll") for (int kk = 0; kk < 2; ++kk)                          \
      _Pragma("unroll") for (int rf = 0; rf < 2; ++rf)                        \
        _Pragma("unroll") for (int cf = 0; cf < NCF; ++cf)                    \
          acc[AA][rf][cf] = __builtin_amdgcn_mfma_f32_16x16x32_bf16(          \
              fa[rf][kk], fb[cf][kk], acc[AA][rf][cf], 0, 0, 0); }            \
  __builtin_amdgcn_s_setprio(0);
#define GATEN do { if constexpr (NBCH == 3) { WAITV(4); } else { WAITV(3); } } while (0)

#define GROUPF(J, P, DO1, DO2, GATE)                                          \
  {                                                                           \
    LDA(0, P); LDBF(P);                                                       \
    if (DO1) { STGA(1, (J) + 1, (P) ^ 1); }                                   \
    BARLG(); MF(0);                                                           \
    __builtin_amdgcn_s_barrier();                                             \
    LDA(1, P);                                                                \
    if (DO2) { STGA(0, (J) + 2, P); STGB((J) + 2, P); }                       \
    BARLG(); MF(1);                                                           \
    GATE;                                                                     \
    __builtin_amdgcn_s_barrier();                                             \
  }

  // prologue: tile0 complete -> buf0; tile1 A0,B -> buf1 (A1(1) at grp0 p0)
  STGA(0, 0, 0); STGB(0, 0); STGA(1, 0, 0);
  STGA(0, 1, 1); STGB(1, 1);
  GATEN;
  __builtin_amdgcn_s_barrier();

  for (int j = 0; j + 3 < NT; j += 2) {
    GROUPF(j, 0, true, true, GATEN);
    GROUPF(j + 1, 1, true, true, GATEN);
  }
  GROUPF(NT - 2, 0, true, false, WAITV(0));
  GROUPF(NT - 1, 1, false, false, );

  // epilogue: C[m0 + AA*64 + wm*32 + rf*16 + g*4 + r][n0 + wn*NCF*16 + cf*16 + fr]
#pragma unroll
  for (int AA = 0; AA < 2; ++AA)
#pragma unroll
    for (int rf = 0; rf < 2; ++rf)
#pragma unroll
      for (int cf = 0; cf < NCF; ++cf) {
        float* cp = C + (size_t)(m0 + AA * 64 + wm * 32 + rf * 16 + g * 4) * ldc
                      + (n0 + wn * NCF * 16 + cf * 16 + fr);
#pragma unroll
        for (int r = 0; r < 4; ++r) cp[(size_t)r * ldc] = acc[AA][rf][cf][r];
      }
#undef STGA
#undef STGB
#undef LDA
#undef LDBF
#undef BARLG
#undef MF
#undef GATEN
#undef GROUPF
}

// ---------------- RoPE on Q (folds QK scale), fp32 -> bf16 ----------
__global__ __launch_bounds__(256) void rope_q_kern(
    const float* __restrict__ xqkv, const float* __restrict__ cos_f,
    const float* __restrict__ sin_f, unsigned short* __restrict__ qb) {
  const int gid = blockIdx.x * 256 + threadIdx.x;
  const int e0 = gid * 8;
  const int s = e0 >> 12;
  const int col = e0 & 4095;
  const int i0 = (col & 127) >> 1;
  const float* src = xqkv + (size_t)s * 6144 + col;
  const float4 f1 = *(const float4*)src;
  const float4 f2 = *(const float4*)(src + 4);
  const float4 c  = *(const float4*)(cos_f + s * 64 + i0);
  const float4 sn = *(const float4*)(sin_f + s * 64 + i0);
  u16x8 o;
  o[0] = f2bf((f1.x * c.x - f1.y * sn.x) * QK_SCALE);
  o[1] = f2bf((f1.x * sn.x + f1.y * c.x) * QK_SCALE);
  o[2] = f2bf((f1.z * c.y - f1.w * sn.y) * QK_SCALE);
  o[3] = f2bf((f1.z * sn.y + f1.w * c.y) * QK_SCALE);
  o[4] = f2bf((f2.x * c.z - f2.y * sn.z) * QK_SCALE);
  o[5] = f2bf((f2.x * sn.z + f2.y * c.z) * QK_SCALE);
  o[6] = f2bf((f2.z * c.w - f2.w * sn.w) * QK_SCALE);
  o[7] = f2bf((f2.z * sn.w + f2.w * c.w) * QK_SCALE);
  *(u16x8*)(qb + e0) = o;
}

// ---------------- RoPE on K: fp32 cache out + bf16 attn K -----------
__global__ __launch_bounds__(256) void rope_k_kern(
    const float* __restrict__ xqkv, const float* __restrict__ cos_f,
    const float* __restrict__ sin_f, float* __restrict__ ck, unsigned short* __restrict__ kb) {
  const int gid = blockIdx.x * 256 + threadIdx.x;
  const int e0 = gid * 8;
  const int s = e0 >> 10;
  const int col = e0 & 1023;
  const int i0 = (col & 127) >> 1;
  const float* src = xqkv + (size_t)s * 6144 + 4096 + col;
  const float4 f1 = *(const float4*)src;
  const float4 f2 = *(const float4*)(src + 4);
  const float4 c  = *(const float4*)(cos_f + s * 64 + i0);
  const float4 sn = *(const float4*)(sin_f + s * 64 + i0);
  const float r0 = f1.x * c.x - f1.y * sn.x, r1 = f1.x * sn.x + f1.y * c.x;
  const float r2 = f1.z * c.y - f1.w * sn.y, r3 = f1.z * sn.y + f1.w * c.y;
  const float r4 = f2.x * c.z - f2.y * sn.z, r5 = f2.x * sn.z + f2.y * c.z;
  const float r6 = f2.z * c.w - f2.w * sn.w, r7 = f2.z * sn.w + f2.w * c.w;
  float4 o1; o1.x = r0; o1.y = r1; o1.z = r2; o1.w = r3;
  float4 o2; o2.x = r4; o2.y = r5; o2.z = r6; o2.w = r7;
  *(float4*)(ck + (size_t)s * 1024 + col) = o1;
  *(float4*)(ck + (size_t)s * 1024 + col + 4) = o2;
  u16x8 o;
  o[0] = f2bf(r0); o[1] = f2bf(r1); o[2] = f2bf(r2); o[3] = f2bf(r3);
  o[4] = f2bf(r4); o[5] = f2bf(r5); o[6] = f2bf(r6); o[7] = f2bf(r7);
  *(u16x8*)(kb + (size_t)s * 1024 + col) = o;
}

// ------- V: fp32 cache out (coalesced) + bf16 V^T [NKV*HD][S] -------
__global__ __launch_bounds__(256) void vtrans_kern(
    const float* __restrict__ xqkv, float* __restrict__ cv, unsigned short* __restrict__ vtb) {
  __shared__ float tile[64][65];
  const int st = blockIdx.x * 64;
  const int ct = blockIdx.y * 64;
  const int tid = threadIdx.x;
#pragma unroll
  for (int j = 0; j < 16; ++j) {
    const int lin = tid + j * 256;
    const int si = lin >> 6, ci = lin & 63;
    const float v = xqkv[(size_t)(st + si) * 6144 + 5120 + ct + ci];
    cv[(size_t)(st + si) * 1024 + ct + ci] = v;
    tile[si][ci] = v;
  }
  __syncthreads();
#pragma unroll
  for (int j = 0; j < 16; ++j) {
    const int lin = tid + j * 256;
    const int co = lin >> 6, so = lin & 63;
    vtb[(size_t)(ct + co) * 2048 + st + so] = f2bf(tile[so][co]);
  }
}

// ---------------- flash attention v2 (unchanged) --------------------
__global__ __launch_bounds__(256, 2) void attn_fwd2(
    const unsigned short* __restrict__ qb, const unsigned short* __restrict__ kb,
    const unsigned short* __restrict__ vtb, unsigned short* __restrict__ ob) {
  __shared__ unsigned short Ks[2][64 * 128];
  __shared__ unsigned short Vs[2][128 * 64];
  const int bx = blockIdx.x;
  const int h  = blockIdx.y;
  const int hkv = h >> 2;
  const int g = (bx & 1) ? (15 - (bx >> 1)) : (bx >> 1);
  const int qtile = (h < 16) ? g : (15 - g);
  const int q0 = qtile * 128;
  const int tid = threadIdx.x, wave = tid >> 6, lane = tid & 63;
  const int col = lane & 31;
  const int hi  = lane >> 5;
  const int q0w = q0 + wave * 32;
  const int nt = (q0 >> 6) + 2;

  s16x8 qf[8];
  {
    const unsigned short* qrow = qb + (size_t)(q0w + col) * 4096 + h * 128 + hi * 8;
#pragma unroll
    for (int ks = 0; ks < 8; ++ks) qf[ks] = *(const s16x8*)(qrow + ks * 16);
  }

  f32x16 oacc[4] = {};
  float m_s = -3e30f, l_s = 0.0f;

#define STAGE_K(KT, B)                                                        \
  {                                                                           \
    const unsigned short* src = kb + (size_t)((KT) * 64) * 1024 + hkv * 128;  \
    _Pragma("unroll")                                                         \
    for (int i_ = 0; i_ < 4; ++i_) {                                          \
      const int c_ = wave * 4 + i_;                                           \
      const int row_ = c_ * 4 + (lane >> 4);                                  \
      const int cb_ = ((lane & 15) * 16) ^ ((row_ & 7) << 4);                 \
      async_cp16(src + (size_t)row_ * 1024 + (cb_ >> 1), (char*)Ks[B] + c_ * 1024); \
    }                                                                         \
  }
#define STAGE_V(KT, B)                                                        \
  {                                                                           \
    const unsigned short* src = vtb + (size_t)hkv * (128 * 2048) + (KT) * 64; \
    _Pragma("unroll")                                                         \
    for (int i_ = 0; i_ < 4; ++i_) {                                          \
      const int c_ = wave * 4 + i_;                                           \
      const int row_ = c_ * 8 + (lane >> 3);                                  \
      const int cb_ = ((lane & 7) * 16) ^ ((row_ & 7) << 4);                  \
      async_cp16(src + (size_t)row_ * 2048 + (cb_ >> 1), (char*)Vs[B] + c_ * 1024); \
    }                                                                         \
  }

  STAGE_K(0, 0); STAGE_V(0, 0);
  __syncthreads();

  for (int kt = 0; kt < nt; ++kt) {
    const int kv0 = kt * 64;
    const int cur = kt & 1;
    if (kt + 1 < nt) { STAGE_K(kt + 1, cur ^ 1); STAGE_V(kt + 1, cur ^ 1); }

    if (kv0 < q0w + 32) {
      f32x16 s0 = {}, s1 = {};
#pragma unroll
      for (int ks = 0; ks < 8; ++ks) {
        const int gcb = 32 * ks + 16 * hi;
        const int sw = (col & 7) << 4;
        const s16x8 k0 = *(const s16x8*)((const char*)Ks[cur] + col * 256 + (gcb ^ sw));
        const s16x8 k1 = *(const s16x8*)((const char*)Ks[cur] + (32 + col) * 256 + (gcb ^ sw));
        s0 = __builtin_amdgcn_mfma_f32_32x32x16_bf16(k0, qf[ks], s0, 0, 0, 0);
        s1 = __builtin_amdgcn_mfma_f32_32x32x16_bf16(k1, qf[ks], s1, 0, 0, 0);
      }

      const int qg = q0w + col;
      if (kv0 + 63 > q0w) {
#pragma unroll
        for (int r = 0; r < 16; ++r) {
          const int kvl = (r & 3) + 8 * (r >> 2) + 4 * hi;
          if (kv0 + kvl > qg)      s0[r] = -3e30f;
          if (kv0 + 32 + kvl > qg) s1[r] = -3e30f;
        }
      }

      float mxl = s0[0];
#pragma unroll
      for (int r = 1; r < 16; ++r) mxl = fmaxf(mxl, s0[r]);
#pragma unroll
      for (int r = 0; r < 16; ++r) mxl = fmaxf(mxl, s1[r]);
      const float mxf = fmaxf(mxl, __shfl_xor(mxl, 32));
      if (__any(mxf > m_s + 8.0f)) {
        const float mn = fmaxf(m_s, mxf);
        const float scl = __expf(m_s - mn);
        m_s = mn;
        l_s *= scl;
#pragma unroll
        for (int r = 0; r < 16; ++r) {
          const int qq = (r & 3) + 8 * (r >> 2) + 4 * hi;
          const float sr = __int_as_float(
              __builtin_amdgcn_ds_bpermute(qq * 4, __float_as_int(scl)));
          oacc[0][r] *= sr; oacc[1][r] *= sr; oacc[2][r] *= sr; oacc[3][r] *= sr;
        }
      }
      float lsum = 0.0f;
#pragma unroll
      for (int r = 0; r < 16; ++r) {
        s0[r] = __expf(s0[r] - m_s); s1[r] = __expf(s1[r] - m_s);
        lsum += s0[r] + s1[r];
      }
      lsum += __shfl_xor(lsum, 32);
      l_s += lsum;

#define PV_STEP(KS, PP)                                                       \
      {                                                                       \
        const int rb2 = 8 * ((KS) & 1);                                       \
        const uint32_t g0a = cvt_pk_bf16(PP[rb2 + 0], PP[rb2 + 1]);           \
        const uint32_t g0b = cvt_pk_bf16(PP[rb2 + 2], PP[rb2 + 3]);           \
        const uint32_t g1a = cvt_pk_bf16(PP[rb2 + 4], PP[rb2 + 5]);           \
        const uint32_t g1b = cvt_pk_bf16(PP[rb2 + 6], PP[rb2 + 7]);           \
        const uint32_t sa = hi ? g0a : g1a, sb = hi ? g0b : g1b;              \
        const uint32_t ra = (uint32_t)__shfl_xor((int)sa, 32);                \
        const uint32_t rb_ = (uint32_t)__shfl_xor((int)sb, 32);               \
        frag_u af;                                                            \
        af.w[0] = hi ? ra  : g0a; af.w[1] = hi ? rb_ : g0b;                   \
        af.w[2] = hi ? g1a : ra;  af.w[3] = hi ? g1b : rb_;                   \
        const int gcb = 32 * (KS) + 16 * hi;                                  \
        const int vsw = (col & 7) << 4;                                       \
        _Pragma("unroll")                                                     \
        for (int db = 0; db < 4; ++db) {                                      \
          const s16x8 bv = *(const s16x8*)((const char*)Vs[cur] +             \
              (db * 32 + col) * 128 + (gcb ^ vsw));                           \
          oacc[db] = __builtin_amdgcn_mfma_f32_32x32x16_bf16(af.f, bv, oacc[db], 0, 0, 0); \
        }                                                                     \
      }
      PV_STEP(0, s0); PV_STEP(1, s0); PV_STEP(2, s1); PV_STEP(3, s1);
#undef PV_STEP
    }
    __syncthreads();
  }

  const float linv = 1.0f / l_s;
#pragma unroll
  for (int r = 0; r < 16; ++r) {
    const int qq = (r & 3) + 8 * (r >> 2) + 4 * hi;
    const float lr = __int_as_float(
        __builtin_amdgcn_ds_bpermute(qq * 4, __float_as_int(linv)));
    unsigned short* orow = ob + (size_t)(q0w + qq) * 4096 + h * 128 + col;
#pragma unroll
    for (int db = 0; db < 4; ++db)
      orow[db * 32] = f2bf(oacc[db][r] * lr);
  }
#undef STAGE_K
#undef STAGE_V
}

// ------------------------------ launch ------------------------------
extern "C" void kernel_launch(void* const* d_in, const int* in_sizes, int n_in,
                              void* d_out, int out_size, void* d_ws, size_t ws_size,
                              hipStream_t stream) {
  const float* x     = (const float*)d_in[0];
  const float* cos_f = (const float*)d_in[1];
  const float* sin_f = (const float*)d_in[2];
  const float* wq = (const float*)d_in[4];
  const float* wk = (const float*)d_in[5];
  const float* wv = (const float*)d_in[6];
  const float* wo = (const float*)d_in[7];
  float* out = (float*)d_out;

  char* ws = (char*)d_ws;
  unsigned short* xb    = (unsigned short*)(ws);                 // 2048x4096 bf16
  unsigned short* wqkvb = (unsigned short*)(ws + 16777216);      // 6144x4096 bf16
  unsigned short* wob   = (unsigned short*)(ws + 67108864);      // 4096x4096 bf16
  float*          xqkv  = (float*)(ws + 100663296);              // 2048x6144 fp32
  unsigned short* qb    = (unsigned short*)(ws + 150994944);     // 2048x4096 bf16
  unsigned short* kb    = (unsigned short*)(ws + 167772160);     // 2048x1024 bf16
  unsigned short* vtb   = (unsigned short*)(ws + 171966464);     // [8*128][2048] bf16
  unsigned short* attno = (unsigned short*)(ws + 176160768);     // 2048x4096 bf16

  cast_f32_bf16<<<dim3(8192), 256, 0, stream>>>(x, xb, 2097152);
  cast_f32_bf16<<<dim3(16384), 256, 0, stream>>>(wq, wqkvb, 4194304);
  cast_f32_bf16<<<dim3(4096), 256, 0, stream>>>(wk, wqkvb + 16777216, 1048576);
  cast_f32_bf16<<<dim3(4096), 256, 0, stream>>>(wv, wqkvb + 20971520, 1048576);
  cast_f32_bf16<<<dim3(16384), 256, 0, stream>>>(wo, wob, 4194304);

  // fused QKV projection: [2048x4096] x [6144x4096]^T -> [2048x6144] fp32
  // 16 m-tiles x 32 n-tiles of 128x192 = 512 blocks (2 blocks/CU, 80KB LDS)
  gemmF<64, 192, 3, 3><<<dim3(512), 512, 0, stream>>>(xb, wqkvb, xqkv, 6144);

  rope_q_kern<<<dim3(4096), 256, 0, stream>>>(xqkv, cos_f, sin_f, qb);
  rope_k_kern<<<dim3(1024), 256, 0, stream>>>(xqkv, cos_f, sin_f, out + 8388608, kb);
  vtrans_kern<<<dim3(32, 16), 256, 0, stream>>>(xqkv, out + 12582912, vtb);

  (void)hipMemsetAsync(out + 10485760, 0, 8388608, stream);
  (void)hipMemsetAsync(out + 14680064, 0, 8388608, stream);

  attn_fwd2<<<dim3(16, 32), 256, 0, stream>>>(qb, kb, vtb, attno);

  // output projection: [2048x4096] x [4096x4096]^T -> d_out directly
  // 16 m x 32 n tiles of 128x128 = 512 blocks (2 blocks/CU, 64KB LDS)
  gemmF<64, 128, 2, 2><<<dim3(512), 512, 0, stream>>>(attno, wob, out, 4096);
}

// Round 12
// 314.027 us; speedup vs baseline: 1.3764x; 1.0117x over previous
//
#include <hip/hip_runtime.h>
#include <stdint.h>

// Problem constants
#define S_LEN 2048
#define DIM_   4096
#define NH_    32
#define NKV_   8
#define HD_    128
#define QK_SCALE 0.08838834764831845f   // 1/sqrt(128)

typedef __attribute__((ext_vector_type(8)))  short  s16x8;   // 8 bf16 (4 VGPRs) MFMA frag
typedef __attribute__((ext_vector_type(4)))  float  f32x4;   // 16x16 MFMA accum
typedef __attribute__((ext_vector_type(16))) float  f32x16;  // 32x32 MFMA accum
typedef __attribute__((ext_vector_type(8))) unsigned short u16x8;
typedef __attribute__((ext_vector_type(4))) unsigned short u16x4;

union frag_u { s16x8 f; uint32_t w[4]; };

__device__ __forceinline__ unsigned short f2bf(float f) {
  union { float f; uint32_t u; } v; v.f = f;
  return (unsigned short)((v.u + 0x7fffu + ((v.u >> 16) & 1u)) >> 16);   // RNE
}

__device__ __forceinline__ uint32_t cvt_pk_bf16(float lo, float hi2) {
  uint32_t r;
  asm volatile("v_cvt_pk_bf16_f32 %0, %1, %2" : "=v"(r) : "v"(lo), "v"(hi2));
  return r;
}

// async global->LDS, 16B per lane. LDS dest is wave-uniform base + lane*16.
__device__ __forceinline__ void async_cp16(const void* g, void* l) {
  __builtin_amdgcn_global_load_lds(
      (const __attribute__((address_space(1))) unsigned int*)g,
      (__attribute__((address_space(3))) unsigned int*)l, 16, 0, 0);
}

#define WAITV(n) asm volatile("s_waitcnt vmcnt(" #n ")" ::: "memory")

// ---------------- cast fp32 -> bf16 (vectorized x4) ----------------
__global__ __launch_bounds__(256) void cast_f32_bf16(
    const float* __restrict__ src, unsigned short* __restrict__ dst, int n4) {
  const int i = blockIdx.x * 256 + threadIdx.x;
  if (i >= n4) return;
  const float4 v = ((const float4*)src)[i];
  u16x4 o; o[0] = f2bf(v.x); o[1] = f2bf(v.y); o[2] = f2bf(v.z); o[3] = f2bf(v.w);
  ((u16x4*)dst)[i] = o;
}

// == 128 x NTILE_N 2-phase GEMM, 4 waves x (64 x NTILE_N/2), rotate-slot ====
// C = A(MxK)*B^T(NxK), bf16 in fp32 out. K=4096 (NT=64 BK=64 tiles).
// Grid = 16 m-tiles x (4096/... ) = 512 blocks of 256 thr (2 blocks/CU).
// 4 waves 2wm x 2wn; per-wave out 64 x NCF*16 (FLOP/LDS-byte: 64x96 -> 38.4
// vs R11's 64x48 -> 27.4; cuts per-block ds_reads 112KB -> 80KB per k-tile;
// R11 post-mortem showed the LDS unit ~96% busy = the binding resource).
// LDS per buf: A 2x8KB halves (wave wm reads half wm) + B NTILE_N*128B.
// Rotate-slot layout (R6-verified, 0 conflicts) unchanged.
// Phases per k-tile J (buf P=J&1), kk = K-half split:
//   p0: read fa[rf][0..1] (8) + fbk kk=0 (NCF); stage B(J+1)->P^1;
//       barrier+lgkm0; MFK(0); mid-barrier
//   p1: read fbk kk=1 (NCF) [B region of P]; stage A(J+2)->P [A regions of P
//       -- DISJOINT from p1's reads, preserving the proven invariant];
//       barrier+lgkm0; MFK(1); gate WAITV(4); barrier
// Ledger (loads/thread: A=4, B=NBCH): at gate, outstanding =
// {A(J+1),B(J+1),A(J+2)}; WAITV(4) leaves exactly A(J+2) => tile J+1 fully
// resident at group J+1 entry. Prologue gate WAITV(4); tail WAITV(0).
template <int NT, int NTILE_N, int NCF, int NBCH>
__global__ __launch_bounds__(256, 2) void gemmF(
    const unsigned short* __restrict__ A, const unsigned short* __restrict__ B,
    float* __restrict__ C, int ldc) {
  constexpr int BUFB = 16384 + NTILE_N * 128;   // bytes per buffer
  __shared__ unsigned char lds[2 * BUFB];

  const int bid = blockIdx.x;
  const int idx = (bid & 7) * 64 + (bid >> 3);   // XCD-contiguous
  const int m = idx & 15, n = idx >> 4;
  const int m0 = m * 128, n0 = n * NTILE_N;

  const int tid = threadIdx.x;
  const int wave = tid >> 6, lane = tid & 63;
  const int wm = wave >> 1, wn = wave & 1;
  const int fr = lane & 15, g = lane >> 4;

  // fragment LDS offsets (rotate-slot read side); offA includes wm half
  int offA[4][2], offB[NCF][2];
#pragma unroll
  for (int rf = 0; rf < 4; ++rf)
#pragma unroll
    for (int kk = 0; kk < 2; ++kk)
      offA[rf][kk] = wm * 8192 + (rf * 16 + fr) * 128 + (((kk * 4 + g + fr) & 7) << 4);
#pragma unroll
  for (int cf = 0; cf < NCF; ++cf)
#pragma unroll
    for (int kk = 0; kk < 2; ++kk)
      offB[cf][kk] = (wn * NCF * 16 + cf * 16 + fr) * 128 + (((kk * 4 + g + fr) & 7) << 4);

  // staging source offsets (inverse rotate-slot on global source); 256 thr
  const int srk = (((tid & 7) - (tid >> 3)) & 7) * 8;
  uint32_t aoff[2][2];     // [A half][iter of 32 rows]
  uint32_t boff[NBCH];     // [B chunk of 32 rows]
#pragma unroll
  for (int h = 0; h < 2; ++h)
#pragma unroll
    for (int i = 0; i < 2; ++i)
      aoff[h][i] = (uint32_t)((m0 + h * 64 + i * 32 + (tid >> 3)) * 4096 + srk);
#pragma unroll
  for (int i = 0; i < NBCH; ++i)
    boff[i] = (uint32_t)((n0 + i * 32 + (tid >> 3)) * 4096 + srk);

  f32x4 acc[4][NCF] = {};   // [rf][cf]
  s16x8 fa[4][2], fbk[NCF];

#define STGA(T, BUF)                                                          \
  { _Pragma("unroll") for (int h_ = 0; h_ < 2; ++h_)                          \
      _Pragma("unroll") for (int i_ = 0; i_ < 2; ++i_)                        \
        async_cp16(A + aoff[h_][i_] + (size_t)(T) * 64,                       \
                   (char*)lds + (BUF) * BUFB + h_ * 8192 + i_ * 4096 + tid * 16); }
#define STGB(T, BUF)                                                          \
  { _Pragma("unroll") for (int i_ = 0; i_ < NBCH; ++i_)                       \
      async_cp16(B + boff[i_] + (size_t)(T) * 64,                             \
                 (char*)lds + (BUF) * BUFB + 16384 + i_ * 4096 + tid * 16); }
#define LDA2(P)                                                               \
  { _Pragma("unroll") for (int rf = 0; rf < 4; ++rf)                          \
      _Pragma("unroll") for (int kk = 0; kk < 2; ++kk)                        \
        fa[rf][kk] = *(const s16x8*)((char*)lds + (P) * BUFB + offA[rf][kk]); }
#define LDBK(KK, P)                                                           \
  { _Pragma("unroll") for (int cf = 0; cf < NCF; ++cf)                        \
      fbk[cf] = *(const s16x8*)((char*)lds + (P) * BUFB + 16384 + offB[cf][KK]); }
#define BARLG()                                                               \
  __builtin_amdgcn_s_barrier();                                               \
  asm volatile("s_waitcnt lgkmcnt(0)" ::: "memory");                          \
  __builtin_amdgcn_sched_barrier(0);
#define MFK(KK)                                                               \
  __builtin_amdgcn_s_setprio(1);                                              \
  { _Pragma("unroll") for (int rf = 0; rf < 4; ++rf)                          \
      _Pragma("unroll") for (int cf = 0; cf < NCF; ++cf)                      \
        acc[rf][cf] = __builtin_amdgcn_mfma_f32_16x16x32_bf16(                \
            fa[rf][KK], fbk[cf], acc[rf][cf], 0, 0, 0); }                     \
  __builtin_amdgcn_s_setprio(0);

#define GROUPF(J, P, DO1, DO2, GATE)                                          \
  {                                                                           \
    LDA2(P); LDBK(0, P);                                                      \
    if (DO1) { STGB((J) + 1, (P) ^ 1); }                                      \
    BARLG(); MFK(0);                                                          \
    __builtin_amdgcn_s_barrier();                                             \
    LDBK(1, P);                                                               \
    if (DO2) { STGA((J) + 2, P); }                                            \
    BARLG(); MFK(1);                                                          \
    GATE;                                                                     \
    __builtin_amdgcn_s_barrier();                                             \
  }

  // prologue: tile0 A+B -> buf0; tile1 A -> buf1 (B(1) staged at grp0 p0)
  STGA(0, 0); STGB(0, 0); STGA(1, 1);
  WAITV(4);
  __builtin_amdgcn_s_barrier();

  for (int j = 0; j + 3 < NT; j += 2) {
    GROUPF(j, 0, true, true, WAITV(4));
    GROUPF(j + 1, 1, true, true, WAITV(4));
  }
  GROUPF(NT - 2, 0, true, false, WAITV(0));
  GROUPF(NT - 1, 1, false, false, );

  // epilogue: C[m0 + wm*64 + rf*16 + g*4 + r][n0 + wn*NCF*16 + cf*16 + fr]
#pragma unroll
  for (int rf = 0; rf < 4; ++rf)
#pragma unroll
    for (int cf = 0; cf < NCF; ++cf) {
      float* cp = C + (size_t)(m0 + wm * 64 + rf * 16 + g * 4) * ldc
                    + (n0 + wn * NCF * 16 + cf * 16 + fr);
#pragma unroll
      for (int r = 0; r < 4; ++r) cp[(size_t)r * ldc] = acc[rf][cf][r];
    }
#undef STGA
#undef STGB
#undef LDA2
#undef LDBK
#undef BARLG
#undef MFK
#undef GROUPF
}

// ---------------- RoPE on Q (folds QK scale), fp32 -> bf16 ----------
__global__ __launch_bounds__(256) void rope_q_kern(
    const float* __restrict__ xqkv, const float* __restrict__ cos_f,
    const float* __restrict__ sin_f, unsigned short* __restrict__ qb) {
  const int gid = blockIdx.x * 256 + threadIdx.x;
  const int e0 = gid * 8;
  const int s = e0 >> 12;
  const int col = e0 & 4095;
  const int i0 = (col & 127) >> 1;
  const float* src = xqkv + (size_t)s * 6144 + col;
  const float4 f1 = *(const float4*)src;
  const float4 f2 = *(const float4*)(src + 4);
  const float4 c  = *(const float4*)(cos_f + s * 64 + i0);
  const float4 sn = *(const float4*)(sin_f + s * 64 + i0);
  u16x8 o;
  o[0] = f2bf((f1.x * c.x - f1.y * sn.x) * QK_SCALE);
  o[1] = f2bf((f1.x * sn.x + f1.y * c.x) * QK_SCALE);
  o[2] = f2bf((f1.z * c.y - f1.w * sn.y) * QK_SCALE);
  o[3] = f2bf((f1.z * sn.y + f1.w * c.y) * QK_SCALE);
  o[4] = f2bf((f2.x * c.z - f2.y * sn.z) * QK_SCALE);
  o[5] = f2bf((f2.x * sn.z + f2.y * c.z) * QK_SCALE);
  o[6] = f2bf((f2.z * c.w - f2.w * sn.w) * QK_SCALE);
  o[7] = f2bf((f2.z * sn.w + f2.w * c.w) * QK_SCALE);
  *(u16x8*)(qb + e0) = o;
}

// ---------------- RoPE on K: fp32 cache out + bf16 attn K -----------
__global__ __launch_bounds__(256) void rope_k_kern(
    const float* __restrict__ xqkv, const float* __restrict__ cos_f,
    const float* __restrict__ sin_f, float* __restrict__ ck, unsigned short* __restrict__ kb) {
  const int gid = blockIdx.x * 256 + threadIdx.x;
  const int e0 = gid * 8;
  const int s = e0 >> 10;
  const int col = e0 & 1023;
  const int i0 = (col & 127) >> 1;
  const float* src = xqkv + (size_t)s * 6144 + 4096 + col;
  const float4 f1 = *(const float4*)src;
  const float4 f2 = *(const float4*)(src + 4);
  const float4 c  = *(const float4*)(cos_f + s * 64 + i0);
  const float4 sn = *(const float4*)(sin_f + s * 64 + i0);
  const float r0 = f1.x * c.x - f1.y * sn.x, r1 = f1.x * sn.x + f1.y * c.x;
  const float r2 = f1.z * c.y - f1.w * sn.y, r3 = f1.z * sn.y + f1.w * c.y;
  const float r4 = f2.x * c.z - f2.y * sn.z, r5 = f2.x * sn.z + f2.y * c.z;
  const float r6 = f2.z * c.w - f2.w * sn.w, r7 = f2.z * sn.w + f2.w * c.w;
  float4 o1; o1.x = r0; o1.y = r1; o1.z = r2; o1.w = r3;
  float4 o2; o2.x = r4; o2.y = r5; o2.z = r6; o2.w = r7;
  *(float4*)(ck + (size_t)s * 1024 + col) = o1;
  *(float4*)(ck + (size_t)s * 1024 + col + 4) = o2;
  u16x8 o;
  o[0] = f2bf(r0); o[1] = f2bf(r1); o[2] = f2bf(r2); o[3] = f2bf(r3);
  o[4] = f2bf(r4); o[5] = f2bf(r5); o[6] = f2bf(r6); o[7] = f2bf(r7);
  *(u16x8*)(kb + (size_t)s * 1024 + col) = o;
}

// ------- V: fp32 cache out (coalesced) + bf16 V^T [NKV*HD][S] -------
__global__ __launch_bounds__(256) void vtrans_kern(
    const float* __restrict__ xqkv, float* __restrict__ cv, unsigned short* __restrict__ vtb) {
  __shared__ float tile[64][65];
  const int st = blockIdx.x * 64;
  const int ct = blockIdx.y * 64;
  const int tid = threadIdx.x;
#pragma unroll
  for (int j = 0; j < 16; ++j) {
    const int lin = tid + j * 256;
    const int si = lin >> 6, ci = lin & 63;
    const float v = xqkv[(size_t)(st + si) * 6144 + 5120 + ct + ci];
    cv[(size_t)(st + si) * 1024 + ct + ci] = v;
    tile[si][ci] = v;
  }
  __syncthreads();
#pragma unroll
  for (int j = 0; j < 16; ++j) {
    const int lin = tid + j * 256;
    const int co = lin >> 6, so = lin & 63;
    vtb[(size_t)(ct + co) * 2048 + st + so] = f2bf(tile[so][co]);
  }
}

// ---------------- flash attention v2 (unchanged) --------------------
__global__ __launch_bounds__(256, 2) void attn_fwd2(
    const unsigned short* __restrict__ qb, const unsigned short* __restrict__ kb,
    const unsigned short* __restrict__ vtb, unsigned short* __restrict__ ob) {
  __shared__ unsigned short Ks[2][64 * 128];
  __shared__ unsigned short Vs[2][128 * 64];
  const int bx = blockIdx.x;
  const int h  = blockIdx.y;
  const int hkv = h >> 2;
  const int g = (bx & 1) ? (15 - (bx >> 1)) : (bx >> 1);
  const int qtile = (h < 16) ? g : (15 - g);
  const int q0 = qtile * 128;
  const int tid = threadIdx.x, wave = tid >> 6, lane = tid & 63;
  const int col = lane & 31;
  const int hi  = lane >> 5;
  const int q0w = q0 + wave * 32;
  const int nt = (q0 >> 6) + 2;

  s16x8 qf[8];
  {
    const unsigned short* qrow = qb + (size_t)(q0w + col) * 4096 + h * 128 + hi * 8;
#pragma unroll
    for (int ks = 0; ks < 8; ++ks) qf[ks] = *(const s16x8*)(qrow + ks * 16);
  }

  f32x16 oacc[4] = {};
  float m_s = -3e30f, l_s = 0.0f;

#define STAGE_K(KT, B)                                                        \
  {                                                                           \
    const unsigned short* src = kb + (size_t)((KT) * 64) * 1024 + hkv * 128;  \
    _Pragma("unroll")                                                         \
    for (int i_ = 0; i_ < 4; ++i_) {                                          \
      const int c_ = wave * 4 + i_;                                           \
      const int row_ = c_ * 4 + (lane >> 4);                                  \
      const int cb_ = ((lane & 15) * 16) ^ ((row_ & 7) << 4);                 \
      async_cp16(src + (size_t)row_ * 1024 + (cb_ >> 1), (char*)Ks[B] + c_ * 1024); \
    }                                                                         \
  }
#define STAGE_V(KT, B)                                                        \
  {                                                                           \
    const unsigned short* src = vtb + (size_t)hkv * (128 * 2048) + (KT) * 64; \
    _Pragma("unroll")                                                         \
    for (int i_ = 0; i_ < 4; ++i_) {                                          \
      const int c_ = wave * 4 + i_;                                           \
      const int row_ = c_ * 8 + (lane >> 3);                                  \
      const int cb_ = ((lane & 7) * 16) ^ ((row_ & 7) << 4);                  \
      async_cp16(src + (size_t)row_ * 2048 + (cb_ >> 1), (char*)Vs[B] + c_ * 1024); \
    }                                                                         \
  }

  STAGE_K(0, 0); STAGE_V(0, 0);
  __syncthreads();

  for (int kt = 0; kt < nt; ++kt) {
    const int kv0 = kt * 64;
    const int cur = kt & 1;
    if (kt + 1 < nt) { STAGE_K(kt + 1, cur ^ 1); STAGE_V(kt + 1, cur ^ 1); }

    if (kv0 < q0w + 32) {
      f32x16 s0 = {}, s1 = {};
#pragma unroll
      for (int ks = 0; ks < 8; ++ks) {
        const int gcb = 32 * ks + 16 * hi;
        const int sw = (col & 7) << 4;
        const s16x8 k0 = *(const s16x8*)((const char*)Ks[cur] + col * 256 + (gcb ^ sw));
        const s16x8 k1 = *(const s16x8*)((const char*)Ks[cur] + (32 + col) * 256 + (gcb ^ sw));
        s0 = __builtin_amdgcn_mfma_f32_32x32x16_bf16(k0, qf[ks], s0, 0, 0, 0);
        s1 = __builtin_amdgcn_mfma_f32_32x32x16_bf16(k1, qf[ks], s1, 0, 0, 0);
      }

      const int qg = q0w + col;
      if (kv0 + 63 > q0w) {
#pragma unroll
        for (int r = 0; r < 16; ++r) {
          const int kvl = (r & 3) + 8 * (r >> 2) + 4 * hi;
          if (kv0 + kvl > qg)      s0[r] = -3e30f;
          if (kv0 + 32 + kvl > qg) s1[r] = -3e30f;
        }
      }

      float mxl = s0[0];
#pragma unroll
      for (int r = 1; r < 16; ++r) mxl = fmaxf(mxl, s0[r]);
#pragma unroll
      for (int r = 0; r < 16; ++r) mxl = fmaxf(mxl, s1[r]);
      const float mxf = fmaxf(mxl, __shfl_xor(mxl, 32));
      if (__any(mxf > m_s + 8.0f)) {
        const float mn = fmaxf(m_s, mxf);
        const float scl = __expf(m_s - mn);
        m_s = mn;
        l_s *= scl;
#pragma unroll
        for (int r = 0; r < 16; ++r) {
          const int qq = (r & 3) + 8 * (r >> 2) + 4 * hi;
          const float sr = __int_as_float(
              __builtin_amdgcn_ds_bpermute(qq * 4, __float_as_int(scl)));
          oacc[0][r] *= sr; oacc[1][r] *= sr; oacc[2][r] *= sr; oacc[3][r] *= sr;
        }
      }
      float lsum = 0.0f;
#pragma unroll
      for (int r = 0; r < 16; ++r) {
        s0[r] = __expf(s0[r] - m_s); s1[r] = __expf(s1[r] - m_s);
        lsum += s0[r] + s1[r];
      }
      lsum += __shfl_xor(lsum, 32);
      l_s += lsum;

#define PV_STEP(KS, PP)                                                       \
      {                                                                       \
        const int rb2 = 8 * ((KS) & 1);                                       \
        const uint32_t g0a = cvt_pk_bf16(PP[rb2 + 0], PP[rb2 + 1]);           \
        const uint32_t g0b = cvt_pk_bf16(PP[rb2 + 2], PP[rb2 + 3]);           \
        const uint32_t g1a = cvt_pk_bf16(PP[rb2 + 4], PP[rb2 + 5]);           \
        const uint32_t g1b = cvt_pk_bf16(PP[rb2 + 6], PP[rb2 + 7]);           \
        const uint32_t sa = hi ? g0a : g1a, sb = hi ? g0b : g1b;              \
        const uint32_t ra = (uint32_t)__shfl_xor((int)sa, 32);                \
        const uint32_t rb_ = (uint32_t)__shfl_xor((int)sb, 32);               \
        frag_u af;                                                            \
        af.w[0] = hi ? ra  : g0a; af.w[1] = hi ? rb_ : g0b;                   \
        af.w[2] = hi ? g1a : ra;  af.w[3] = hi ? g1b : rb_;                   \
        const int gcb = 32 * (KS) + 16 * hi;                                  \
        const int vsw = (col & 7) << 4;                                       \
        _Pragma("unroll")                                                     \
        for (int db = 0; db < 4; ++db) {                                      \
          const s16x8 bv = *(const s16x8*)((const char*)Vs[cur] +             \
              (db * 32 + col) * 128 + (gcb ^ vsw));                           \
          oacc[db] = __builtin_amdgcn_mfma_f32_32x32x16_bf16(af.f, bv, oacc[db], 0, 0, 0); \
        }                                                                     \
      }
      PV_STEP(0, s0); PV_STEP(1, s0); PV_STEP(2, s1); PV_STEP(3, s1);
#undef PV_STEP
    }
    __syncthreads();
  }

  const float linv = 1.0f / l_s;
#pragma unroll
  for (int r = 0; r < 16; ++r) {
    const int qq = (r & 3) + 8 * (r >> 2) + 4 * hi;
    const float lr = __int_as_float(
        __builtin_amdgcn_ds_bpermute(qq * 4, __float_as_int(linv)));
    unsigned short* orow = ob + (size_t)(q0w + qq) * 4096 + h * 128 + col;
#pragma unroll
    for (int db = 0; db < 4; ++db)
      orow[db * 32] = f2bf(oacc[db][r] * lr);
  }
#undef STAGE_K
#undef STAGE_V
}

// ------------------------------ launch ------------------------------
extern "C" void kernel_launch(void* const* d_in, const int* in_sizes, int n_in,
                              void* d_out, int out_size, void* d_ws, size_t ws_size,
                              hipStream_t stream) {
  const float* x     = (const float*)d_in[0];
  const float* cos_f = (const float*)d_in[1];
  const float* sin_f = (const float*)d_in[2];
  const float* wq = (const float*)d_in[4];
  const float* wk = (const float*)d_in[5];
  const float* wv = (const float*)d_in[6];
  const float* wo = (const float*)d_in[7];
  float* out = (float*)d_out;

  char* ws = (char*)d_ws;
  unsigned short* xb    = (unsigned short*)(ws);                 // 2048x4096 bf16
  unsigned short* wqkvb = (unsigned short*)(ws + 16777216);      // 6144x4096 bf16
  unsigned short* wob   = (unsigned short*)(ws + 67108864);      // 4096x4096 bf16
  float*          xqkv  = (float*)(ws + 100663296);              // 2048x6144 fp32
  unsigned short* qb    = (unsigned short*)(ws + 150994944);     // 2048x4096 bf16
  unsigned short* kb    = (unsigned short*)(ws + 167772160);     // 2048x1024 bf16
  unsigned short* vtb   = (unsigned short*)(ws + 171966464);     // [8*128][2048] bf16
  unsigned short* attno = (unsigned short*)(ws + 176160768);     // 2048x4096 bf16

  cast_f32_bf16<<<dim3(8192), 256, 0, stream>>>(x, xb, 2097152);
  cast_f32_bf16<<<dim3(16384), 256, 0, stream>>>(wq, wqkvb, 4194304);
  cast_f32_bf16<<<dim3(4096), 256, 0, stream>>>(wk, wqkvb + 16777216, 1048576);
  cast_f32_bf16<<<dim3(4096), 256, 0, stream>>>(wv, wqkvb + 20971520, 1048576);
  cast_f32_bf16<<<dim3(16384), 256, 0, stream>>>(wo, wob, 4194304);

  // fused QKV projection: [2048x4096] x [6144x4096]^T -> [2048x6144] fp32
  // 16 m x 32 n tiles of 128x192 = 512 blocks of 256 thr (2 blocks/CU)
  gemmF<64, 192, 6, 6><<<dim3(512), 256, 0, stream>>>(xb, wqkvb, xqkv, 6144);

  rope_q_kern<<<dim3(4096), 256, 0, stream>>>(xqkv, cos_f, sin_f, qb);
  rope_k_kern<<<dim3(1024), 256, 0, stream>>>(xqkv, cos_f, sin_f, out + 8388608, kb);
  vtrans_kern<<<dim3(32, 16), 256, 0, stream>>>(xqkv, out + 12582912, vtb);

  (void)hipMemsetAsync(out + 10485760, 0, 8388608, stream);
  (void)hipMemsetAsync(out + 14680064, 0, 8388608, stream);

  attn_fwd2<<<dim3(16, 32), 256, 0, stream>>>(qb, kb, vtb, attno);

  // output projection: [2048x4096] x [4096x4096]^T -> d_out directly
  // 16 m x 32 n tiles of 128x128 = 512 blocks of 256 thr (2 blocks/CU)
  gemmF<64, 128, 4, 4><<<dim3(512), 256, 0, stream>>>(attno, wob, out, 4096);
}

// Round 13
// 292.952 us; speedup vs baseline: 1.4754x; 1.0719x over previous
//
#include <hip/hip_runtime.h>
#include <stdint.h>

// Problem constants
#define S_LEN 2048
#define DIM_   4096
#define NH_    32
#define NKV_   8
#define HD_    128
#define QK_SCALE 0.08838834764831845f   // 1/sqrt(128)

typedef __attribute__((ext_vector_type(8)))  short  s16x8;   // 8 bf16 (4 VGPRs) MFMA frag
typedef __attribute__((ext_vector_type(4)))  float  f32x4;   // 16x16 MFMA accum
typedef __attribute__((ext_vector_type(16))) float  f32x16;  // 32x32 MFMA accum
typedef __attribute__((ext_vector_type(8))) unsigned short u16x8;
typedef __attribute__((ext_vector_type(4))) unsigned short u16x4;

union frag_u { s16x8 f; uint32_t w[4]; };

__device__ __forceinline__ unsigned short f2bf(float f) {
  union { float f; uint32_t u; } v; v.f = f;
  return (unsigned short)((v.u + 0x7fffu + ((v.u >> 16) & 1u)) >> 16);   // RNE
}

__device__ __forceinline__ float bf2f(unsigned short u) {
  union { uint32_t u; float f; } v; v.u = (uint32_t)u << 16;
  return v.f;
}

__device__ __forceinline__ uint32_t cvt_pk_bf16(float lo, float hi2) {
  uint32_t r;
  asm volatile("v_cvt_pk_bf16_f32 %0, %1, %2" : "=v"(r) : "v"(lo), "v"(hi2));
  return r;
}

// async global->LDS, 16B per lane. LDS dest is wave-uniform base + lane*16.
__device__ __forceinline__ void async_cp16(const void* g, void* l) {
  __builtin_amdgcn_global_load_lds(
      (const __attribute__((address_space(1))) unsigned int*)g,
      (__attribute__((address_space(3))) unsigned int*)l, 16, 0, 0);
}

#define WAITV(n) asm volatile("s_waitcnt vmcnt(" #n ")" ::: "memory")

// ------------- fused cast fp32 -> bf16 for all 5 inputs -------------
// float4-index ranges: x [0,2097152) | wq [..,6291456) | wk [..,7340032)
// | wv [..,8388608) | wo [..,12582912)
__global__ __launch_bounds__(256) void cast_all(
    const float* __restrict__ x,  const float* __restrict__ wq,
    const float* __restrict__ wk, const float* __restrict__ wv,
    const float* __restrict__ wo, unsigned short* __restrict__ xb,
    unsigned short* __restrict__ wqkvb, unsigned short* __restrict__ wob) {
  const int i = blockIdx.x * 256 + threadIdx.x;
  const float* src; unsigned short* dst; int off;
  if (i < 2097152)      { src = x;  dst = xb;               off = i; }
  else if (i < 6291456) { src = wq; dst = wqkvb;            off = i - 2097152; }
  else if (i < 7340032) { src = wk; dst = wqkvb + 16777216; off = i - 6291456; }
  else if (i < 8388608) { src = wv; dst = wqkvb + 20971520; off = i - 7340032; }
  else                  { src = wo; dst = wob;              off = i - 8388608; }
  const float4 v = ((const float4*)src)[off];
  u16x4 o; o[0] = f2bf(v.x); o[1] = f2bf(v.y); o[2] = f2bf(v.z); o[3] = f2bf(v.w);
  ((u16x4*)dst)[off] = o;
}

// == 128 x NTILE_N 2-phase GEMM, 4 waves x (64 x NTILE_N/2), rotate-slot ====
// Structure identical to R12 (proven); only the epilogue gained a BF16OUT
// path (xqkv intermediate now bf16: halves C-write + downstream read bytes).
// Sync skeleton / ledger unchanged -- see R12 comments.
template <int NT, int NTILE_N, int NCF, int NBCH, int BF16OUT>
__global__ __launch_bounds__(256, 2) void gemmF(
    const unsigned short* __restrict__ A, const unsigned short* __restrict__ B,
    void* __restrict__ C, int ldc) {
  constexpr int BUFB = 16384 + NTILE_N * 128;   // bytes per buffer
  __shared__ unsigned char lds[2 * BUFB];

  const int bid = blockIdx.x;
  const int idx = (bid & 7) * 64 + (bid >> 3);   // XCD-contiguous
  const int m = idx & 15, n = idx >> 4;
  const int m0 = m * 128, n0 = n * NTILE_N;

  const int tid = threadIdx.x;
  const int wave = tid >> 6, lane = tid & 63;
  const int wm = wave >> 1, wn = wave & 1;
  const int fr = lane & 15, g = lane >> 4;

  // fragment LDS offsets (rotate-slot read side); offA includes wm half
  int offA[4][2], offB[NCF][2];
#pragma unroll
  for (int rf = 0; rf < 4; ++rf)
#pragma unroll
    for (int kk = 0; kk < 2; ++kk)
      offA[rf][kk] = wm * 8192 + (rf * 16 + fr) * 128 + (((kk * 4 + g + fr) & 7) << 4);
#pragma unroll
  for (int cf = 0; cf < NCF; ++cf)
#pragma unroll
    for (int kk = 0; kk < 2; ++kk)
      offB[cf][kk] = (wn * NCF * 16 + cf * 16 + fr) * 128 + (((kk * 4 + g + fr) & 7) << 4);

  // staging source offsets (inverse rotate-slot on global source); 256 thr
  const int srk = (((tid & 7) - (tid >> 3)) & 7) * 8;
  uint32_t aoff[2][2];     // [A half][iter of 32 rows]
  uint32_t boff[NBCH];     // [B chunk of 32 rows]
#pragma unroll
  for (int h = 0; h < 2; ++h)
#pragma unroll
    for (int i = 0; i < 2; ++i)
      aoff[h][i] = (uint32_t)((m0 + h * 64 + i * 32 + (tid >> 3)) * 4096 + srk);
#pragma unroll
  for (int i = 0; i < NBCH; ++i)
    boff[i] = (uint32_t)((n0 + i * 32 + (tid >> 3)) * 4096 + srk);

  f32x4 acc[4][NCF] = {};   // [rf][cf]
  s16x8 fa[4][2], fbk[NCF];

#define STGA(T, BUF)                                                          \
  { _Pragma("unroll") for (int h_ = 0; h_ < 2; ++h_)                          \
      _Pragma("unroll") for (int i_ = 0; i_ < 2; ++i_)                        \
        async_cp16(A + aoff[h_][i_] + (size_t)(T) * 64,                       \
                   (char*)lds + (BUF) * BUFB + h_ * 8192 + i_ * 4096 + tid * 16); }
#define STGB(T, BUF)                                                          \
  { _Pragma("unroll") for (int i_ = 0; i_ < NBCH; ++i_)                       \
      async_cp16(B + boff[i_] + (size_t)(T) * 64,                             \
                 (char*)lds + (BUF) * BUFB + 16384 + i_ * 4096 + tid * 16); }
#define LDA2(P)                                                               \
  { _Pragma("unroll") for (int rf = 0; rf < 4; ++rf)                          \
      _Pragma("unroll") for (int kk = 0; kk < 2; ++kk)                        \
        fa[rf][kk] = *(const s16x8*)((char*)lds + (P) * BUFB + offA[rf][kk]); }
#define LDBK(KK, P)                                                           \
  { _Pragma("unroll") for (int cf = 0; cf < NCF; ++cf)                        \
      fbk[cf] = *(const s16x8*)((char*)lds + (P) * BUFB + 16384 + offB[cf][KK]); }
#define BARLG()                                                               \
  __builtin_amdgcn_s_barrier();                                               \
  asm volatile("s_waitcnt lgkmcnt(0)" ::: "memory");                          \
  __builtin_amdgcn_sched_barrier(0);
#define MFK(KK)                                                               \
  __builtin_amdgcn_s_setprio(1);                                              \
  { _Pragma("unroll") for (int rf = 0; rf < 4; ++rf)                          \
      _Pragma("unroll") for (int cf = 0; cf < NCF; ++cf)                      \
        acc[rf][cf] = __builtin_amdgcn_mfma_f32_16x16x32_bf16(                \
            fa[rf][KK], fbk[cf], acc[rf][cf], 0, 0, 0); }                     \
  __builtin_amdgcn_s_setprio(0);

#define GROUPF(J, P, DO1, DO2, GATE)                                          \
  {                                                                           \
    LDA2(P); LDBK(0, P);                                                      \
    if (DO1) { STGB((J) + 1, (P) ^ 1); }                                      \
    BARLG(); MFK(0);                                                          \
    __builtin_amdgcn_s_barrier();                                             \
    LDBK(1, P);                                                               \
    if (DO2) { STGA((J) + 2, P); }                                            \
    BARLG(); MFK(1);                                                          \
    GATE;                                                                     \
    __builtin_amdgcn_s_barrier();                                             \
  }

  // prologue: tile0 A+B -> buf0; tile1 A -> buf1 (B(1) staged at grp0 p0)
  STGA(0, 0); STGB(0, 0); STGA(1, 1);
  WAITV(4);
  __builtin_amdgcn_s_barrier();

  for (int j = 0; j + 3 < NT; j += 2) {
    GROUPF(j, 0, true, true, WAITV(4));
    GROUPF(j + 1, 1, true, true, WAITV(4));
  }
  GROUPF(NT - 2, 0, true, false, WAITV(0));
  GROUPF(NT - 1, 1, false, false, );

  // epilogue: C[m0 + wm*64 + rf*16 + g*4 + r][n0 + wn*NCF*16 + cf*16 + fr]
#pragma unroll
  for (int rf = 0; rf < 4; ++rf)
#pragma unroll
    for (int cf = 0; cf < NCF; ++cf) {
      const size_t rbase = (size_t)(m0 + wm * 64 + rf * 16 + g * 4) * ldc
                         + (n0 + wn * NCF * 16 + cf * 16 + fr);
      if constexpr (BF16OUT) {
        unsigned short* cp = (unsigned short*)C + rbase;
#pragma unroll
        for (int r = 0; r < 4; ++r) cp[(size_t)r * ldc] = f2bf(acc[rf][cf][r]);
      } else {
        float* cp = (float*)C + rbase;
#pragma unroll
        for (int r = 0; r < 4; ++r) cp[(size_t)r * ldc] = acc[rf][cf][r];
      }
    }
#undef STGA
#undef STGB
#undef LDA2
#undef LDBK
#undef BARLG
#undef MFK
#undef GROUPF
}

// ------- RoPE on Q (folds QK scale), bf16 xqkv -> bf16 qb -----------
__global__ __launch_bounds__(256) void rope_q_kern(
    const unsigned short* __restrict__ xqkv, const float* __restrict__ cos_f,
    const float* __restrict__ sin_f, unsigned short* __restrict__ qb) {
  const int gid = blockIdx.x * 256 + threadIdx.x;
  const int e0 = gid * 8;
  const int s = e0 >> 12;
  const int col = e0 & 4095;
  const int i0 = (col & 127) >> 1;
  const u16x8 uv = *(const u16x8*)(xqkv + (size_t)s * 6144 + col);
  float f[8];
#pragma unroll
  for (int j = 0; j < 8; ++j) f[j] = bf2f(uv[j]);
  const float4 c  = *(const float4*)(cos_f + s * 64 + i0);
  const float4 sn = *(const float4*)(sin_f + s * 64 + i0);
  u16x8 o;
  o[0] = f2bf((f[0] * c.x - f[1] * sn.x) * QK_SCALE);
  o[1] = f2bf((f[0] * sn.x + f[1] * c.x) * QK_SCALE);
  o[2] = f2bf((f[2] * c.y - f[3] * sn.y) * QK_SCALE);
  o[3] = f2bf((f[2] * sn.y + f[3] * c.y) * QK_SCALE);
  o[4] = f2bf((f[4] * c.z - f[5] * sn.z) * QK_SCALE);
  o[5] = f2bf((f[4] * sn.z + f[5] * c.z) * QK_SCALE);
  o[6] = f2bf((f[6] * c.w - f[7] * sn.w) * QK_SCALE);
  o[7] = f2bf((f[6] * sn.w + f[7] * c.w) * QK_SCALE);
  *(u16x8*)(qb + e0) = o;
}

// ---- RoPE on K: bf16 xqkv -> fp32 cache out + bf16 attn K ----------
__global__ __launch_bounds__(256) void rope_k_kern(
    const unsigned short* __restrict__ xqkv, const float* __restrict__ cos_f,
    const float* __restrict__ sin_f, float* __restrict__ ck, unsigned short* __restrict__ kb) {
  const int gid = blockIdx.x * 256 + threadIdx.x;
  const int e0 = gid * 8;
  const int s = e0 >> 10;
  const int col = e0 & 1023;
  const int i0 = (col & 127) >> 1;
  const u16x8 uv = *(const u16x8*)(xqkv + (size_t)s * 6144 + 4096 + col);
  float f[8];
#pragma unroll
  for (int j = 0; j < 8; ++j) f[j] = bf2f(uv[j]);
  const float4 c  = *(const float4*)(cos_f + s * 64 + i0);
  const float4 sn = *(const float4*)(sin_f + s * 64 + i0);
  const float r0 = f[0] * c.x - f[1] * sn.x, r1 = f[0] * sn.x + f[1] * c.x;
  const float r2 = f[2] * c.y - f[3] * sn.y, r3 = f[2] * sn.y + f[3] * c.y;
  const float r4 = f[4] * c.z - f[5] * sn.z, r5 = f[4] * sn.z + f[5] * c.z;
  const float r6 = f[6] * c.w - f[7] * sn.w, r7 = f[6] * sn.w + f[7] * c.w;
  float4 o1; o1.x = r0; o1.y = r1; o1.z = r2; o1.w = r3;
  float4 o2; o2.x = r4; o2.y = r5; o2.z = r6; o2.w = r7;
  *(float4*)(ck + (size_t)s * 1024 + col) = o1;
  *(float4*)(ck + (size_t)s * 1024 + col + 4) = o2;
  u16x8 o;
  o[0] = f2bf(r0); o[1] = f2bf(r1); o[2] = f2bf(r2); o[3] = f2bf(r3);
  o[4] = f2bf(r4); o[5] = f2bf(r5); o[6] = f2bf(r6); o[7] = f2bf(r7);
  *(u16x8*)(kb + (size_t)s * 1024 + col) = o;
}

// -- V: bf16 xqkv -> fp32 cache out (coalesced) + bf16 V^T [NKV*HD][S] --
__global__ __launch_bounds__(256) void vtrans_kern(
    const unsigned short* __restrict__ xqkv, float* __restrict__ cv,
    unsigned short* __restrict__ vtb) {
  __shared__ float tile[64][65];
  const int st = blockIdx.x * 64;
  const int ct = blockIdx.y * 64;
  const int tid = threadIdx.x;
#pragma unroll
  for (int j = 0; j < 16; ++j) {
    const int lin = tid + j * 256;
    const int si = lin >> 6, ci = lin & 63;
    const float v = bf2f(xqkv[(size_t)(st + si) * 6144 + 5120 + ct + ci]);
    cv[(size_t)(st + si) * 1024 + ct + ci] = v;
    tile[si][ci] = v;
  }
  __syncthreads();
#pragma unroll
  for (int j = 0; j < 16; ++j) {
    const int lin = tid + j * 256;
    const int co = lin >> 6, so = lin & 63;
    vtb[(size_t)(ct + co) * 2048 + st + so] = f2bf(tile[so][co]);
  }
}

// ---------------- flash attention v2 (unchanged) --------------------
__global__ __launch_bounds__(256, 2) void attn_fwd2(
    const unsigned short* __restrict__ qb, const unsigned short* __restrict__ kb,
    const unsigned short* __restrict__ vtb, unsigned short* __restrict__ ob) {
  __shared__ unsigned short Ks[2][64 * 128];
  __shared__ unsigned short Vs[2][128 * 64];
  const int bx = blockIdx.x;
  const int h  = blockIdx.y;
  const int hkv = h >> 2;
  const int g = (bx & 1) ? (15 - (bx >> 1)) : (bx >> 1);
  const int qtile = (h < 16) ? g : (15 - g);
  const int q0 = qtile * 128;
  const int tid = threadIdx.x, wave = tid >> 6, lane = tid & 63;
  const int col = lane & 31;
  const int hi  = lane >> 5;
  const int q0w = q0 + wave * 32;
  const int nt = (q0 >> 6) + 2;

  s16x8 qf[8];
  {
    const unsigned short* qrow = qb + (size_t)(q0w + col) * 4096 + h * 128 + hi * 8;
#pragma unroll
    for (int ks = 0; ks < 8; ++ks) qf[ks] = *(const s16x8*)(qrow + ks * 16);
  }

  f32x16 oacc[4] = {};
  float m_s = -3e30f, l_s = 0.0f;

#define STAGE_K(KT, B)                                                        \
  {                                                                           \
    const unsigned short* src = kb + (size_t)((KT) * 64) * 1024 + hkv * 128;  \
    _Pragma("unroll")                                                         \
    for (int i_ = 0; i_ < 4; ++i_) {                                          \
      const int c_ = wave * 4 + i_;                                           \
      const int row_ = c_ * 4 + (lane >> 4);                                  \
      const int cb_ = ((lane & 15) * 16) ^ ((row_ & 7) << 4);                 \
      async_cp16(src + (size_t)row_ * 1024 + (cb_ >> 1), (char*)Ks[B] + c_ * 1024); \
    }                                                                         \
  }
#define STAGE_V(KT, B)                                                        \
  {                                                                           \
    const unsigned short* src = vtb + (size_t)hkv * (128 * 2048) + (KT) * 64; \
    _Pragma("unroll")                                                         \
    for (int i_ = 0; i_ < 4; ++i_) {                                          \
      const int c_ = wave * 4 + i_;                                           \
      const int row_ = c_ * 8 + (lane >> 3);                                  \
      const int cb_ = ((lane & 7) * 16) ^ ((row_ & 7) << 4);                  \
      async_cp16(src + (size_t)row_ * 2048 + (cb_ >> 1), (char*)Vs[B] + c_ * 1024); \
    }                                                                         \
  }

  STAGE_K(0, 0); STAGE_V(0, 0);
  __syncthreads();

  for (int kt = 0; kt < nt; ++kt) {
    const int kv0 = kt * 64;
    const int cur = kt & 1;
    if (kt + 1 < nt) { STAGE_K(kt + 1, cur ^ 1); STAGE_V(kt + 1, cur ^ 1); }

    if (kv0 < q0w + 32) {
      f32x16 s0 = {}, s1 = {};
#pragma unroll
      for (int ks = 0; ks < 8; ++ks) {
        const int gcb = 32 * ks + 16 * hi;
        const int sw = (col & 7) << 4;
        const s16x8 k0 = *(const s16x8*)((const char*)Ks[cur] + col * 256 + (gcb ^ sw));
        const s16x8 k1 = *(const s16x8*)((const char*)Ks[cur] + (32 + col) * 256 + (gcb ^ sw));
        s0 = __builtin_amdgcn_mfma_f32_32x32x16_bf16(k0, qf[ks], s0, 0, 0, 0);
        s1 = __builtin_amdgcn_mfma_f32_32x32x16_bf16(k1, qf[ks], s1, 0, 0, 0);
      }

      const int qg = q0w + col;
      if (kv0 + 63 > q0w) {
#pragma unroll
        for (int r = 0; r < 16; ++r) {
          const int kvl = (r & 3) + 8 * (r >> 2) + 4 * hi;
          if (kv0 + kvl > qg)      s0[r] = -3e30f;
          if (kv0 + 32 + kvl > qg) s1[r] = -3e30f;
        }
      }

      float mxl = s0[0];
#pragma unroll
      for (int r = 1; r < 16; ++r) mxl = fmaxf(mxl, s0[r]);
#pragma unroll
      for (int r = 0; r < 16; ++r) mxl = fmaxf(mxl, s1[r]);
      const float mxf = fmaxf(mxl, __shfl_xor(mxl, 32));
      if (__any(mxf > m_s + 8.0f)) {
        const float mn = fmaxf(m_s, mxf);
        const float scl = __expf(m_s - mn);
        m_s = mn;
        l_s *= scl;
#pragma unroll
        for (int r = 0; r < 16; ++r) {
          const int qq = (r & 3) + 8 * (r >> 2) + 4 * hi;
          const float sr = __int_as_float(
              __builtin_amdgcn_ds_bpermute(qq * 4, __float_as_int(scl)));
          oacc[0][r] *= sr; oacc[1][r] *= sr; oacc[2][r] *= sr; oacc[3][r] *= sr;
        }
      }
      float lsum = 0.0f;
#pragma unroll
      for (int r = 0; r < 16; ++r) {
        s0[r] = __expf(s0[r] - m_s); s1[r] = __expf(s1[r] - m_s);
        lsum += s0[r] + s1[r];
      }
      lsum += __shfl_xor(lsum, 32);
      l_s += lsum;

#define PV_STEP(KS, PP)                                                       \
      {                                                                       \
        const int rb2 = 8 * ((KS) & 1);                                       \
        const uint32_t g0a = cvt_pk_bf16(PP[rb2 + 0], PP[rb2 + 1]);           \
        const uint32_t g0b = cvt_pk_bf16(PP[rb2 + 2], PP[rb2 + 3]);           \
        const uint32_t g1a = cvt_pk_bf16(PP[rb2 + 4], PP[rb2 + 5]);           \
        const uint32_t g1b = cvt_pk_bf16(PP[rb2 + 6], PP[rb2 + 7]);           \
        const uint32_t sa = hi ? g0a : g1a, sb = hi ? g0b : g1b;              \
        const uint32_t ra = (uint32_t)__shfl_xor((int)sa, 32);                \
        const uint32_t rb_ = (uint32_t)__shfl_xor((int)sb, 32);               \
        frag_u af;                                                            \
        af.w[0] = hi ? ra  : g0a; af.w[1] = hi ? rb_ : g0b;                   \
        af.w[2] = hi ? g1a : ra;  af.w[3] = hi ? g1b : rb_;                   \
        const int gcb = 32 * (KS) + 16 * hi;                                  \
        const int vsw = (col & 7) << 4;                                       \
        _Pragma("unroll")                                                     \
        for (int db = 0; db < 4; ++db) {                                      \
          const s16x8 bv = *(const s16x8*)((const char*)Vs[cur] +             \
              (db * 32 + col) * 128 + (gcb ^ vsw));                           \
          oacc[db] = __builtin_amdgcn_mfma_f32_32x32x16_bf16(af.f, bv, oacc[db], 0, 0, 0); \
        }                                                                     \
      }
      PV_STEP(0, s0); PV_STEP(1, s0); PV_STEP(2, s1); PV_STEP(3, s1);
#undef PV_STEP
    }
    __syncthreads();
  }

  const float linv = 1.0f / l_s;
#pragma unroll
  for (int r = 0; r < 16; ++r) {
    const int qq = (r & 3) + 8 * (r >> 2) + 4 * hi;
    const float lr = __int_as_float(
        __builtin_amdgcn_ds_bpermute(qq * 4, __float_as_int(linv)));
    unsigned short* orow = ob + (size_t)(q0w + qq) * 4096 + h * 128 + col;
#pragma unroll
    for (int db = 0; db < 4; ++db)
      orow[db * 32] = f2bf(oacc[db][r] * lr);
  }
#undef STAGE_K
#undef STAGE_V
}

// ------------------------------ launch ------------------------------
extern "C" void kernel_launch(void* const* d_in, const int* in_sizes, int n_in,
                              void* d_out, int out_size, void* d_ws, size_t ws_size,
                              hipStream_t stream) {
  const float* x     = (const float*)d_in[0];
  const float* cos_f = (const float*)d_in[1];
  const float* sin_f = (const float*)d_in[2];
  const float* wq = (const float*)d_in[4];
  const float* wk = (const float*)d_in[5];
  const float* wv = (const float*)d_in[6];
  const float* wo = (const float*)d_in[7];
  float* out = (float*)d_out;

  char* ws = (char*)d_ws;
  unsigned short* xb    = (unsigned short*)(ws);                 // 2048x4096 bf16
  unsigned short* wqkvb = (unsigned short*)(ws + 16777216);      // 6144x4096 bf16
  unsigned short* wob   = (unsigned short*)(ws + 67108864);      // 4096x4096 bf16
  unsigned short* xqkvb = (unsigned short*)(ws + 100663296);     // 2048x6144 bf16
  unsigned short* qb    = (unsigned short*)(ws + 150994944);     // 2048x4096 bf16
  unsigned short* kb    = (unsigned short*)(ws + 167772160);     // 2048x1024 bf16
  unsigned short* vtb   = (unsigned short*)(ws + 171966464);     // [8*128][2048] bf16
  unsigned short* attno = (unsigned short*)(ws + 176160768);     // 2048x4096 bf16

  // all fp32->bf16 casts in one dispatch (12582912 float4 items)
  cast_all<<<dim3(49152), 256, 0, stream>>>(x, wq, wk, wv, wo, xb, wqkvb, wob);

  // fused QKV projection: [2048x4096] x [6144x4096]^T -> [2048x6144] bf16
  // 16 m x 32 n tiles of 128x192 = 512 blocks of 256 thr (2 blocks/CU)
  gemmF<64, 192, 6, 6, 1><<<dim3(512), 256, 0, stream>>>(xb, wqkvb, xqkvb, 6144);

  rope_q_kern<<<dim3(4096), 256, 0, stream>>>(xqkvb, cos_f, sin_f, qb);
  rope_k_kern<<<dim3(1024), 256, 0, stream>>>(xqkvb, cos_f, sin_f, out + 8388608, kb);
  vtrans_kern<<<dim3(32, 16), 256, 0, stream>>>(xqkvb, out + 12582912, vtb);

  (void)hipMemsetAsync(out + 10485760, 0, 8388608, stream);
  (void)hipMemsetAsync(out + 14680064, 0, 8388608, stream);

  attn_fwd2<<<dim3(16, 32), 256, 0, stream>>>(qb, kb, vtb, attno);

  // output projection: [2048x4096] x [4096x4096]^T -> d_out fp32 directly
  gemmF<64, 128, 4, 4, 0><<<dim3(512), 256, 0, stream>>>(attno, wob, out, 4096);
}

// Round 14
// 292.110 us; speedup vs baseline: 1.4797x; 1.0029x over previous
//
#include <hip/hip_runtime.h>
#include <stdint.h>

// Problem constants
#define S_LEN 2048
#define DIM_   4096
#define NH_    32
#define NKV_   8
#define HD_    128
#define QK_SCALE 0.08838834764831845f   // 1/sqrt(128)

typedef __attribute__((ext_vector_type(8)))  short  s16x8;   // 8 bf16 (4 VGPRs) MFMA frag
typedef __attribute__((ext_vector_type(4)))  float  f32x4;   // 16x16 MFMA accum
typedef __attribute__((ext_vector_type(16))) float  f32x16;  // 32x32 MFMA accum
typedef __attribute__((ext_vector_type(8))) unsigned short u16x8;
typedef __attribute__((ext_vector_type(4))) unsigned short u16x4;

union frag_u { s16x8 f; uint32_t w[4]; };

__device__ __forceinline__ unsigned short f2bf(float f) {
  union { float f; uint32_t u; } v; v.f = f;
  return (unsigned short)((v.u + 0x7fffu + ((v.u >> 16) & 1u)) >> 16);   // RNE
}

__device__ __forceinline__ float bf2f(unsigned short u) {
  union { uint32_t u; float f; } v; v.u = (uint32_t)u << 16;
  return v.f;
}

__device__ __forceinline__ uint32_t cvt_pk_bf16(float lo, float hi2) {
  uint32_t r;
  asm volatile("v_cvt_pk_bf16_f32 %0, %1, %2" : "=v"(r) : "v"(lo), "v"(hi2));
  return r;
}

// async global->LDS, 16B per lane. LDS dest is wave-uniform base + lane*16.
__device__ __forceinline__ void async_cp16(const void* g, void* l) {
  __builtin_amdgcn_global_load_lds(
      (const __attribute__((address_space(1))) unsigned int*)g,
      (__attribute__((address_space(3))) unsigned int*)l, 16, 0, 0);
}

#define WAITV(n) asm volatile("s_waitcnt vmcnt(" #n ")" ::: "memory")

// ------------- fused cast fp32 -> bf16 for all 5 inputs -------------
__global__ __launch_bounds__(256) void cast_all(
    const float* __restrict__ x,  const float* __restrict__ wq,
    const float* __restrict__ wk, const float* __restrict__ wv,
    const float* __restrict__ wo, unsigned short* __restrict__ xb,
    unsigned short* __restrict__ wqkvb, unsigned short* __restrict__ wob) {
  const int i = blockIdx.x * 256 + threadIdx.x;
  const float* src; unsigned short* dst; int off;
  if (i < 2097152)      { src = x;  dst = xb;               off = i; }
  else if (i < 6291456) { src = wq; dst = wqkvb;            off = i - 2097152; }
  else if (i < 7340032) { src = wk; dst = wqkvb + 16777216; off = i - 6291456; }
  else if (i < 8388608) { src = wv; dst = wqkvb + 20971520; off = i - 7340032; }
  else                  { src = wo; dst = wob;              off = i - 8388608; }
  const float4 v = ((const float4*)src)[off];
  u16x4 o; o[0] = f2bf(v.x); o[1] = f2bf(v.y); o[2] = f2bf(v.z); o[3] = f2bf(v.w);
  ((u16x4*)dst)[off] = o;
}

// == 128 x NTILE_N 2-phase GEMM, 4 waves x (64 x NTILE_N/2), rotate-slot ====
// Structure identical to R12/R13 (proven). See prior round comments.
template <int NT, int NTILE_N, int NCF, int NBCH, int BF16OUT>
__global__ __launch_bounds__(256, 2) void gemmF(
    const unsigned short* __restrict__ A, const unsigned short* __restrict__ B,
    void* __restrict__ C, int ldc) {
  constexpr int BUFB = 16384 + NTILE_N * 128;   // bytes per buffer
  __shared__ unsigned char lds[2 * BUFB];

  const int bid = blockIdx.x;
  const int idx = (bid & 7) * 64 + (bid >> 3);   // XCD-contiguous
  const int m = idx & 15, n = idx >> 4;
  const int m0 = m * 128, n0 = n * NTILE_N;

  const int tid = threadIdx.x;
  const int wave = tid >> 6, lane = tid & 63;
  const int wm = wave >> 1, wn = wave & 1;
  const int fr = lane & 15, g = lane >> 4;

  int offA[4][2], offB[NCF][2];
#pragma unroll
  for (int rf = 0; rf < 4; ++rf)
#pragma unroll
    for (int kk = 0; kk < 2; ++kk)
      offA[rf][kk] = wm * 8192 + (rf * 16 + fr) * 128 + (((kk * 4 + g + fr) & 7) << 4);
#pragma unroll
  for (int cf = 0; cf < NCF; ++cf)
#pragma unroll
    for (int kk = 0; kk < 2; ++kk)
      offB[cf][kk] = (wn * NCF * 16 + cf * 16 + fr) * 128 + (((kk * 4 + g + fr) & 7) << 4);

  const int srk = (((tid & 7) - (tid >> 3)) & 7) * 8;
  uint32_t aoff[2][2];
  uint32_t boff[NBCH];
#pragma unroll
  for (int h = 0; h < 2; ++h)
#pragma unroll
    for (int i = 0; i < 2; ++i)
      aoff[h][i] = (uint32_t)((m0 + h * 64 + i * 32 + (tid >> 3)) * 4096 + srk);
#pragma unroll
  for (int i = 0; i < NBCH; ++i)
    boff[i] = (uint32_t)((n0 + i * 32 + (tid >> 3)) * 4096 + srk);

  f32x4 acc[4][NCF] = {};
  s16x8 fa[4][2], fbk[NCF];

#define STGA(T, BUF)                                                          \
  { _Pragma("unroll") for (int h_ = 0; h_ < 2; ++h_)                          \
      _Pragma("unroll") for (int i_ = 0; i_ < 2; ++i_)                        \
        async_cp16(A + aoff[h_][i_] + (size_t)(T) * 64,                       \
                   (char*)lds + (BUF) * BUFB + h_ * 8192 + i_ * 4096 + tid * 16); }
#define STGB(T, BUF)                                                          \
  { _Pragma("unroll") for (int i_ = 0; i_ < NBCH; ++i_)                       \
      async_cp16(B + boff[i_] + (size_t)(T) * 64,                             \
                 (char*)lds + (BUF) * BUFB + 16384 + i_ * 4096 + tid * 16); }
#define LDA2(P)                                                               \
  { _Pragma("unroll") for (int rf = 0; rf < 4; ++rf)                          \
      _Pragma("unroll") for (int kk = 0; kk < 2; ++kk)                        \
        fa[rf][kk] = *(const s16x8*)((char*)lds + (P) * BUFB + offA[rf][kk]); }
#define LDBK(KK, P)                                                           \
  { _Pragma("unroll") for (int cf = 0; cf < NCF; ++cf)                        \
      fbk[cf] = *(const s16x8*)((char*)lds + (P) * BUFB + 16384 + offB[cf][KK]); }
#define BARLG()                                                               \
  __builtin_amdgcn_s_barrier();                                               \
  asm volatile("s_waitcnt lgkmcnt(0)" ::: "memory");                          \
  __builtin_amdgcn_sched_barrier(0);
#define MFK(KK)                                                               \
  __builtin_amdgcn_s_setprio(1);                                              \
  { _Pragma("unroll") for (int rf = 0; rf < 4; ++rf)                          \
      _Pragma("unroll") for (int cf = 0; cf < NCF; ++cf)                      \
        acc[rf][cf] = __builtin_amdgcn_mfma_f32_16x16x32_bf16(                \
            fa[rf][KK], fbk[cf], acc[rf][cf], 0, 0, 0); }                     \
  __builtin_amdgcn_s_setprio(0);

#define GROUPF(J, P, DO1, DO2, GATE)                                          \
  {                                                                           \
    LDA2(P); LDBK(0, P);                                                      \
    if (DO1) { STGB((J) + 1, (P) ^ 1); }                                      \
    BARLG(); MFK(0);                                                          \
    __builtin_amdgcn_s_barrier();                                             \
    LDBK(1, P);                                                               \
    if (DO2) { STGA((J) + 2, P); }                                            \
    BARLG(); MFK(1);                                                          \
    GATE;                                                                     \
    __builtin_amdgcn_s_barrier();                                             \
  }

  STGA(0, 0); STGB(0, 0); STGA(1, 1);
  WAITV(4);
  __builtin_amdgcn_s_barrier();

  for (int j = 0; j + 3 < NT; j += 2) {
    GROUPF(j, 0, true, true, WAITV(4));
    GROUPF(j + 1, 1, true, true, WAITV(4));
  }
  GROUPF(NT - 2, 0, true, false, WAITV(0));
  GROUPF(NT - 1, 1, false, false, );

#pragma unroll
  for (int rf = 0; rf < 4; ++rf)
#pragma unroll
    for (int cf = 0; cf < NCF; ++cf) {
      const size_t rbase = (size_t)(m0 + wm * 64 + rf * 16 + g * 4) * ldc
                         + (n0 + wn * NCF * 16 + cf * 16 + fr);
      if constexpr (BF16OUT) {
        unsigned short* cp = (unsigned short*)C + rbase;
#pragma unroll
        for (int r = 0; r < 4; ++r) cp[(size_t)r * ldc] = f2bf(acc[rf][cf][r]);
      } else {
        float* cp = (float*)C + rbase;
#pragma unroll
        for (int r = 0; r < 4; ++r) cp[(size_t)r * ldc] = acc[rf][cf][r];
      }
    }
#undef STGA
#undef STGB
#undef LDA2
#undef LDBK
#undef BARLG
#undef MFK
#undef GROUPF
}

// ---- fused RoPE on Q and K: bf16 xqkv -> qb/kb (+fp32 cache_k) -----
// flattened [s][5120]: c<4096 -> Q (scale folded); c>=4096 -> K.
__global__ __launch_bounds__(256) void rope_qk_kern(
    const unsigned short* __restrict__ xqkv, const float* __restrict__ cos_f,
    const float* __restrict__ sin_f, unsigned short* __restrict__ qb,
    float* __restrict__ ck, unsigned short* __restrict__ kb) {
  const int gid = blockIdx.x * 256 + threadIdx.x;   // 2048*640 threads
  const int s = gid / 640;
  const int e0 = (gid - s * 640) * 8;               // within-row elem, mult of 8
  const int i0 = (e0 & 127) >> 1;
  const float4 c  = *(const float4*)(cos_f + s * 64 + i0);
  const float4 sn = *(const float4*)(sin_f + s * 64 + i0);
  const u16x8 uv = *(const u16x8*)(xqkv + (size_t)s * 6144 + e0);
  float f[8];
#pragma unroll
  for (int j = 0; j < 8; ++j) f[j] = bf2f(uv[j]);
  const float r0 = f[0] * c.x - f[1] * sn.x, r1 = f[0] * sn.x + f[1] * c.x;
  const float r2 = f[2] * c.y - f[3] * sn.y, r3 = f[2] * sn.y + f[3] * c.y;
  const float r4 = f[4] * c.z - f[5] * sn.z, r5 = f[4] * sn.z + f[5] * c.z;
  const float r6 = f[6] * c.w - f[7] * sn.w, r7 = f[6] * sn.w + f[7] * c.w;
  if (e0 < 4096) {
    u16x8 o;
    o[0] = f2bf(r0 * QK_SCALE); o[1] = f2bf(r1 * QK_SCALE);
    o[2] = f2bf(r2 * QK_SCALE); o[3] = f2bf(r3 * QK_SCALE);
    o[4] = f2bf(r4 * QK_SCALE); o[5] = f2bf(r5 * QK_SCALE);
    o[6] = f2bf(r6 * QK_SCALE); o[7] = f2bf(r7 * QK_SCALE);
    *(u16x8*)(qb + (size_t)s * 4096 + e0) = o;
  } else {
    const int col = e0 - 4096;
    float4 o1; o1.x = r0; o1.y = r1; o1.z = r2; o1.w = r3;
    float4 o2; o2.x = r4; o2.y = r5; o2.z = r6; o2.w = r7;
    *(float4*)(ck + (size_t)s * 1024 + col) = o1;
    *(float4*)(ck + (size_t)s * 1024 + col + 4) = o2;
    u16x8 o;
    o[0] = f2bf(r0); o[1] = f2bf(r1); o[2] = f2bf(r2); o[3] = f2bf(r3);
    o[4] = f2bf(r4); o[5] = f2bf(r5); o[6] = f2bf(r6); o[7] = f2bf(r7);
    *(u16x8*)(kb + (size_t)s * 1024 + col) = o;
  }
}

// -- V: bf16 xqkv -> fp32 cache out (coalesced) + bf16 V^T [NKV*HD][S] --
__global__ __launch_bounds__(256) void vtrans_kern(
    const unsigned short* __restrict__ xqkv, float* __restrict__ cv,
    unsigned short* __restrict__ vtb) {
  __shared__ float tile[64][65];
  const int st = blockIdx.x * 64;
  const int ct = blockIdx.y * 64;
  const int tid = threadIdx.x;
#pragma unroll
  for (int j = 0; j < 16; ++j) {
    const int lin = tid + j * 256;
    const int si = lin >> 6, ci = lin & 63;
    const float v = bf2f(xqkv[(size_t)(st + si) * 6144 + 5120 + ct + ci]);
    cv[(size_t)(st + si) * 1024 + ct + ci] = v;
    tile[si][ci] = v;
  }
  __syncthreads();
#pragma unroll
  for (int j = 0; j < 16; ++j) {
    const int lin = tid + j * 256;
    const int co = lin >> 6, so = lin & 63;
    vtb[(size_t)(ct + co) * 2048 + st + so] = f2bf(tile[so][co]);
  }
}

// ---------------- flash attention v3: XCD-local KV head groups ------
// 1D grid of 512. xcd = bid&7 -> heads 4*xcd..4*xcd+3 (one hkv per XCD,
// KV slice ~1MB fits that XCD's L2). slot -> balanced causal qtile.
// Inner loop identical to proven attn_fwd2.
__global__ __launch_bounds__(256, 2) void attn_fwd3(
    const unsigned short* __restrict__ qb, const unsigned short* __restrict__ kb,
    const unsigned short* __restrict__ vtb, unsigned short* __restrict__ ob) {
  __shared__ unsigned short Ks[2][64 * 128];
  __shared__ unsigned short Vs[2][128 * 64];
  const int bid = blockIdx.x;
  const int xcd = bid & 7;
  const int rem = bid >> 3;                 // 0..63
  const int h   = xcd * 4 + (rem & 3);      // hkv = xcd
  const int slot = rem >> 2;                // 0..15
  const int hkv = h >> 2;
  const int g = (slot & 1) ? (15 - (slot >> 1)) : (slot >> 1);
  const int qtile = (h < 16) ? g : (15 - g);
  const int q0 = qtile * 128;
  const int tid = threadIdx.x, wave = tid >> 6, lane = tid & 63;
  const int col = lane & 31;
  const int hi  = lane >> 5;
  const int q0w = q0 + wave * 32;
  const int nt = (q0 >> 6) + 2;

  s16x8 qf[8];
  {
    const unsigned short* qrow = qb + (size_t)(q0w + col) * 4096 + h * 128 + hi * 8;
#pragma unroll
    for (int ks = 0; ks < 8; ++ks) qf[ks] = *(const s16x8*)(qrow + ks * 16);
  }

  f32x16 oacc[4] = {};
  float m_s = -3e30f, l_s = 0.0f;

#define STAGE_K(KT, B)                                                        \
  {                                                                           \
    const unsigned short* src = kb + (size_t)((KT) * 64) * 1024 + hkv * 128;  \
    _Pragma("unroll")                                                         \
    for (int i_ = 0; i_ < 4; ++i_) {                                          \
      const int c_ = wave * 4 + i_;                                           \
      const int row_ = c_ * 4 + (lane >> 4);                                  \
      const int cb_ = ((lane & 15) * 16) ^ ((row_ & 7) << 4);                 \
      async_cp16(src + (size_t)row_ * 1024 + (cb_ >> 1), (char*)Ks[B] + c_ * 1024); \
    }                                                                         \
  }
#define STAGE_V(KT, B)                                                        \
  {                                                                           \
    const unsigned short* src = vtb + (size_t)hkv * (128 * 2048) + (KT) * 64; \
    _Pragma("unroll")                                                         \
    for (int i_ = 0; i_ < 4; ++i_) {                                          \
      const int c_ = wave * 4 + i_;                                           \
      const int row_ = c_ * 8 + (lane >> 3);                                  \
      const int cb_ = ((lane & 7) * 16) ^ ((row_ & 7) << 4);                  \
      async_cp16(src + (size_t)row_ * 2048 + (cb_ >> 1), (char*)Vs[B] + c_ * 1024); \
    }                                                                         \
  }

  STAGE_K(0, 0); STAGE_V(0, 0);
  __syncthreads();

  for (int kt = 0; kt < nt; ++kt) {
    const int kv0 = kt * 64;
    const int cur = kt & 1;
    if (kt + 1 < nt) { STAGE_K(kt + 1, cur ^ 1); STAGE_V(kt + 1, cur ^ 1); }

    if (kv0 < q0w + 32) {
      f32x16 s0 = {}, s1 = {};
#pragma unroll
      for (int ks = 0; ks < 8; ++ks) {
        const int gcb = 32 * ks + 16 * hi;
        const int sw = (col & 7) << 4;
        const s16x8 k0 = *(const s16x8*)((const char*)Ks[cur] + col * 256 + (gcb ^ sw));
        const s16x8 k1 = *(const s16x8*)((const char*)Ks[cur] + (32 + col) * 256 + (gcb ^ sw));
        s0 = __builtin_amdgcn_mfma_f32_32x32x16_bf16(k0, qf[ks], s0, 0, 0, 0);
        s1 = __builtin_amdgcn_mfma_f32_32x32x16_bf16(k1, qf[ks], s1, 0, 0, 0);
      }

      const int qg = q0w + col;
      if (kv0 + 63 > q0w) {
#pragma unroll
        for (int r = 0; r < 16; ++r) {
          const int kvl = (r & 3) + 8 * (r >> 2) + 4 * hi;
          if (kv0 + kvl > qg)      s0[r] = -3e30f;
          if (kv0 + 32 + kvl > qg) s1[r] = -3e30f;
        }
      }

      float mxl = s0[0];
#pragma unroll
      for (int r = 1; r < 16; ++r) mxl = fmaxf(mxl, s0[r]);
#pragma unroll
      for (int r = 0; r < 16; ++r) mxl = fmaxf(mxl, s1[r]);
      const float mxf = fmaxf(mxl, __shfl_xor(mxl, 32));
      if (__any(mxf > m_s + 8.0f)) {
        const float mn = fmaxf(m_s, mxf);
        const float scl = __expf(m_s - mn);
        m_s = mn;
        l_s *= scl;
#pragma unroll
        for (int r = 0; r < 16; ++r) {
          const int qq = (r & 3) + 8 * (r >> 2) + 4 * hi;
          const float sr = __int_as_float(
              __builtin_amdgcn_ds_bpermute(qq * 4, __float_as_int(scl)));
          oacc[0][r] *= sr; oacc[1][r] *= sr; oacc[2][r] *= sr; oacc[3][r] *= sr;
        }
      }
      float lsum = 0.0f;
#pragma unroll
      for (int r = 0; r < 16; ++r) {
        s0[r] = __expf(s0[r] - m_s); s1[r] = __expf(s1[r] - m_s);
        lsum += s0[r] + s1[r];
      }
      lsum += __shfl_xor(lsum, 32);
      l_s += lsum;

#define PV_STEP(KS, PP)                                                       \
      {                                                                       \
        const int rb2 = 8 * ((KS) & 1);                                       \
        const uint32_t g0a = cvt_pk_bf16(PP[rb2 + 0], PP[rb2 + 1]);           \
        const uint32_t g0b = cvt_pk_bf16(PP[rb2 + 2], PP[rb2 + 3]);           \
        const uint32_t g1a = cvt_pk_bf16(PP[rb2 + 4], PP[rb2 + 5]);           \
        const uint32_t g1b = cvt_pk_bf16(PP[rb2 + 6], PP[rb2 + 7]);           \
        const uint32_t sa = hi ? g0a : g1a, sb = hi ? g0b : g1b;              \
        const uint32_t ra = (uint32_t)__shfl_xor((int)sa, 32);                \
        const uint32_t rb_ = (uint32_t)__shfl_xor((int)sb, 32);               \
        frag_u af;                                                            \
        af.w[0] = hi ? ra  : g0a; af.w[1] = hi ? rb_ : g0b;                   \
        af.w[2] = hi ? g1a : ra;  af.w[3] = hi ? g1b : rb_;                   \
        const int gcb = 32 * (KS) + 16 * hi;                                  \
        const int vsw = (col & 7) << 4;                                       \
        _Pragma("unroll")                                                     \
        for (int db = 0; db < 4; ++db) {                                      \
          const s16x8 bv = *(const s16x8*)((const char*)Vs[cur] +             \
              (db * 32 + col) * 128 + (gcb ^ vsw));                           \
          oacc[db] = __builtin_amdgcn_mfma_f32_32x32x16_bf16(af.f, bv, oacc[db], 0, 0, 0); \
        }                                                                     \
      }
      PV_STEP(0, s0); PV_STEP(1, s0); PV_STEP(2, s1); PV_STEP(3, s1);
#undef PV_STEP
    }
    __syncthreads();
  }

  const float linv = 1.0f / l_s;
#pragma unroll
  for (int r = 0; r < 16; ++r) {
    const int qq = (r & 3) + 8 * (r >> 2) + 4 * hi;
    const float lr = __int_as_float(
        __builtin_amdgcn_ds_bpermute(qq * 4, __float_as_int(linv)));
    unsigned short* orow = ob + (size_t)(q0w + qq) * 4096 + h * 128 + col;
#pragma unroll
    for (int db = 0; db < 4; ++db)
      orow[db * 32] = f2bf(oacc[db][r] * lr);
  }
#undef STAGE_K
#undef STAGE_V
}

// ------------------------------ launch ------------------------------
extern "C" void kernel_launch(void* const* d_in, const int* in_sizes, int n_in,
                              void* d_out, int out_size, void* d_ws, size_t ws_size,
                              hipStream_t stream) {
  const float* x     = (const float*)d_in[0];
  const float* cos_f = (const float*)d_in[1];
  const float* sin_f = (const float*)d_in[2];
  const float* wq = (const float*)d_in[4];
  const float* wk = (const float*)d_in[5];
  const float* wv = (const float*)d_in[6];
  const float* wo = (const float*)d_in[7];
  float* out = (float*)d_out;

  char* ws = (char*)d_ws;
  unsigned short* xb    = (unsigned short*)(ws);                 // 2048x4096 bf16
  unsigned short* wqkvb = (unsigned short*)(ws + 16777216);      // 6144x4096 bf16
  unsigned short* wob   = (unsigned short*)(ws + 67108864);      // 4096x4096 bf16
  unsigned short* xqkvb = (unsigned short*)(ws + 100663296);     // 2048x6144 bf16
  unsigned short* qb    = (unsigned short*)(ws + 150994944);     // 2048x4096 bf16
  unsigned short* kb    = (unsigned short*)(ws + 167772160);     // 2048x1024 bf16
  unsigned short* vtb   = (unsigned short*)(ws + 171966464);     // [8*128][2048] bf16
  unsigned short* attno = (unsigned short*)(ws + 176160768);     // 2048x4096 bf16

  // all fp32->bf16 casts in one dispatch (12582912 float4 items)
  cast_all<<<dim3(49152), 256, 0, stream>>>(x, wq, wk, wv, wo, xb, wqkvb, wob);

  // fused QKV projection: [2048x4096] x [6144x4096]^T -> [2048x6144] bf16
  gemmF<64, 192, 6, 6, 1><<<dim3(512), 256, 0, stream>>>(xb, wqkvb, xqkvb, 6144);

  // fused RoPE Q+K (+fp32 cache_k write)
  rope_qk_kern<<<dim3(5120), 256, 0, stream>>>(xqkvb, cos_f, sin_f, qb,
                                               out + 8388608, kb);
  vtrans_kern<<<dim3(32, 16), 256, 0, stream>>>(xqkvb, out + 12582912, vtb);

  (void)hipMemsetAsync(out + 10485760, 0, 8388608, stream);
  (void)hipMemsetAsync(out + 14680064, 0, 8388608, stream);

  attn_fwd3<<<dim3(512), 256, 0, stream>>>(qb, kb, vtb, attno);

  // output projection: [2048x4096] x [4096x4096]^T -> d_out fp32 directly
  gemmF<64, 128, 4, 4, 0><<<dim3(512), 256, 0, stream>>>(attno, wob, out, 4096);
}